// Round 16
// baseline (18191.220 us; speedup 1.0000x reference)
//
#include <hip/hip_runtime.h>

#define Bz 32
#define Tz 256
#define Hz 512
#define Nz 5
#define Rz 2
#define Wz 512
#define WP 520           // padded s_M row stride
#define RWz 1024
#define XD 1536          // H + R*W
#define IFz 2573
#define EPSF 1e-6f
#define NWG 256
#define NT 1024
#define NTH (NWG*NT)     // 262144

#define HTB (Bz*Hz)      // 16384 floats per h buffer
#define RTB (Bz*RWz)     // 32768 floats per r buffer
#define BLS 2064         // per-batch LDS slab stride (2048 + 16 pad)

// workspace float offsets (same as R10..R14 runs)
#define WXIT_OFF (Tz*Bz*Hz)                            // 4194304
#define WOUT_OFF (WXIT_OFF + IFz*Hz)                   // 5511680
#define HT_OFF   (WOUT_OFF + Hz*XD)                    // 6298112
#define CT_OFF   (HT_OFF + 2*HTB)                      // 6330880
#define RT_OFF   (CT_OFF + HTB)                        // 6347264
#define XIT_OFF  (RT_OFF + 2*RTB)                      // 6412800
#define MG_OFF   (XIT_OFF + IFz*Bz)                    // 6495136
#define UG_OFF   (MG_OFF + Bz*Nz*Wz)                   // 6577056
#define BAR_OFF  (UG_OFF + 1600 + 32)                  // 6578688 (64-aligned)

// xi field offsets
#define O_KR 0
#define O_BR 1024
#define O_KW 1026
#define O_BW 1538
#define O_E  1539
#define O_V  2051
#define O_FG 2563
#define O_GA 2565
#define O_GW 2566
#define O_PI 2567

typedef unsigned long long u64;

__device__ __forceinline__ float sigf(float x){ return 1.0f/(1.0f+expf(-x)); }
__device__ __forceinline__ float splus(float x){ return fmaxf(x,0.0f) + log1pf(expf(-fabsf(x))); }

// coherent accessors (R12-proven)
__device__ __forceinline__ void stage64(float* dst_lds, const float* src){
  u64 v = __hip_atomic_load((const u64*)src, __ATOMIC_RELAXED, __HIP_MEMORY_SCOPE_AGENT);
  *(u64*)dst_lds = v;
}
__device__ __forceinline__ float ld32cv(const float* p){
  return __hip_atomic_load(p, __ATOMIC_RELAXED, __HIP_MEMORY_SCOPE_AGENT);
}
__device__ __forceinline__ void st32cv(float* p, float v){
  __hip_atomic_store(p, v, __ATOMIC_RELAXED, __HIP_MEMORY_SCOPE_AGENT);
}
// non-temporal STREAM accessors (no L2 allocation; R13-proven asm shapes)
__device__ __forceinline__ void ldnt64(float* dst_lds, const float* src){
  u64 v;
  asm volatile("global_load_dwordx2 %0, %1, off nt\n\t"
               "s_waitcnt vmcnt(0)"
               : "=v"(v) : "v"(src) : "memory");
  *(u64*)dst_lds = v;
}
__device__ __forceinline__ void stnt32(float* p, float v){
  asm volatile("global_store_dword %0, %1, off nt" :: "v"(p), "v"(v) : "memory");
}

// ---- grid barriers ----
// fence version (init/final only): two-level with full agent fences
__device__ __forceinline__ void gbar_fence(unsigned* bar, unsigned k){
  asm volatile("s_waitcnt vmcnt(0) lgkmcnt(0)" ::: "memory");
  __syncthreads();
  const int tid = threadIdx.x;
  const unsigned wg = blockIdx.x;
  if (tid == 0){
    __builtin_amdgcn_fence(__ATOMIC_RELEASE, "agent");
    __hip_atomic_fetch_add(&bar[(wg & 15u)*64], 1u, __ATOMIC_RELAXED, __HIP_MEMORY_SCOPE_AGENT);
  }
  if (wg == 0){
    if (tid < 16){
      const unsigned tgt = (NWG/16u)*(k+1u);
      while (__hip_atomic_load(&bar[tid*64], __ATOMIC_RELAXED, __HIP_MEMORY_SCOPE_AGENT) < tgt)
        __builtin_amdgcn_s_sleep(1);
    }
    __syncthreads();
    if (tid < 16){
      __builtin_amdgcn_fence(__ATOMIC_ACQ_REL, "agent");
      __hip_atomic_store(&bar[1024 + tid*64], k+1u, __ATOMIC_RELAXED, __HIP_MEMORY_SCOPE_AGENT);
    }
    __syncthreads();
  } else {
    if (tid == 0){
      while (__hip_atomic_load(&bar[1024 + (wg & 15u)*64], __ATOMIC_RELAXED, __HIP_MEMORY_SCOPE_AGENT) < k+1u)
        __builtin_amdgcn_s_sleep(1);
      __builtin_amdgcn_fence(__ATOMIC_ACQUIRE, "agent");
    }
    __syncthreads();
  }
}
// flat no-fence barrier: every WG polls all 16 counters directly (one hop)
__device__ __forceinline__ void gbar_nf(unsigned* bar, unsigned k){
  __syncthreads();
  const int tid = threadIdx.x;
  if (tid == 0){
    asm volatile("s_waitcnt vmcnt(0) lgkmcnt(0)" ::: "memory");
    __hip_atomic_fetch_add(&bar[(blockIdx.x & 15u)*64], 1u, __ATOMIC_RELAXED, __HIP_MEMORY_SCOPE_AGENT);
  }
  if (tid < 16){
    const unsigned tgt = (NWG/16u)*(k+1u);
    while (__hip_atomic_load(&bar[tid*64], __ATOMIC_RELAXED, __HIP_MEMORY_SCOPE_AGENT) < tgt)
      __builtin_amdgcn_s_sleep(1);
  }
  __syncthreads();
}

// contiguous · contiguous dot (epilogue)
__device__ __forceinline__ float dot4c(const float* __restrict__ x,
                                       const float* __restrict__ w, int n){
  const float4* x4 = (const float4*)x;
  const float4* w4 = (const float4*)w;
  float a0=0.f,a1=0.f,a2=0.f,a3=0.f;
  #pragma unroll 8
  for (int i=0;i<n/4;i++){
    float4 xv=x4[i], wv=w4[i];
    a0=fmaf(xv.x,wv.x,a0); a1=fmaf(xv.y,wv.y,a1);
    a2=fmaf(xv.z,wv.z,a2); a3=fmaf(xv.w,wv.w,a3);
  }
  return (a0+a1)+(a2+a3);
}
// strided dot
__device__ __forceinline__ float dotS(const float* x, const float* __restrict__ w,
                                      int iters, int strf){
  float a0=0.f,a1=0.f,a2=0.f,a3=0.f;
  #pragma unroll 16
  for (int i=0;i<iters;i++){
    float4 xv = *(const float4*)(x + (size_t)i*strf);
    float4 wv = *(const float4*)(w + (size_t)i*strf);
    a0=fmaf(xv.x,wv.x,a0); a1=fmaf(xv.y,wv.y,a1);
    a2=fmaf(xv.z,wv.z,a2); a3=fmaf(xv.w,wv.w,a3);
  }
  return (a0+a1)+(a2+a3);
}

__device__ void memops(int b, int t, const float* xiT,
                       float* Mg, float* ug, float* pg, float* wwg, float* Lg, float* wrg,
                       float* rT)
{
  __shared__ float s_xi[IFz];
  __shared__ float s_M[Nz*WP];
  __shared__ float s_u[Nz], s_p[Nz], s_ww[Nz], s_a[Nz], s_L[Nz*Nz], s_wr[Rz*Nz];
  __shared__ float s_sc[13];
  __shared__ float s_m2[Nz], s_dt[Nz], s_d0[Nz], s_d1[Nz];
  __shared__ float s_kw2, s_kr2[2];
  __shared__ float s_fwd[Rz*Nz], s_bwd[Rz*Nz];

  const int tid = threadIdx.x;
  const int wv = tid >> 6, ln = tid & 63;

  for (int f = tid; f < IFz; f += NT) s_xi[f] = ld32cv(&xiT[(size_t)b*IFz + f]);
  for (int i = tid; i < Nz*Wz; i += NT){
    int n = i >> 9, w = i & 511;
    s_M[n*WP+w] = Mg[(size_t)b*Nz*Wz + i];
  }
  if (tid < Nz){ s_u[tid]=ug[b*Nz+tid]; s_p[tid]=pg[b*Nz+tid]; s_ww[tid]=wwg[b*Nz+tid]; }
  if (tid < Nz*Nz) s_L[tid] = Lg[b*Nz*Nz+tid];
  if (tid < Rz*Nz) s_wr[tid] = wrg[b*Rz*Nz+tid];
  __syncthreads();

  if (tid == 0){
    s_sc[0] = 1.0f + splus(s_xi[O_BR+0]);
    s_sc[1] = 1.0f + splus(s_xi[O_BR+1]);
    s_sc[2] = 1.0f + splus(s_xi[O_BW]);
    s_sc[3] = sigf(s_xi[O_FG+0]);
    s_sc[4] = sigf(s_xi[O_FG+1]);
    s_sc[5] = sigf(s_xi[O_GA]);
    s_sc[6] = sigf(s_xi[O_GW]);
    for (int r=0;r<Rz;r++){
      float x0=s_xi[O_PI+r*3+0], x1=s_xi[O_PI+r*3+1], x2=s_xi[O_PI+r*3+2];
      float m = fmaxf(x0,fmaxf(x1,x2));
      float e0=expf(x0-m), e1=expf(x1-m), e2=expf(x2-m);
      float s = e0+e1+e2;
      s_sc[7+r*3+0]=e0/s; s_sc[7+r*3+1]=e1/s; s_sc[7+r*3+2]=e2/s;
    }
  }
  __syncthreads();

  if (tid < Nz){
    float psi = (1.0f - s_sc[3]*s_wr[0*Nz+tid]) * (1.0f - s_sc[4]*s_wr[1*Nz+tid]);
    float uu = s_u[tid], w = s_ww[tid];
    s_u[tid] = (uu + w - uu*w) * psi;
  }

  // cosine(M_old, kw)
  if (wv < 4){
    const int n = wv;
    float pd=0.f, pm=0.f;
    for (int w = ln; w < Wz; w += 64){
      float kv = s_xi[O_KW+w], mv = s_M[n*WP+w];
      pd = fmaf(kv,mv,pd); pm = fmaf(mv,mv,pm);
    }
    for (int off=32; off; off>>=1){ pd += __shfl_down(pd,off,64); pm += __shfl_down(pm,off,64); }
    if (ln==0){ s_dt[n]=pd; s_m2[n]=pm; }
  }
  if (wv == 3){
    float p2=0.f;
    for (int w=ln; w<Wz; w+=64){ float kv=s_xi[O_KW+w]; p2=fmaf(kv,kv,p2); }
    for (int off=32; off; off>>=1) p2 += __shfl_down(p2,off,64);
    if (ln==0) s_kw2 = p2;
  }
  __syncthreads();
  if (wv == 0){
    const int n = 4;
    float pd=0.f, pm=0.f;
    for (int w = ln; w < Wz; w += 64){
      float kv = s_xi[O_KW+w], mv = s_M[n*WP+w];
      pd = fmaf(kv,mv,pd); pm = fmaf(mv,mv,pm);
    }
    for (int off=32; off; off>>=1){ pd += __shfl_down(pd,off,64); pm += __shfl_down(pm,off,64); }
    if (ln==0){ s_dt[n]=pd; s_m2[n]=pm; }
  }
  __syncthreads();

  if (tid == 0){
    float su[Nz]; int idx[Nz];
    for (int i=0;i<Nz;i++){
      float v = EPSF + (1.0f-EPSF)*s_u[i];
      int j=i;
      while (j>0 && su[j-1] > v){ su[j]=su[j-1]; idx[j]=idx[j-1]; j--; }
      su[j]=v; idx[j]=i;
    }
    float cp = 1.0f;
    for (int k=0;k<Nz;k++){ s_a[idx[k]] = (1.0f - su[k])*cp; cp *= su[k]; }
    float rk = rsqrtf(s_kw2 + EPSF);
    float lg[Nz], mx=-1e30f;
    for (int n=0;n<Nz;n++){ lg[n] = s_sc[2]*s_dt[n]*rk*rsqrtf(s_m2[n]+EPSF); mx=fmaxf(mx,lg[n]); }
    float ssum=0.f;
    for (int n=0;n<Nz;n++){ lg[n]=expf(lg[n]-mx); ssum+=lg[n]; }
    float ga=s_sc[5], gw=s_sc[6];
    for (int n=0;n<Nz;n++){ float cwn = lg[n]/ssum; s_ww[n] = gw*(ga*s_a[n] + (1.0f-ga)*cwn); }
  }
  __syncthreads();

  for (int i = tid; i < Nz*Wz; i += NT){
    int n = i >> 9, w = i & 511;
    float e = sigf(s_xi[O_E+w]);
    float v = s_xi[O_V+w];
    s_M[n*WP+w] = s_M[n*WP+w]*(1.0f - s_ww[n]*e) + s_ww[n]*v;
  }
  __syncthreads();

  if (tid == 0){
    float wsum = 0.f;
    for (int n=0;n<Nz;n++) wsum += s_ww[n];
    float Lo[Nz*Nz];
    for (int i=0;i<Nz;i++)
      for (int j=0;j<Nz;j++)
        Lo[i*Nz+j] = (i==j) ? 0.0f : ((1.0f - s_ww[i] - s_ww[j])*s_L[i*Nz+j] + s_ww[i]*s_p[j]);
    for (int i=0;i<Nz*Nz;i++) s_L[i]=Lo[i];
    for (int j=0;j<Nz;j++) s_p[j] = (1.0f-wsum)*s_p[j] + s_ww[j];
    for (int r=0;r<Rz;r++)
      for (int n=0;n<Nz;n++){
        float f=0.f, bb=0.f;
        for (int m=0;m<Nz;m++){ f = fmaf(s_L[n*Nz+m], s_wr[r*Nz+m], f); bb = fmaf(s_L[m*Nz+n], s_wr[r*Nz+m], bb); }
        s_fwd[r*Nz+n]=f; s_bwd[r*Nz+n]=bb;
      }
  }
  __syncthreads();

  // cosine(M_new, kr)
  if (wv < 4){
    const int n = wv;
    float pm=0.f,p0=0.f,p1=0.f;
    for (int w=ln; w<Wz; w+=64){
      float mv=s_M[n*WP+w];
      pm=fmaf(mv,mv,pm);
      p0=fmaf(s_xi[O_KR+w],    mv,p0);
      p1=fmaf(s_xi[O_KR+Wz+w], mv,p1);
    }
    for (int off=32; off; off>>=1){
      pm += __shfl_down(pm,off,64); p0 += __shfl_down(p0,off,64); p1 += __shfl_down(p1,off,64);
    }
    if (ln==0){ s_m2[n]=pm; s_d0[n]=p0; s_d1[n]=p1; }
  }
  __syncthreads();
  if (wv == 0){
    const int n = 4;
    float pm=0.f,p0=0.f,p1=0.f;
    for (int w=ln; w<Wz; w+=64){
      float mv=s_M[n*WP+w];
      pm=fmaf(mv,mv,pm);
      p0=fmaf(s_xi[O_KR+w],    mv,p0);
      p1=fmaf(s_xi[O_KR+Wz+w], mv,p1);
    }
    for (int off=32; off; off>>=1){
      pm += __shfl_down(pm,off,64); p0 += __shfl_down(p0,off,64); p1 += __shfl_down(p1,off,64);
    }
    if (ln==0){ s_m2[n]=pm; s_d0[n]=p0; s_d1[n]=p1; }
  } else if (wv == 1 || wv == 2){
    const int r = wv - 1;
    float p2=0.f;
    for (int w=ln; w<Wz; w+=64){ float kv=s_xi[O_KR+r*Wz+w]; p2=fmaf(kv,kv,p2); }
    for (int off=32; off; off>>=1) p2 += __shfl_down(p2,off,64);
    if (ln==0) s_kr2[r]=p2;
  }
  __syncthreads();

  if (tid == 0){
    for (int r=0;r<Rz;r++){
      float rk = rsqrtf(s_kr2[r]+EPSF);
      const float* dd = (r==0) ? s_d0 : s_d1;
      float br = s_sc[r];
      float lg[Nz], mx=-1e30f;
      for (int n=0;n<Nz;n++){ lg[n] = br*dd[n]*rk*rsqrtf(s_m2[n]+EPSF); mx=fmaxf(mx,lg[n]); }
      float ssum=0.f;
      for (int n=0;n<Nz;n++){ lg[n]=expf(lg[n]-mx); ssum+=lg[n]; }
      for (int n=0;n<Nz;n++){
        float crn = lg[n]/ssum;
        s_wr[r*Nz+n] = s_sc[7+r*3+0]*s_bwd[r*Nz+n] + s_sc[7+r*3+1]*crn + s_sc[7+r*3+2]*s_fwd[r*Nz+n];
      }
    }
  }
  __syncthreads();

  // read vectors -> rT[nxt][b][r*512+w] (coherent) + private state (cached)
  float* rdst = rT + (size_t)((t+1)&1)*RTB + (size_t)b*RWz;
  for (int w = tid; w < Wz; w += NT){
    float m0=s_M[0*WP+w], m1=s_M[1*WP+w], m2=s_M[2*WP+w], m3=s_M[3*WP+w], m4=s_M[4*WP+w];
    #pragma unroll
    for (int r=0;r<Rz;r++){
      float rv = s_wr[r*Nz+0]*m0 + s_wr[r*Nz+1]*m1 + s_wr[r*Nz+2]*m2
               + s_wr[r*Nz+3]*m3 + s_wr[r*Nz+4]*m4;
      st32cv(&rdst[r*Wz + w], rv);
    }
  }
  for (int i = tid; i < Nz*Wz; i += NT){
    int n = i >> 9, w = i & 511;
    Mg[(size_t)b*Nz*Wz+i] = s_M[n*WP+w];
  }
  if (tid < Nz){ ug[b*Nz+tid]=s_u[tid]; pg[b*Nz+tid]=s_p[tid]; wwg[b*Nz+tid]=s_ww[tid]; }
  if (tid < Nz*Nz) Lg[b*Nz*Nz+tid]=s_L[tid];
  if (tid < Rz*Nz) wrg[b*Rz*Nz+tid]=s_wr[tid];
}

__global__ void __launch_bounds__(NT, 4)
dnc_kernel(const int* __restrict__ src, const float* __restrict__ emb,
           const float* __restrict__ w_ih, const float* __restrict__ w_hh,
           const float* __restrict__ b_lstm,
           const float* __restrict__ w_xi, const float* __restrict__ b_xi,
           const float* __restrict__ w_out, const float* __restrict__ b_out,
           float* __restrict__ out, float* __restrict__ ws)
{
  __shared__ __align__(16) float s_x[4112];   // 2 batches x 2048, stride BLS=2064

  const int tid = threadIdx.x;
  const int gid = blockIdx.x*NT + tid;

  float* embT  = ws;                       // [T][B][512]   nt-streamed RO
  float* wxiT  = ws + WXIT_OFF;            // [IF][512]     cached RO (L2-resident)
  float* woutT = ws + WOUT_OFF;            // [512][1536]   cached RO (L2-resident)
  float* hT    = ws + HT_OFF;              // [2][B][512]   coherent
  float* cT    = ws + CT_OFF;              // [B][512]      cached, WG-pinned
  float* rT    = ws + RT_OFF;              // [2][B][1024]  coherent
  float* xiT   = ws + XIT_OFF;             // [B][IFz]      coherent
  float* Mg    = ws + MG_OFF;              // [B][2560]     cached, WG-pinned
  float* ug    = ws + UG_OFF;
  float* pg    = ug + Bz*Nz;
  float* wwg   = pg + Bz*Nz;
  float* Lg    = wwg + Bz*Nz;
  float* wrg   = Lg + Bz*Nz*Nz;
  unsigned* bar = (unsigned*)(ws + BAR_OFF);
  unsigned kbar = 0;

  // ---- init ----
  {
    float4* embT4 = (float4*)embT;
    const float4* emb4 = (const float4*)emb;
    for (int i = gid; i < Tz*Bz*128; i += NTH){
      int kg = i & 127, b = (i>>7) & 31, tt = i >> 12;
      embT4[i] = emb4[(size_t)src[b*Tz+tt]*128 + kg];
    }
  }
  for (size_t i = gid; i < (size_t)IFz*Hz; i += NTH){
    int k = (int)(i % Hz); size_t f = i / Hz;
    wxiT[i] = w_xi[(size_t)k*IFz + f];
  }
  for (size_t i = gid; i < (size_t)Hz*XD; i += NTH){
    int k = (int)(i % XD); int j = (int)(i / XD);
    woutT[i] = w_out[(size_t)k*Hz + j];
  }
  for (int i = gid; i < 2*HTB; i += NTH) hT[i]=0.f;
  for (int i = gid; i < HTB;   i += NTH) cT[i]=0.f;
  for (int i = gid; i < 2*RTB; i += NTH) rT[i]=0.f;
  for (int i = gid; i < Bz*Nz*Wz;i += NTH) Mg[i]=0.f;
  for (int i = gid; i < Bz*(3*Nz + Nz*Nz + Rz*Nz); i += NTH) ug[i]=0.f;
  gbar_fence(bar, kbar); kbar++;

  // WG decomposition: jc (XCD pin) x sj (j-half) x bp (batch pair)
  const int jc = blockIdx.x & 7;          // 0..7
  const int sj = (blockIdx.x >> 3) & 1;   // 0..1
  const int bp = blockIdx.x >> 4;         // 0..15
  const int b0 = 2*bp;                    // batches b0, b0+1
  const int jbase = jc*64 + sj*32;        // 32 j-rows per WG

  // ---- time loop (no agent fences inside) ----
  for (int t = 0; t < Tz; ++t){
    const int cur = t & 1, nxt = (t+1)&1;

    // ===== Phase A: gates GEMV (strided ks-4) + fused out(t-1) (strided 16), 2 batches =====
    {
      // stage per-batch [emb 0:512 | r 512:1536 | h 1536:2048] at s_x + bl*BLS
      // all as u64 pairs; emb via nt (read-once stream, keep L2 clean)
      for (int u = tid; u < 2048; u += NT){
        const int bl = u >> 10;
        const int v  = u & 1023;
        const int b  = b0 + bl;
        float* dst = s_x + bl*BLS;
        if (v < 256)
          stage64(dst + 1536 + v*2, hT + (size_t)cur*HTB + (size_t)b*Hz + v*2);
        else if (v < 768)
          stage64(dst + 512 + (v-256)*2, rT + (size_t)cur*RTB + (size_t)b*RWz + (v-256)*2);
        else
          ldnt64(dst + (v-768)*2, embT + ((size_t)t*Bz + b)*Hz + (v-768)*2);
      }
      __syncthreads();

      // gates: tid = jj(5b) | bl(1b) | gate(2b) | ks(2b)
      {
        const int ks   = tid & 3;
        const int gate = (tid >> 2) & 3;
        const int bl   = (tid >> 4) & 1;
        const int jj   = tid >> 5;         // 0..31
        const int j    = jbase + jj;
        const int row  = gate*Hz + j;
        const float* xb = s_x + bl*BLS;
        float acc = dotS(xb + ks*4,        w_ih + (size_t)row*XD + ks*4, 96, 16)  // [emb|r]·w_ih
                  + dotS(xb + 1536 + ks*4, w_hh + (size_t)row*Hz + ks*4, 32, 16); // h·w_hh
        acc += __shfl_xor(acc, 1, 64);
        acc += __shfl_xor(acc, 2, 64);
        acc += b_lstm[row];
        const int lane = tid & 63;
        const int base = lane & ~12;       // zero gate bits [2:3]
        float gi = __shfl(acc, base+0,  64);
        float gf = __shfl(acc, base+4,  64);
        float gg = __shfl(acc, base+8,  64);
        float go = __shfl(acc, base+12, 64);
        if ((lane & 15) == 0){             // ks==0 && gate==0
          const int b = b0 + bl;
          float cv = cT[(size_t)b*Hz + j];
          float cn = sigf(gf)*cv + sigf(gi)*tanhf(gg);
          float hn = sigf(go)*tanhf(cn);
          cT[(size_t)b*Hz + j] = cn;
          st32cv(&hT[(size_t)nxt*HTB + (size_t)b*Hz + j], hn);
        }
      }

      // fused out(t-1): tid = ojj(5b) | bl(1b) | oks(4b); [h|r]·wout strided-16
      if (t > 0){
        const int oks = tid & 15;
        const int bl  = (tid >> 4) & 1;
        const int ojj = tid >> 5;          // 0..31
        const int oj  = jbase + ojj;
        const float* xb = s_x + bl*BLS;
        const float* wo = woutT + (size_t)oj*XD + oks*4;
        const float* xh = xb + 1536 + oks*4;   // logical k<512 -> h
        const float* xr = xb + oks*4;          // logical k in [512,1536): s_x[k] = r
        float a0=0.f,a1=0.f,a2=0.f,a3=0.f;
        #pragma unroll 8
        for (int i=0;i<8;i++){
          float4 xv = *(const float4*)(xh + i*64);
          float4 wv = *(const float4*)(wo + i*64);
          a0=fmaf(xv.x,wv.x,a0); a1=fmaf(xv.y,wv.y,a1);
          a2=fmaf(xv.z,wv.z,a2); a3=fmaf(xv.w,wv.w,a3);
        }
        #pragma unroll 16
        for (int i=8;i<24;i++){
          float4 xv = *(const float4*)(xr + i*64);
          float4 wv = *(const float4*)(wo + i*64);
          a0=fmaf(xv.x,wv.x,a0); a1=fmaf(xv.y,wv.y,a1);
          a2=fmaf(xv.z,wv.z,a2); a3=fmaf(xv.w,wv.w,a3);
        }
        float oa = (a0+a1)+(a2+a3);
        oa += __shfl_xor(oa, 1, 64);
        oa += __shfl_xor(oa, 2, 64);
        oa += __shfl_xor(oa, 4, 64);
        oa += __shfl_xor(oa, 8, 64);
        if (oks == 0)
          stnt32(&out[(size_t)(b0+bl)*Tz*Hz + (size_t)(t-1)*Hz + oj], oa + b_out[oj]);
      }
    }
    gbar_nf(bar, kbar); kbar++;

    // ===== Phase B: xi = h_new @ w_xi (strided ks-4), 2 batches =====
    {
      if (tid < 512){
        const int bl = tid >> 8, v = tid & 255;
        stage64(s_x + bl*BLS + v*2, hT + (size_t)nxt*HTB + (size_t)(b0+bl)*Hz + v*2);
      }
      __syncthreads();
      const int ks  = tid & 3;
      const int bl  = (tid >> 2) & 1;
      const int fi0 = tid >> 3;            // 0..127
      #pragma unroll
      for (int round = 0; round < 2; ++round){
        int fi = round*128 + fi0;          // 0..255 (need 0..160)
        int f  = jc*322 + sj*161 + fi;
        bool ok = (fi < 161) && (f < IFz);
        int fr = ok ? f : 0;
        float acc = dotS(s_x + bl*BLS + ks*4, wxiT + (size_t)fr*Hz + ks*4, 32, 16);
        acc += __shfl_xor(acc, 1, 64);
        acc += __shfl_xor(acc, 2, 64);
        if (ok && ks == 0)
          st32cv(&xiT[(size_t)(b0+bl)*IFz + f], acc + b_xi[f]);
      }
    }
    gbar_nf(bar, kbar); kbar++;

    // ===== Phase C: memops only (one WG per batch, XCD-spread) =====
    {
      const int bA = b0;       // even batch: owned by sj==0 && jc==(bA&7)
      const int bB = b0 + 1;   // odd batch:  owned by sj==1 && jc==(bB&7)
      if (sj == 0 && jc == (bA & 7))
        memops(bA, t, xiT, Mg, ug, pg, wwg, Lg, wrg, rT);
      else if (sj == 1 && jc == (bB & 7))
        memops(bB, t, xiT, Mg, ug, pg, wwg, Lg, wrg, rT);
    }
    gbar_nf(bar, kbar); kbar++;
  }

  gbar_fence(bar, kbar); kbar++;   // make coherent state + private cT cache-readable

  // ---- epilogue: out(T-1), final h, c (state in buffer 0) ----
  if (gid < Bz*Hz){
    const int eb = gid >> 9, ej = gid & 511;
    const float* wj = woutT + (size_t)ej*XD;
    float acc = dot4c(hT + (size_t)eb*Hz,  wj,       512)
              + dot4c(rT + (size_t)eb*RWz, wj + 512, 1024)
              + b_out[ej];
    out[(size_t)eb*Tz*Hz + (size_t)(Tz-1)*Hz + ej] = acc;
    out[(size_t)Bz*Tz*Hz + (size_t)eb*Hz + ej]       = hT[(size_t)eb*Hz + ej];
    out[(size_t)Bz*Tz*Hz + HTB + (size_t)eb*Hz + ej] = cT[(size_t)eb*Hz + ej];
  }
}

extern "C" void kernel_launch(void* const* d_in, const int* in_sizes, int n_in,
                              void* d_out, int out_size, void* d_ws, size_t ws_size,
                              hipStream_t stream)
{
  const int*   src    = (const int*)  d_in[0];
  // d_in[1] = source_lengths (unused by reference)
  const float* emb    = (const float*)d_in[2];
  const float* w_ih   = (const float*)d_in[3];
  const float* w_hh   = (const float*)d_in[4];
  const float* b_lstm = (const float*)d_in[5];
  const float* w_xi   = (const float*)d_in[6];
  const float* b_xi   = (const float*)d_in[7];
  const float* w_out  = (const float*)d_in[8];
  const float* b_out  = (const float*)d_in[9];
  float* out = (float*)d_out;
  float* ws  = (float*)d_ws;

  hipMemsetAsync((char*)d_ws + (size_t)BAR_OFF*4, 0, 8192, stream);

  void* args[] = { &src, &emb, &w_ih, &w_hh, &b_lstm, &w_xi, &b_xi, &w_out, &b_out, &out, &ws };
  hipLaunchCooperativeKernel((const void*)dnc_kernel, dim3(NWG), dim3(NT), args, 0, stream);
}

// Round 17
// 18129.984 us; speedup vs baseline: 1.0034x; 1.0034x over previous
//
#include <hip/hip_runtime.h>

#define Bz 32
#define Tz 256
#define Hz 512
#define Nz 5
#define Rz 2
#define Wz 512
#define WP 520           // padded s_M row stride
#define RWz 1024
#define XD 1536          // H + R*W
#define IFz 2573
#define EPSF 1e-6f
#define NWG 256
#define NT 1024
#define NTH (NWG*NT)     // 262144

#define HTB (Bz*Hz)      // 16384 floats per h buffer
#define RTB (Bz*RWz)     // 32768 floats per r buffer
#define BLS 2064         // per-batch LDS slab stride (2048 + 16 pad)

// workspace float offsets (same as R10..R15 runs)
#define WXIT_OFF (Tz*Bz*Hz)                            // 4194304
#define WOUT_OFF (WXIT_OFF + IFz*Hz)                   // 5511680
#define HT_OFF   (WOUT_OFF + Hz*XD)                    // 6298112
#define CT_OFF   (HT_OFF + 2*HTB)                      // 6330880
#define RT_OFF   (CT_OFF + HTB)                        // 6347264
#define XIT_OFF  (RT_OFF + 2*RTB)                      // 6412800
#define MG_OFF   (XIT_OFF + IFz*Bz)                    // 6495136
#define UG_OFF   (MG_OFF + Bz*Nz*Wz)                   // 6577056
#define BAR_OFF  (UG_OFF + 1600 + 32)                  // 6578688 (64-aligned)

// xi field offsets
#define O_KR 0
#define O_BR 1024
#define O_KW 1026
#define O_BW 1538
#define O_E  1539
#define O_V  2051
#define O_FG 2563
#define O_GA 2565
#define O_GW 2566
#define O_PI 2567

typedef unsigned long long u64;

__device__ __forceinline__ float sigf(float x){ return 1.0f/(1.0f+expf(-x)); }
__device__ __forceinline__ float splus(float x){ return fmaxf(x,0.0f) + log1pf(expf(-fabsf(x))); }

// coherent accessors (R12-proven: __hip_atomic, MALL-served, non-L2-allocating)
__device__ __forceinline__ void stage64(float* dst_lds, const float* src){
  u64 v = __hip_atomic_load((const u64*)src, __ATOMIC_RELAXED, __HIP_MEMORY_SCOPE_AGENT);
  *(u64*)dst_lds = v;
}
__device__ __forceinline__ float ld32cv(const float* p){
  return __hip_atomic_load(p, __ATOMIC_RELAXED, __HIP_MEMORY_SCOPE_AGENT);
}
__device__ __forceinline__ void st32cv(float* p, float v){
  __hip_atomic_store(p, v, __ATOMIC_RELAXED, __HIP_MEMORY_SCOPE_AGENT);
}

// ---- grid barriers (verbatim from R12/R14 runs) ----
__device__ __forceinline__ void gbar_fence(unsigned* bar, unsigned k){
  __syncthreads();
  const int tid = threadIdx.x;
  const unsigned wg = blockIdx.x;
  if (tid == 0){
    __builtin_amdgcn_fence(__ATOMIC_RELEASE, "agent");
    __hip_atomic_fetch_add(&bar[(wg & 15u)*64], 1u, __ATOMIC_RELAXED, __HIP_MEMORY_SCOPE_AGENT);
  }
  if (wg == 0){
    if (tid < 16){
      const unsigned tgt = (NWG/16u)*(k+1u);
      while (__hip_atomic_load(&bar[tid*64], __ATOMIC_RELAXED, __HIP_MEMORY_SCOPE_AGENT) < tgt)
        __builtin_amdgcn_s_sleep(1);
    }
    __syncthreads();
    if (tid < 16){
      __builtin_amdgcn_fence(__ATOMIC_ACQ_REL, "agent");
      __hip_atomic_store(&bar[1024 + tid*64], k+1u, __ATOMIC_RELAXED, __HIP_MEMORY_SCOPE_AGENT);
    }
    __syncthreads();
  } else {
    if (tid == 0){
      while (__hip_atomic_load(&bar[1024 + (wg & 15u)*64], __ATOMIC_RELAXED, __HIP_MEMORY_SCOPE_AGENT) < k+1u)
        __builtin_amdgcn_s_sleep(1);
      __builtin_amdgcn_fence(__ATOMIC_ACQUIRE, "agent");
    }
    __syncthreads();
  }
}
__device__ __forceinline__ void gbar_nf(unsigned* bar, unsigned k){
  __syncthreads();
  const int tid = threadIdx.x;
  const unsigned wg = blockIdx.x;
  if (tid == 0){
    asm volatile("s_waitcnt vmcnt(0) lgkmcnt(0)" ::: "memory");
    __hip_atomic_fetch_add(&bar[(wg & 15u)*64], 1u, __ATOMIC_RELAXED, __HIP_MEMORY_SCOPE_AGENT);
  }
  if (wg == 0){
    if (tid < 16){
      const unsigned tgt = (NWG/16u)*(k+1u);
      while (__hip_atomic_load(&bar[tid*64], __ATOMIC_RELAXED, __HIP_MEMORY_SCOPE_AGENT) < tgt)
        __builtin_amdgcn_s_sleep(1);
    }
    __syncthreads();
    if (tid < 16)
      __hip_atomic_store(&bar[1024 + tid*64], k+1u, __ATOMIC_RELAXED, __HIP_MEMORY_SCOPE_AGENT);
    __syncthreads();
  } else {
    if (tid == 0){
      while (__hip_atomic_load(&bar[1024 + (wg & 15u)*64], __ATOMIC_RELAXED, __HIP_MEMORY_SCOPE_AGENT) < k+1u)
        __builtin_amdgcn_s_sleep(1);
    }
    __syncthreads();
  }
}

// contiguous · contiguous dot (epilogue)
__device__ __forceinline__ float dot4c(const float* __restrict__ x,
                                       const float* __restrict__ w, int n){
  const float4* x4 = (const float4*)x;
  const float4* w4 = (const float4*)w;
  float a0=0.f,a1=0.f,a2=0.f,a3=0.f;
  #pragma unroll 8
  for (int i=0;i<n/4;i++){
    float4 xv=x4[i], wv=w4[i];
    a0=fmaf(xv.x,wv.x,a0); a1=fmaf(xv.y,wv.y,a1);
    a2=fmaf(xv.z,wv.z,a2); a3=fmaf(xv.w,wv.w,a3);
  }
  return (a0+a1)+(a2+a3);
}
// strided dot: float4 at stride `strf` floats (x and w pre-offset by lane slice)
__device__ __forceinline__ float dotS(const float* x, const float* __restrict__ w,
                                      int iters, int strf){
  float a0=0.f,a1=0.f,a2=0.f,a3=0.f;
  #pragma unroll 16
  for (int i=0;i<iters;i++){
    float4 xv = *(const float4*)(x + (size_t)i*strf);
    float4 wv = *(const float4*)(w + (size_t)i*strf);
    a0=fmaf(xv.x,wv.x,a0); a1=fmaf(xv.y,wv.y,a1);
    a2=fmaf(xv.z,wv.z,a2); a3=fmaf(xv.w,wv.w,a3);
  }
  return (a0+a1)+(a2+a3);
}

__device__ void memops(int b, int t, const float* xiT,
                       float* Mg, float* ug, float* pg, float* wwg, float* Lg, float* wrg,
                       float* rT)
{
  __shared__ float s_xi[IFz];
  __shared__ float s_M[Nz*WP];
  __shared__ float s_u[Nz], s_p[Nz], s_ww[Nz], s_a[Nz], s_L[Nz*Nz], s_wr[Rz*Nz];
  __shared__ float s_sc[13];
  __shared__ float s_m2[Nz], s_dt[Nz], s_d0[Nz], s_d1[Nz];
  __shared__ float s_kw2, s_kr2[2];
  __shared__ float s_fwd[Rz*Nz], s_bwd[Rz*Nz];

  const int tid = threadIdx.x;
  const int wv = tid >> 6, ln = tid & 63;

  for (int f = tid; f < IFz; f += NT) s_xi[f] = ld32cv(&xiT[(size_t)b*IFz + f]);
  for (int i = tid; i < Nz*Wz; i += NT){
    int n = i >> 9, w = i & 511;
    s_M[n*WP+w] = Mg[(size_t)b*Nz*Wz + i];
  }
  if (tid < Nz){ s_u[tid]=ug[b*Nz+tid]; s_p[tid]=pg[b*Nz+tid]; s_ww[tid]=wwg[b*Nz+tid]; }
  if (tid < Nz*Nz) s_L[tid] = Lg[b*Nz*Nz+tid];
  if (tid < Rz*Nz) s_wr[tid] = wrg[b*Rz*Nz+tid];
  __syncthreads();

  if (tid == 0){
    s_sc[0] = 1.0f + splus(s_xi[O_BR+0]);
    s_sc[1] = 1.0f + splus(s_xi[O_BR+1]);
    s_sc[2] = 1.0f + splus(s_xi[O_BW]);
    s_sc[3] = sigf(s_xi[O_FG+0]);
    s_sc[4] = sigf(s_xi[O_FG+1]);
    s_sc[5] = sigf(s_xi[O_GA]);
    s_sc[6] = sigf(s_xi[O_GW]);
    for (int r=0;r<Rz;r++){
      float x0=s_xi[O_PI+r*3+0], x1=s_xi[O_PI+r*3+1], x2=s_xi[O_PI+r*3+2];
      float m = fmaxf(x0,fmaxf(x1,x2));
      float e0=expf(x0-m), e1=expf(x1-m), e2=expf(x2-m);
      float s = e0+e1+e2;
      s_sc[7+r*3+0]=e0/s; s_sc[7+r*3+1]=e1/s; s_sc[7+r*3+2]=e2/s;
    }
  }
  __syncthreads();

  if (tid < Nz){
    float psi = (1.0f - s_sc[3]*s_wr[0*Nz+tid]) * (1.0f - s_sc[4]*s_wr[1*Nz+tid]);
    float uu = s_u[tid], w = s_ww[tid];
    s_u[tid] = (uu + w - uu*w) * psi;
  }

  // cosine(M_old, kw)
  if (wv < 4){
    const int n = wv;
    float pd=0.f, pm=0.f;
    for (int w = ln; w < Wz; w += 64){
      float kv = s_xi[O_KW+w], mv = s_M[n*WP+w];
      pd = fmaf(kv,mv,pd); pm = fmaf(mv,mv,pm);
    }
    for (int off=32; off; off>>=1){ pd += __shfl_down(pd,off,64); pm += __shfl_down(pm,off,64); }
    if (ln==0){ s_dt[n]=pd; s_m2[n]=pm; }
  }
  if (wv == 3){
    float p2=0.f;
    for (int w=ln; w<Wz; w+=64){ float kv=s_xi[O_KW+w]; p2=fmaf(kv,kv,p2); }
    for (int off=32; off; off>>=1) p2 += __shfl_down(p2,off,64);
    if (ln==0) s_kw2 = p2;
  }
  __syncthreads();
  if (wv == 0){
    const int n = 4;
    float pd=0.f, pm=0.f;
    for (int w = ln; w < Wz; w += 64){
      float kv = s_xi[O_KW+w], mv = s_M[n*WP+w];
      pd = fmaf(kv,mv,pd); pm = fmaf(mv,mv,pm);
    }
    for (int off=32; off; off>>=1){ pd += __shfl_down(pd,off,64); pm += __shfl_down(pm,off,64); }
    if (ln==0){ s_dt[n]=pd; s_m2[n]=pm; }
  }
  __syncthreads();

  if (tid == 0){
    float su[Nz]; int idx[Nz];
    for (int i=0;i<Nz;i++){
      float v = EPSF + (1.0f-EPSF)*s_u[i];
      int j=i;
      while (j>0 && su[j-1] > v){ su[j]=su[j-1]; idx[j]=idx[j-1]; j--; }
      su[j]=v; idx[j]=i;
    }
    float cp = 1.0f;
    for (int k=0;k<Nz;k++){ s_a[idx[k]] = (1.0f - su[k])*cp; cp *= su[k]; }
    float rk = rsqrtf(s_kw2 + EPSF);
    float lg[Nz], mx=-1e30f;
    for (int n=0;n<Nz;n++){ lg[n] = s_sc[2]*s_dt[n]*rk*rsqrtf(s_m2[n]+EPSF); mx=fmaxf(mx,lg[n]); }
    float ssum=0.f;
    for (int n=0;n<Nz;n++){ lg[n]=expf(lg[n]-mx); ssum+=lg[n]; }
    float ga=s_sc[5], gw=s_sc[6];
    for (int n=0;n<Nz;n++){ float cwn = lg[n]/ssum; s_ww[n] = gw*(ga*s_a[n] + (1.0f-ga)*cwn); }
  }
  __syncthreads();

  for (int i = tid; i < Nz*Wz; i += NT){
    int n = i >> 9, w = i & 511;
    float e = sigf(s_xi[O_E+w]);
    float v = s_xi[O_V+w];
    s_M[n*WP+w] = s_M[n*WP+w]*(1.0f - s_ww[n]*e) + s_ww[n]*v;
  }
  __syncthreads();

  if (tid == 0){
    float wsum = 0.f;
    for (int n=0;n<Nz;n++) wsum += s_ww[n];
    float Lo[Nz*Nz];
    for (int i=0;i<Nz;i++)
      for (int j=0;j<Nz;j++)
        Lo[i*Nz+j] = (i==j) ? 0.0f : ((1.0f - s_ww[i] - s_ww[j])*s_L[i*Nz+j] + s_ww[i]*s_p[j]);
    for (int i=0;i<Nz*Nz;i++) s_L[i]=Lo[i];
    for (int j=0;j<Nz;j++) s_p[j] = (1.0f-wsum)*s_p[j] + s_ww[j];
    for (int r=0;r<Rz;r++)
      for (int n=0;n<Nz;n++){
        float f=0.f, bb=0.f;
        for (int m=0;m<Nz;m++){ f = fmaf(s_L[n*Nz+m], s_wr[r*Nz+m], f); bb = fmaf(s_L[m*Nz+n], s_wr[r*Nz+m], bb); }
        s_fwd[r*Nz+n]=f; s_bwd[r*Nz+n]=bb;
      }
  }
  __syncthreads();

  // cosine(M_new, kr)
  if (wv < 4){
    const int n = wv;
    float pm=0.f,p0=0.f,p1=0.f;
    for (int w=ln; w<Wz; w+=64){
      float mv=s_M[n*WP+w];
      pm=fmaf(mv,mv,pm);
      p0=fmaf(s_xi[O_KR+w],    mv,p0);
      p1=fmaf(s_xi[O_KR+Wz+w], mv,p1);
    }
    for (int off=32; off; off>>=1){
      pm += __shfl_down(pm,off,64); p0 += __shfl_down(p0,off,64); p1 += __shfl_down(p1,off,64);
    }
    if (ln==0){ s_m2[n]=pm; s_d0[n]=p0; s_d1[n]=p1; }
  }
  __syncthreads();
  if (wv == 0){
    const int n = 4;
    float pm=0.f,p0=0.f,p1=0.f;
    for (int w=ln; w<Wz; w+=64){
      float mv=s_M[n*WP+w];
      pm=fmaf(mv,mv,pm);
      p0=fmaf(s_xi[O_KR+w],    mv,p0);
      p1=fmaf(s_xi[O_KR+Wz+w], mv,p1);
    }
    for (int off=32; off; off>>=1){
      pm += __shfl_down(pm,off,64); p0 += __shfl_down(p0,off,64); p1 += __shfl_down(p1,off,64);
    }
    if (ln==0){ s_m2[n]=pm; s_d0[n]=p0; s_d1[n]=p1; }
  } else if (wv == 1 || wv == 2){
    const int r = wv - 1;
    float p2=0.f;
    for (int w=ln; w<Wz; w+=64){ float kv=s_xi[O_KR+r*Wz+w]; p2=fmaf(kv,kv,p2); }
    for (int off=32; off; off>>=1) p2 += __shfl_down(p2,off,64);
    if (ln==0) s_kr2[r]=p2;
  }
  __syncthreads();

  if (tid == 0){
    for (int r=0;r<Rz;r++){
      float rk = rsqrtf(s_kr2[r]+EPSF);
      const float* dd = (r==0) ? s_d0 : s_d1;
      float br = s_sc[r];
      float lg[Nz], mx=-1e30f;
      for (int n=0;n<Nz;n++){ lg[n] = br*dd[n]*rk*rsqrtf(s_m2[n]+EPSF); mx=fmaxf(mx,lg[n]); }
      float ssum=0.f;
      for (int n=0;n<Nz;n++){ lg[n]=expf(lg[n]-mx); ssum+=lg[n]; }
      for (int n=0;n<Nz;n++){
        float crn = lg[n]/ssum;
        s_wr[r*Nz+n] = s_sc[7+r*3+0]*s_bwd[r*Nz+n] + s_sc[7+r*3+1]*crn + s_sc[7+r*3+2]*s_fwd[r*Nz+n];
      }
    }
  }
  __syncthreads();

  // read vectors -> rT[nxt][b][r*512+w] (coherent) + private state (cached)
  float* rdst = rT + (size_t)((t+1)&1)*RTB + (size_t)b*RWz;
  for (int w = tid; w < Wz; w += NT){
    float m0=s_M[0*WP+w], m1=s_M[1*WP+w], m2=s_M[2*WP+w], m3=s_M[3*WP+w], m4=s_M[4*WP+w];
    #pragma unroll
    for (int r=0;r<Rz;r++){
      float rv = s_wr[r*Nz+0]*m0 + s_wr[r*Nz+1]*m1 + s_wr[r*Nz+2]*m2
               + s_wr[r*Nz+3]*m3 + s_wr[r*Nz+4]*m4;
      st32cv(&rdst[r*Wz + w], rv);
    }
  }
  for (int i = tid; i < Nz*Wz; i += NT){
    int n = i >> 9, w = i & 511;
    Mg[(size_t)b*Nz*Wz+i] = s_M[n*WP+w];
  }
  if (tid < Nz){ ug[b*Nz+tid]=s_u[tid]; pg[b*Nz+tid]=s_p[tid]; wwg[b*Nz+tid]=s_ww[tid]; }
  if (tid < Nz*Nz) Lg[b*Nz*Nz+tid]=s_L[tid];
  if (tid < Rz*Nz) wrg[b*Rz*Nz+tid]=s_wr[tid];
}

__global__ void __launch_bounds__(NT, 4)
dnc_kernel(const int* __restrict__ src, const float* __restrict__ emb,
           const float* __restrict__ w_ih, const float* __restrict__ w_hh,
           const float* __restrict__ b_lstm,
           const float* __restrict__ w_xi, const float* __restrict__ b_xi,
           const float* __restrict__ w_out, const float* __restrict__ b_out,
           float* __restrict__ out, float* __restrict__ ws)
{
  __shared__ __align__(16) float s_x[4112];   // 2 batches x 2048, stride BLS=2064

  const int tid = threadIdx.x;
  const int gid = blockIdx.x*NT + tid;

  float* embT  = ws;                       // [T][B][512]   coherent-streamed RO (keep L2 clean)
  float* wxiT  = ws + WXIT_OFF;            // [IF][512]     cached RO (L2-resident)
  float* woutT = ws + WOUT_OFF;            // [512][1536]   cached RO (L2-resident)
  float* hT    = ws + HT_OFF;              // [2][B][512]   coherent
  float* cT    = ws + CT_OFF;              // [B][512]      cached, WG-pinned
  float* rT    = ws + RT_OFF;              // [2][B][1024]  coherent
  float* xiT   = ws + XIT_OFF;             // [B][IFz]      coherent
  float* Mg    = ws + MG_OFF;              // [B][2560]     cached, WG-pinned
  float* ug    = ws + UG_OFF;
  float* pg    = ug + Bz*Nz;
  float* wwg   = pg + Bz*Nz;
  float* Lg    = wwg + Bz*Nz;
  float* wrg   = Lg + Bz*Nz*Nz;
  unsigned* bar = (unsigned*)(ws + BAR_OFF);
  unsigned kbar = 0;

  // ---- init ----
  {
    float4* embT4 = (float4*)embT;
    const float4* emb4 = (const float4*)emb;
    for (int i = gid; i < Tz*Bz*128; i += NTH){
      int kg = i & 127, b = (i>>7) & 31, tt = i >> 12;
      embT4[i] = emb4[(size_t)src[b*Tz+tt]*128 + kg];
    }
  }
  for (size_t i = gid; i < (size_t)IFz*Hz; i += NTH){
    int k = (int)(i % Hz); size_t f = i / Hz;
    wxiT[i] = w_xi[(size_t)k*IFz + f];
  }
  for (size_t i = gid; i < (size_t)Hz*XD; i += NTH){
    int k = (int)(i % XD); int j = (int)(i / XD);
    woutT[i] = w_out[(size_t)k*Hz + j];
  }
  for (int i = gid; i < 2*HTB; i += NTH) hT[i]=0.f;
  for (int i = gid; i < HTB;   i += NTH) cT[i]=0.f;
  for (int i = gid; i < 2*RTB; i += NTH) rT[i]=0.f;
  for (int i = gid; i < Bz*Nz*Wz;i += NTH) Mg[i]=0.f;
  for (int i = gid; i < Bz*(3*Nz + Nz*Nz + Rz*Nz); i += NTH) ug[i]=0.f;
  gbar_fence(bar, kbar); kbar++;

  // WG decomposition: jc (XCD pin) x sj (j-half) x bp (batch pair)
  const int jc = blockIdx.x & 7;          // 0..7
  const int sj = (blockIdx.x >> 3) & 1;   // 0..1
  const int bp = blockIdx.x >> 4;         // 0..15
  const int b0 = 2*bp;                    // batches b0, b0+1
  const int jbase = jc*64 + sj*32;        // 32 j-rows per WG

  // ---- time loop (no agent fences inside) ----
  for (int t = 0; t < Tz; ++t){
    const int cur = t & 1, nxt = (t+1)&1;

    // ===== Phase A: gates GEMV (strided ks-4) + fused out(t-1) (strided 16), 2 batches =====
    {
      // stage per-batch [emb 0:512 | r 512:1536 | h 1536:2048] at s_x + bl*BLS
      // ALL cross-step state AND the emb stream via coherent u64 (no L2 allocation)
      for (int u = tid; u < 2048; u += NT){
        const int bl = u >> 10;
        const int v  = u & 1023;
        const int b  = b0 + bl;
        float* dst = s_x + bl*BLS;
        if (v < 256)
          stage64(dst + 1536 + v*2, hT + (size_t)cur*HTB + (size_t)b*Hz + v*2);
        else if (v < 768)
          stage64(dst + 512 + (v-256)*2, rT + (size_t)cur*RTB + (size_t)b*RWz + (v-256)*2);
        else
          stage64(dst + (v-768)*2, embT + ((size_t)t*Bz + b)*Hz + (v-768)*2);
      }
      __syncthreads();

      // gates: tid = jj(5b) | bl(1b) | gate(2b) | ks(2b)
      {
        const int ks   = tid & 3;
        const int gate = (tid >> 2) & 3;
        const int bl   = (tid >> 4) & 1;
        const int jj   = tid >> 5;         // 0..31
        const int j    = jbase + jj;
        const int row  = gate*Hz + j;
        const float* xb = s_x + bl*BLS;
        float acc = dotS(xb + ks*4,        w_ih + (size_t)row*XD + ks*4, 96, 16)  // [emb|r]·w_ih
                  + dotS(xb + 1536 + ks*4, w_hh + (size_t)row*Hz + ks*4, 32, 16); // h·w_hh
        acc += __shfl_xor(acc, 1, 64);
        acc += __shfl_xor(acc, 2, 64);
        acc += b_lstm[row];
        const int lane = tid & 63;
        const int base = lane & ~12;       // zero gate bits [2:3]
        float gi = __shfl(acc, base+0,  64);
        float gf = __shfl(acc, base+4,  64);
        float gg = __shfl(acc, base+8,  64);
        float go = __shfl(acc, base+12, 64);
        if ((lane & 15) == 0){             // ks==0 && gate==0
          const int b = b0 + bl;
          float cv = cT[(size_t)b*Hz + j];
          float cn = sigf(gf)*cv + sigf(gi)*tanhf(gg);
          float hn = sigf(go)*tanhf(cn);
          cT[(size_t)b*Hz + j] = cn;
          st32cv(&hT[(size_t)nxt*HTB + (size_t)b*Hz + j], hn);
        }
      }

      // fused out(t-1): tid = ojj(5b) | bl(1b) | oks(4b); [h|r]·wout strided-16
      if (t > 0){
        const int oks = tid & 15;
        const int bl  = (tid >> 4) & 1;
        const int ojj = tid >> 5;          // 0..31
        const int oj  = jbase + ojj;
        const float* xb = s_x + bl*BLS;
        const float* wo = woutT + (size_t)oj*XD + oks*4;
        const float* xh = xb + 1536 + oks*4;   // logical k<512 -> h
        const float* xr = xb + oks*4;          // logical k in [512,1536): s_x[k] = r
        float a0=0.f,a1=0.f,a2=0.f,a3=0.f;
        #pragma unroll 8
        for (int i=0;i<8;i++){
          float4 xv = *(const float4*)(xh + i*64);
          float4 wv = *(const float4*)(wo + i*64);
          a0=fmaf(xv.x,wv.x,a0); a1=fmaf(xv.y,wv.y,a1);
          a2=fmaf(xv.z,wv.z,a2); a3=fmaf(xv.w,wv.w,a3);
        }
        #pragma unroll 16
        for (int i=8;i<24;i++){
          float4 xv = *(const float4*)(xr + i*64);
          float4 wv = *(const float4*)(wo + i*64);
          a0=fmaf(xv.x,wv.x,a0); a1=fmaf(xv.y,wv.y,a1);
          a2=fmaf(xv.z,wv.z,a2); a3=fmaf(xv.w,wv.w,a3);
        }
        float oa = (a0+a1)+(a2+a3);
        oa += __shfl_xor(oa, 1, 64);
        oa += __shfl_xor(oa, 2, 64);
        oa += __shfl_xor(oa, 4, 64);
        oa += __shfl_xor(oa, 8, 64);
        if (oks == 0)
          st32cv(&out[(size_t)(b0+bl)*Tz*Hz + (size_t)(t-1)*Hz + oj], oa + b_out[oj]);
      }
    }
    gbar_nf(bar, kbar); kbar++;

    // ===== Phase B: xi = h_new @ w_xi (strided ks-4), 2 batches =====
    {
      if (tid < 512){
        const int bl = tid >> 8, v = tid & 255;
        stage64(s_x + bl*BLS + v*2, hT + (size_t)nxt*HTB + (size_t)(b0+bl)*Hz + v*2);
      }
      __syncthreads();
      const int ks  = tid & 3;
      const int bl  = (tid >> 2) & 1;
      const int fi0 = tid >> 3;            // 0..127
      #pragma unroll
      for (int round = 0; round < 2; ++round){
        int fi = round*128 + fi0;          // 0..255 (need 0..160)
        int f  = jc*322 + sj*161 + fi;
        bool ok = (fi < 161) && (f < IFz);
        int fr = ok ? f : 0;
        float acc = dotS(s_x + bl*BLS + ks*4, wxiT + (size_t)fr*Hz + ks*4, 32, 16);
        acc += __shfl_xor(acc, 1, 64);
        acc += __shfl_xor(acc, 2, 64);
        if (ok && ks == 0)
          st32cv(&xiT[(size_t)(b0+bl)*IFz + f], acc + b_xi[f]);
      }
    }
    gbar_nf(bar, kbar); kbar++;

    // ===== Phase C: memops only (one WG per batch, XCD-spread) =====
    {
      const int bA = b0;       // even batch: owned by sj==0 && jc==(bA&7)
      const int bB = b0 + 1;   // odd batch:  owned by sj==1 && jc==(bB&7)
      if (sj == 0 && jc == (bA & 7))
        memops(bA, t, xiT, Mg, ug, pg, wwg, Lg, wrg, rT);
      else if (sj == 1 && jc == (bB & 7))
        memops(bB, t, xiT, Mg, ug, pg, wwg, Lg, wrg, rT);
    }
    gbar_nf(bar, kbar); kbar++;
  }

  gbar_fence(bar, kbar); kbar++;   // make coherent state + private cT cache-readable

  // ---- epilogue: out(T-1), final h, c (state in buffer 0) ----
  if (gid < Bz*Hz){
    const int eb = gid >> 9, ej = gid & 511;
    const float* wj = woutT + (size_t)ej*XD;
    float acc = dot4c(hT + (size_t)eb*Hz,  wj,       512)
              + dot4c(rT + (size_t)eb*RWz, wj + 512, 1024)
              + b_out[ej];
    out[(size_t)eb*Tz*Hz + (size_t)(Tz-1)*Hz + ej] = acc;
    out[(size_t)Bz*Tz*Hz + (size_t)eb*Hz + ej]       = hT[(size_t)eb*Hz + ej];
    out[(size_t)Bz*Tz*Hz + HTB + (size_t)eb*Hz + ej] = cT[(size_t)eb*Hz + ej];
  }
}

extern "C" void kernel_launch(void* const* d_in, const int* in_sizes, int n_in,
                              void* d_out, int out_size, void* d_ws, size_t ws_size,
                              hipStream_t stream)
{
  const int*   src    = (const int*)  d_in[0];
  // d_in[1] = source_lengths (unused by reference)
  const float* emb    = (const float*)d_in[2];
  const float* w_ih   = (const float*)d_in[3];
  const float* w_hh   = (const float*)d_in[4];
  const float* b_lstm = (const float*)d_in[5];
  const float* w_xi   = (const float*)d_in[6];
  const float* b_xi   = (const float*)d_in[7];
  const float* w_out  = (const float*)d_in[8];
  const float* b_out  = (const float*)d_in[9];
  float* out = (float*)d_out;
  float* ws  = (float*)d_ws;

  hipMemsetAsync((char*)d_ws + (size_t)BAR_OFF*4, 0, 8192, stream);

  void* args[] = { &src, &emb, &w_ih, &w_hh, &b_lstm, &w_xi, &b_xi, &w_out, &b_out, &out, &ws };
  hipLaunchCooperativeKernel((const void*)dnc_kernel, dim3(NWG), dim3(NT), args, 0, stream);
}

// Round 18
// 15283.118 us; speedup vs baseline: 1.1903x; 1.1863x over previous
//
#include <hip/hip_runtime.h>

#define Bz 32
#define Tz 256
#define Hz 512
#define Nz 5
#define Rz 2
#define Wz 512
#define WP 520           // padded s_M row stride
#define RWz 1024
#define XD 1536          // H + R*W
#define GK 2048          // gates K (XD + Hz)
#define IFz 2573
#define EPSF 1e-6f
#define NWG 256
#define NT 1024
#define NTH (NWG*NT)     // 262144

#define HTB (Bz*Hz)      // 16384 floats per h buffer
#define RTB (Bz*RWz)     // 32768 floats per r buffer
#define BLS 2064         // per-batch LDS slab stride (2048 + 16 pad)

// workspace float offsets
#define WXIT_OFF (Tz*Bz*Hz)                            // 4194304
#define WOUT_OFF (WXIT_OFF + IFz*Hz)                   // 5511680
#define HT_OFF   (WOUT_OFF + Hz*XD)                    // 6298112
#define CT_OFF   (HT_OFF + 2*HTB)                      // 6330880
#define RT_OFF   (CT_OFF + HTB)                        // 6347264
#define XIT_OFF  (RT_OFF + 2*RTB)                      // 6412800
#define MG_OFF   (XIT_OFF + IFz*Bz)                    // 6495136
#define UG_OFF   (MG_OFF + Bz*Nz*Wz)                   // 6577056
#define BAR_OFF  (UG_OFF + 1600 + 32)                  // 6578688 (64-aligned)
#define WBF_OFF  (BAR_OFF + 2048)                      // 6580736 (bf16 gates: 2048x2048 ushort)

// xi field offsets
#define O_KR 0
#define O_BR 1024
#define O_KW 1026
#define O_BW 1538
#define O_E  1539
#define O_V  2051
#define O_FG 2563
#define O_GA 2565
#define O_GW 2566
#define O_PI 2567

typedef unsigned long long u64;

__device__ __forceinline__ float sigf(float x){ return 1.0f/(1.0f+expf(-x)); }
__device__ __forceinline__ float splus(float x){ return fmaxf(x,0.0f) + log1pf(expf(-fabsf(x))); }

// coherent accessors (R12-proven)
__device__ __forceinline__ void stage64(float* dst_lds, const float* src){
  u64 v = __hip_atomic_load((const u64*)src, __ATOMIC_RELAXED, __HIP_MEMORY_SCOPE_AGENT);
  *(u64*)dst_lds = v;
}
__device__ __forceinline__ float ld32cv(const float* p){
  return __hip_atomic_load(p, __ATOMIC_RELAXED, __HIP_MEMORY_SCOPE_AGENT);
}
__device__ __forceinline__ void st32cv(float* p, float v){
  __hip_atomic_store(p, v, __ATOMIC_RELAXED, __HIP_MEMORY_SCOPE_AGENT);
}

// ---- grid barriers (verbatim from R12/R14 runs) ----
__device__ __forceinline__ void gbar_fence(unsigned* bar, unsigned k){
  __syncthreads();
  const int tid = threadIdx.x;
  const unsigned wg = blockIdx.x;
  if (tid == 0){
    __builtin_amdgcn_fence(__ATOMIC_RELEASE, "agent");
    __hip_atomic_fetch_add(&bar[(wg & 15u)*64], 1u, __ATOMIC_RELAXED, __HIP_MEMORY_SCOPE_AGENT);
  }
  if (wg == 0){
    if (tid < 16){
      const unsigned tgt = (NWG/16u)*(k+1u);
      while (__hip_atomic_load(&bar[tid*64], __ATOMIC_RELAXED, __HIP_MEMORY_SCOPE_AGENT) < tgt)
        __builtin_amdgcn_s_sleep(1);
    }
    __syncthreads();
    if (tid < 16){
      __builtin_amdgcn_fence(__ATOMIC_ACQ_REL, "agent");
      __hip_atomic_store(&bar[1024 + tid*64], k+1u, __ATOMIC_RELAXED, __HIP_MEMORY_SCOPE_AGENT);
    }
    __syncthreads();
  } else {
    if (tid == 0){
      while (__hip_atomic_load(&bar[1024 + (wg & 15u)*64], __ATOMIC_RELAXED, __HIP_MEMORY_SCOPE_AGENT) < k+1u)
        __builtin_amdgcn_s_sleep(1);
      __builtin_amdgcn_fence(__ATOMIC_ACQUIRE, "agent");
    }
    __syncthreads();
  }
}
__device__ __forceinline__ void gbar_nf(unsigned* bar, unsigned k){
  __syncthreads();
  const int tid = threadIdx.x;
  const unsigned wg = blockIdx.x;
  if (tid == 0){
    asm volatile("s_waitcnt vmcnt(0) lgkmcnt(0)" ::: "memory");
    __hip_atomic_fetch_add(&bar[(wg & 15u)*64], 1u, __ATOMIC_RELAXED, __HIP_MEMORY_SCOPE_AGENT);
  }
  if (wg == 0){
    if (tid < 16){
      const unsigned tgt = (NWG/16u)*(k+1u);
      while (__hip_atomic_load(&bar[tid*64], __ATOMIC_RELAXED, __HIP_MEMORY_SCOPE_AGENT) < tgt)
        __builtin_amdgcn_s_sleep(1);
    }
    __syncthreads();
    if (tid < 16)
      __hip_atomic_store(&bar[1024 + tid*64], k+1u, __ATOMIC_RELAXED, __HIP_MEMORY_SCOPE_AGENT);
    __syncthreads();
  } else {
    if (tid == 0){
      while (__hip_atomic_load(&bar[1024 + (wg & 15u)*64], __ATOMIC_RELAXED, __HIP_MEMORY_SCOPE_AGENT) < k+1u)
        __builtin_amdgcn_s_sleep(1);
    }
    __syncthreads();
  }
}

// contiguous · contiguous dot (epilogue)
__device__ __forceinline__ float dot4c(const float* __restrict__ x,
                                       const float* __restrict__ w, int n){
  const float4* x4 = (const float4*)x;
  const float4* w4 = (const float4*)w;
  float a0=0.f,a1=0.f,a2=0.f,a3=0.f;
  #pragma unroll 8
  for (int i=0;i<n/4;i++){
    float4 xv=x4[i], wv=w4[i];
    a0=fmaf(xv.x,wv.x,a0); a1=fmaf(xv.y,wv.y,a1);
    a2=fmaf(xv.z,wv.z,a2); a3=fmaf(xv.w,wv.w,a3);
  }
  return (a0+a1)+(a2+a3);
}
// strided fp32 dot
__device__ __forceinline__ float dotS(const float* x, const float* __restrict__ w,
                                      int iters, int strf){
  float a0=0.f,a1=0.f,a2=0.f,a3=0.f;
  #pragma unroll 16
  for (int i=0;i<iters;i++){
    float4 xv = *(const float4*)(x + (size_t)i*strf);
    float4 wv = *(const float4*)(w + (size_t)i*strf);
    a0=fmaf(xv.x,wv.x,a0); a1=fmaf(xv.y,wv.y,a1);
    a2=fmaf(xv.z,wv.z,a2); a3=fmaf(xv.w,wv.w,a3);
  }
  return (a0+a1)+(a2+a3);
}
// strided bf16-weight dot: x fp32 in LDS, w bf16 (4 consecutive = one u64)
__device__ __forceinline__ float dotSbf(const float* x, const unsigned short* __restrict__ w,
                                        int iters, int strf){
  float a0=0.f,a1=0.f,a2=0.f,a3=0.f;
  #pragma unroll 16
  for (int i=0;i<iters;i++){
    float4 xv = *(const float4*)(x + (size_t)i*strf);
    u64 wb = *(const u64*)(w + (size_t)i*strf);
    float w0 = __uint_as_float((unsigned)( wb        & 0xFFFFu) << 16);
    float w1 = __uint_as_float((unsigned)((wb >> 16) & 0xFFFFu) << 16);
    float w2 = __uint_as_float((unsigned)((wb >> 32) & 0xFFFFu) << 16);
    float w3 = __uint_as_float((unsigned)((wb >> 48) & 0xFFFFu) << 16);
    a0=fmaf(xv.x,w0,a0); a1=fmaf(xv.y,w1,a1);
    a2=fmaf(xv.z,w2,a2); a3=fmaf(xv.w,w3,a3);
  }
  return (a0+a1)+(a2+a3);
}

__device__ void memops(int b, int t, const float* xiT,
                       float* Mg, float* ug, float* pg, float* wwg, float* Lg, float* wrg,
                       float* rT)
{
  __shared__ float s_xi[IFz];
  __shared__ float s_M[Nz*WP];
  __shared__ float s_u[Nz], s_p[Nz], s_ww[Nz], s_a[Nz], s_L[Nz*Nz], s_wr[Rz*Nz];
  __shared__ float s_sc[13];
  __shared__ float s_m2[Nz], s_dt[Nz], s_d0[Nz], s_d1[Nz];
  __shared__ float s_kw2, s_kr2[2];
  __shared__ float s_fwd[Rz*Nz], s_bwd[Rz*Nz];

  const int tid = threadIdx.x;
  const int wv = tid >> 6, ln = tid & 63;

  for (int f = tid; f < IFz; f += NT) s_xi[f] = ld32cv(&xiT[(size_t)b*IFz + f]);
  for (int i = tid; i < Nz*Wz; i += NT){
    int n = i >> 9, w = i & 511;
    s_M[n*WP+w] = Mg[(size_t)b*Nz*Wz + i];
  }
  if (tid < Nz){ s_u[tid]=ug[b*Nz+tid]; s_p[tid]=pg[b*Nz+tid]; s_ww[tid]=wwg[b*Nz+tid]; }
  if (tid < Nz*Nz) s_L[tid] = Lg[b*Nz*Nz+tid];
  if (tid < Rz*Nz) s_wr[tid] = wrg[b*Rz*Nz+tid];
  __syncthreads();

  if (tid == 0){
    s_sc[0] = 1.0f + splus(s_xi[O_BR+0]);
    s_sc[1] = 1.0f + splus(s_xi[O_BR+1]);
    s_sc[2] = 1.0f + splus(s_xi[O_BW]);
    s_sc[3] = sigf(s_xi[O_FG+0]);
    s_sc[4] = sigf(s_xi[O_FG+1]);
    s_sc[5] = sigf(s_xi[O_GA]);
    s_sc[6] = sigf(s_xi[O_GW]);
    for (int r=0;r<Rz;r++){
      float x0=s_xi[O_PI+r*3+0], x1=s_xi[O_PI+r*3+1], x2=s_xi[O_PI+r*3+2];
      float m = fmaxf(x0,fmaxf(x1,x2));
      float e0=expf(x0-m), e1=expf(x1-m), e2=expf(x2-m);
      float s = e0+e1+e2;
      s_sc[7+r*3+0]=e0/s; s_sc[7+r*3+1]=e1/s; s_sc[7+r*3+2]=e2/s;
    }
  }
  __syncthreads();

  if (tid < Nz){
    float psi = (1.0f - s_sc[3]*s_wr[0*Nz+tid]) * (1.0f - s_sc[4]*s_wr[1*Nz+tid]);
    float uu = s_u[tid], w = s_ww[tid];
    s_u[tid] = (uu + w - uu*w) * psi;
  }

  // cosine(M_old, kw)
  if (wv < 4){
    const int n = wv;
    float pd=0.f, pm=0.f;
    for (int w = ln; w < Wz; w += 64){
      float kv = s_xi[O_KW+w], mv = s_M[n*WP+w];
      pd = fmaf(kv,mv,pd); pm = fmaf(mv,mv,pm);
    }
    for (int off=32; off; off>>=1){ pd += __shfl_down(pd,off,64); pm += __shfl_down(pm,off,64); }
    if (ln==0){ s_dt[n]=pd; s_m2[n]=pm; }
  }
  if (wv == 3){
    float p2=0.f;
    for (int w=ln; w<Wz; w+=64){ float kv=s_xi[O_KW+w]; p2=fmaf(kv,kv,p2); }
    for (int off=32; off; off>>=1) p2 += __shfl_down(p2,off,64);
    if (ln==0) s_kw2 = p2;
  }
  __syncthreads();
  if (wv == 0){
    const int n = 4;
    float pd=0.f, pm=0.f;
    for (int w = ln; w < Wz; w += 64){
      float kv = s_xi[O_KW+w], mv = s_M[n*WP+w];
      pd = fmaf(kv,mv,pd); pm = fmaf(mv,mv,pm);
    }
    for (int off=32; off; off>>=1){ pd += __shfl_down(pd,off,64); pm += __shfl_down(pm,off,64); }
    if (ln==0){ s_dt[n]=pd; s_m2[n]=pm; }
  }
  __syncthreads();

  if (tid == 0){
    float su[Nz]; int idx[Nz];
    for (int i=0;i<Nz;i++){
      float v = EPSF + (1.0f-EPSF)*s_u[i];
      int j=i;
      while (j>0 && su[j-1] > v){ su[j]=su[j-1]; idx[j]=idx[j-1]; j--; }
      su[j]=v; idx[j]=i;
    }
    float cp = 1.0f;
    for (int k=0;k<Nz;k++){ s_a[idx[k]] = (1.0f - su[k])*cp; cp *= su[k]; }
    float rk = rsqrtf(s_kw2 + EPSF);
    float lg[Nz], mx=-1e30f;
    for (int n=0;n<Nz;n++){ lg[n] = s_sc[2]*s_dt[n]*rk*rsqrtf(s_m2[n]+EPSF); mx=fmaxf(mx,lg[n]); }
    float ssum=0.f;
    for (int n=0;n<Nz;n++){ lg[n]=expf(lg[n]-mx); ssum+=lg[n]; }
    float ga=s_sc[5], gw=s_sc[6];
    for (int n=0;n<Nz;n++){ float cwn = lg[n]/ssum; s_ww[n] = gw*(ga*s_a[n] + (1.0f-ga)*cwn); }
  }
  __syncthreads();

  for (int i = tid; i < Nz*Wz; i += NT){
    int n = i >> 9, w = i & 511;
    float e = sigf(s_xi[O_E+w]);
    float v = s_xi[O_V+w];
    s_M[n*WP+w] = s_M[n*WP+w]*(1.0f - s_ww[n]*e) + s_ww[n]*v;
  }
  __syncthreads();

  if (tid == 0){
    float wsum = 0.f;
    for (int n=0;n<Nz;n++) wsum += s_ww[n];
    float Lo[Nz*Nz];
    for (int i=0;i<Nz;i++)
      for (int j=0;j<Nz;j++)
        Lo[i*Nz+j] = (i==j) ? 0.0f : ((1.0f - s_ww[i] - s_ww[j])*s_L[i*Nz+j] + s_ww[i]*s_p[j]);
    for (int i=0;i<Nz*Nz;i++) s_L[i]=Lo[i];
    for (int j=0;j<Nz;j++) s_p[j] = (1.0f-wsum)*s_p[j] + s_ww[j];
    for (int r=0;r<Rz;r++)
      for (int n=0;n<Nz;n++){
        float f=0.f, bb=0.f;
        for (int m=0;m<Nz;m++){ f = fmaf(s_L[n*Nz+m], s_wr[r*Nz+m], f); bb = fmaf(s_L[m*Nz+n], s_wr[r*Nz+m], bb); }
        s_fwd[r*Nz+n]=f; s_bwd[r*Nz+n]=bb;
      }
  }
  __syncthreads();

  // cosine(M_new, kr)
  if (wv < 4){
    const int n = wv;
    float pm=0.f,p0=0.f,p1=0.f;
    for (int w=ln; w<Wz; w+=64){
      float mv=s_M[n*WP+w];
      pm=fmaf(mv,mv,pm);
      p0=fmaf(s_xi[O_KR+w],    mv,p0);
      p1=fmaf(s_xi[O_KR+Wz+w], mv,p1);
    }
    for (int off=32; off; off>>=1){
      pm += __shfl_down(pm,off,64); p0 += __shfl_down(p0,off,64); p1 += __shfl_down(p1,off,64);
    }
    if (ln==0){ s_m2[n]=pm; s_d0[n]=p0; s_d1[n]=p1; }
  }
  __syncthreads();
  if (wv == 0){
    const int n = 4;
    float pm=0.f,p0=0.f,p1=0.f;
    for (int w=ln; w<Wz; w+=64){
      float mv=s_M[n*WP+w];
      pm=fmaf(mv,mv,pm);
      p0=fmaf(s_xi[O_KR+w],    mv,p0);
      p1=fmaf(s_xi[O_KR+Wz+w], mv,p1);
    }
    for (int off=32; off; off>>=1){
      pm += __shfl_down(pm,off,64); p0 += __shfl_down(p0,off,64); p1 += __shfl_down(p1,off,64);
    }
    if (ln==0){ s_m2[n]=pm; s_d0[n]=p0; s_d1[n]=p1; }
  } else if (wv == 1 || wv == 2){
    const int r = wv - 1;
    float p2=0.f;
    for (int w=ln; w<Wz; w+=64){ float kv=s_xi[O_KR+r*Wz+w]; p2=fmaf(kv,kv,p2); }
    for (int off=32; off; off>>=1) p2 += __shfl_down(p2,off,64);
    if (ln==0) s_kr2[r]=p2;
  }
  __syncthreads();

  if (tid == 0){
    for (int r=0;r<Rz;r++){
      float rk = rsqrtf(s_kr2[r]+EPSF);
      const float* dd = (r==0) ? s_d0 : s_d1;
      float br = s_sc[r];
      float lg[Nz], mx=-1e30f;
      for (int n=0;n<Nz;n++){ lg[n] = br*dd[n]*rk*rsqrtf(s_m2[n]+EPSF); mx=fmaxf(mx,lg[n]); }
      float ssum=0.f;
      for (int n=0;n<Nz;n++){ lg[n]=expf(lg[n]-mx); ssum+=lg[n]; }
      for (int n=0;n<Nz;n++){
        float crn = lg[n]/ssum;
        s_wr[r*Nz+n] = s_sc[7+r*3+0]*s_bwd[r*Nz+n] + s_sc[7+r*3+1]*crn + s_sc[7+r*3+2]*s_fwd[r*Nz+n];
      }
    }
  }
  __syncthreads();

  // read vectors -> rT[nxt][b][r*512+w] (coherent) + private state (cached)
  float* rdst = rT + (size_t)((t+1)&1)*RTB + (size_t)b*RWz;
  for (int w = tid; w < Wz; w += NT){
    float m0=s_M[0*WP+w], m1=s_M[1*WP+w], m2=s_M[2*WP+w], m3=s_M[3*WP+w], m4=s_M[4*WP+w];
    #pragma unroll
    for (int r=0;r<Rz;r++){
      float rv = s_wr[r*Nz+0]*m0 + s_wr[r*Nz+1]*m1 + s_wr[r*Nz+2]*m2
               + s_wr[r*Nz+3]*m3 + s_wr[r*Nz+4]*m4;
      st32cv(&rdst[r*Wz + w], rv);
    }
  }
  for (int i = tid; i < Nz*Wz; i += NT){
    int n = i >> 9, w = i & 511;
    Mg[(size_t)b*Nz*Wz+i] = s_M[n*WP+w];
  }
  if (tid < Nz){ ug[b*Nz+tid]=s_u[tid]; pg[b*Nz+tid]=s_p[tid]; wwg[b*Nz+tid]=s_ww[tid]; }
  if (tid < Nz*Nz) Lg[b*Nz*Nz+tid]=s_L[tid];
  if (tid < Rz*Nz) wrg[b*Rz*Nz+tid]=s_wr[tid];
}

__global__ void __launch_bounds__(NT, 4)
dnc_kernel(const int* __restrict__ src, const float* __restrict__ emb,
           const float* __restrict__ w_ih, const float* __restrict__ w_hh,
           const float* __restrict__ b_lstm,
           const float* __restrict__ w_xi, const float* __restrict__ b_xi,
           const float* __restrict__ w_out, const float* __restrict__ b_out,
           float* __restrict__ out, float* __restrict__ ws)
{
  __shared__ __align__(16) float s_x[4112];   // 2 batches x 2048, stride BLS=2064

  const int tid = threadIdx.x;
  const int gid = blockIdx.x*NT + tid;

  float* embT  = ws;                       // [T][B][512]   cached RO
  float* wxiT  = ws + WXIT_OFF;            // [IF][512]     cached RO (L2-resident)
  float* woutT = ws + WOUT_OFF;            // [512][1536]   cached RO (L2-resident)
  float* hT    = ws + HT_OFF;              // [2][B][512]   coherent
  float* cT    = ws + CT_OFF;              // [B][512]      cached, WG-pinned
  float* rT    = ws + RT_OFF;              // [2][B][1024]  coherent
  float* xiT   = ws + XIT_OFF;             // [B][IFz]      coherent
  float* Mg    = ws + MG_OFF;              // [B][2560]     cached, WG-pinned
  float* ug    = ws + UG_OFF;
  float* pg    = ug + Bz*Nz;
  float* wwg   = pg + Bz*Nz;
  float* Lg    = wwg + Bz*Nz;
  float* wrg   = Lg + Bz*Nz*Nz;
  unsigned* bar = (unsigned*)(ws + BAR_OFF);
  unsigned short* wbf = (unsigned short*)(ws + WBF_OFF);  // [2048 rows][2048] bf16 [w_ih|w_hh]
  unsigned kbar = 0;

  // ---- init ----
  {
    float4* embT4 = (float4*)embT;
    const float4* emb4 = (const float4*)emb;
    for (int i = gid; i < Tz*Bz*128; i += NTH){
      int kg = i & 127, b = (i>>7) & 31, tt = i >> 12;
      embT4[i] = emb4[(size_t)src[b*Tz+tt]*128 + kg];
    }
  }
  for (size_t i = gid; i < (size_t)IFz*Hz; i += NTH){
    int k = (int)(i % Hz); size_t f = i / Hz;
    wxiT[i] = w_xi[(size_t)k*IFz + f];
  }
  for (size_t i = gid; i < (size_t)Hz*XD; i += NTH){
    int k = (int)(i % XD); int j = (int)(i / XD);
    woutT[i] = w_out[(size_t)k*Hz + j];
  }
  // bf16 gates-weight mirror: row = gate*Hz+j, cols [w_ih XD | w_hh Hz], RNE
  for (int i = gid; i < GK*GK; i += NTH){
    int row = i >> 11, k = i & 2047;
    float v = (k < XD) ? w_ih[(size_t)row*XD + k] : w_hh[(size_t)row*Hz + (k - XD)];
    unsigned u = __float_as_uint(v);
    unsigned rr = (u + 0x7FFFu + ((u >> 16) & 1u)) >> 16;
    wbf[i] = (unsigned short)rr;
  }
  for (int i = gid; i < 2*HTB; i += NTH) hT[i]=0.f;
  for (int i = gid; i < HTB;   i += NTH) cT[i]=0.f;
  for (int i = gid; i < 2*RTB; i += NTH) rT[i]=0.f;
  for (int i = gid; i < Bz*Nz*Wz;i += NTH) Mg[i]=0.f;
  for (int i = gid; i < Bz*(3*Nz + Nz*Nz + Rz*Nz); i += NTH) ug[i]=0.f;
  gbar_fence(bar, kbar); kbar++;

  // WG decomposition: jc (XCD pin) x sj (j-half) x bp (batch pair)
  const int jc = blockIdx.x & 7;          // 0..7
  const int sj = (blockIdx.x >> 3) & 1;   // 0..1
  const int bp = blockIdx.x >> 4;         // 0..15
  const int b0 = 2*bp;                    // batches b0, b0+1
  const int jbase = jc*64 + sj*32;        // 32 j-rows per WG

  // ---- time loop (no agent fences inside) ----
  for (int t = 0; t < Tz; ++t){
    const int cur = t & 1, nxt = (t+1)&1;

    // ===== Phase A: gates GEMV (bf16 W, strided ks-4) + fused out(t-1), 2 batches =====
    {
      // stage per-batch [emb 0:512 | r 512:1536 | h 1536:2048] at s_x + bl*BLS
      for (int u = tid; u < 1792; u += NT){
        const int bl = (u >= 896) ? 1 : 0;
        const int v  = u - bl*896;
        const int b  = b0 + bl;
        float* dst = s_x + bl*BLS;
        if (v < 256)
          stage64(dst + 1536 + v*2, hT + (size_t)cur*HTB + (size_t)b*Hz + v*2);
        else if (v < 768)
          stage64(dst + 512 + (v-256)*2, rT + (size_t)cur*RTB + (size_t)b*RWz + (v-256)*2);
        else
          *(float4*)(dst + (v-768)*4) =
            *(const float4*)(embT + ((size_t)t*Bz + b)*Hz + (v-768)*4);
      }
      __syncthreads();

      // gates: tid = jj(5b) | bl(1b) | gate(2b) | ks(2b); s_x row order == wbf row order
      {
        const int ks   = tid & 3;
        const int gate = (tid >> 2) & 3;
        const int bl   = (tid >> 4) & 1;
        const int jj   = tid >> 5;         // 0..31
        const int j    = jbase + jj;
        const int row  = gate*Hz + j;
        const float* xb = s_x + bl*BLS;
        float acc = dotSbf(xb + ks*4, wbf + (size_t)row*GK + ks*4, 128, 16);
        acc += __shfl_xor(acc, 1, 64);
        acc += __shfl_xor(acc, 2, 64);
        acc += b_lstm[row];
        const int lane = tid & 63;
        const int base = lane & ~12;       // zero gate bits [2:3]
        float gi = __shfl(acc, base+0,  64);
        float gf = __shfl(acc, base+4,  64);
        float gg = __shfl(acc, base+8,  64);
        float go = __shfl(acc, base+12, 64);
        if ((lane & 15) == 0){             // ks==0 && gate==0
          const int b = b0 + bl;
          float cv = cT[(size_t)b*Hz + j];
          float cn = sigf(gf)*cv + sigf(gi)*tanhf(gg);
          float hn = sigf(go)*tanhf(cn);
          cT[(size_t)b*Hz + j] = cn;
          st32cv(&hT[(size_t)nxt*HTB + (size_t)b*Hz + j], hn);
        }
      }

      // fused out(t-1): tid = ojj(5b) | bl(1b) | oks(4b); [h|r]·wout strided-16 (fp32)
      if (t > 0){
        const int oks = tid & 15;
        const int bl  = (tid >> 4) & 1;
        const int ojj = tid >> 5;          // 0..31
        const int oj  = jbase + ojj;
        const float* xb = s_x + bl*BLS;
        const float* wo = woutT + (size_t)oj*XD + oks*4;
        const float* xh = xb + 1536 + oks*4;   // logical k<512 -> h
        const float* xr = xb + oks*4;          // logical k in [512,1536): s_x[k] = r
        float a0=0.f,a1=0.f,a2=0.f,a3=0.f;
        #pragma unroll 8
        for (int i=0;i<8;i++){
          float4 xv = *(const float4*)(xh + i*64);
          float4 wv = *(const float4*)(wo + i*64);
          a0=fmaf(xv.x,wv.x,a0); a1=fmaf(xv.y,wv.y,a1);
          a2=fmaf(xv.z,wv.z,a2); a3=fmaf(xv.w,wv.w,a3);
        }
        #pragma unroll 16
        for (int i=8;i<24;i++){
          float4 xv = *(const float4*)(xr + i*64);
          float4 wv = *(const float4*)(wo + i*64);
          a0=fmaf(xv.x,wv.x,a0); a1=fmaf(xv.y,wv.y,a1);
          a2=fmaf(xv.z,wv.z,a2); a3=fmaf(xv.w,wv.w,a3);
        }
        float oa = (a0+a1)+(a2+a3);
        oa += __shfl_xor(oa, 1, 64);
        oa += __shfl_xor(oa, 2, 64);
        oa += __shfl_xor(oa, 4, 64);
        oa += __shfl_xor(oa, 8, 64);
        if (oks == 0)
          out[(size_t)(b0+bl)*Tz*Hz + (size_t)(t-1)*Hz + oj] = oa + b_out[oj];
      }
    }
    gbar_nf(bar, kbar); kbar++;

    // ===== Phase B: xi = h_new @ w_xi (strided ks-4, fp32), 2 batches =====
    {
      if (tid < 512){
        const int bl = tid >> 8, v = tid & 255;
        stage64(s_x + bl*BLS + v*2, hT + (size_t)nxt*HTB + (size_t)(b0+bl)*Hz + v*2);
      }
      __syncthreads();
      const int ks  = tid & 3;
      const int bl  = (tid >> 2) & 1;
      const int fi0 = tid >> 3;            // 0..127
      #pragma unroll
      for (int round = 0; round < 2; ++round){
        int fi = round*128 + fi0;          // 0..255 (need 0..160)
        int f  = jc*322 + sj*161 + fi;
        bool ok = (fi < 161) && (f < IFz);
        int fr = ok ? f : 0;
        float acc = dotS(s_x + bl*BLS + ks*4, wxiT + (size_t)fr*Hz + ks*4, 32, 16);
        acc += __shfl_xor(acc, 1, 64);
        acc += __shfl_xor(acc, 2, 64);
        if (ok && ks == 0)
          st32cv(&xiT[(size_t)(b0+bl)*IFz + f], acc + b_xi[f]);
      }
    }
    gbar_nf(bar, kbar); kbar++;

    // ===== Phase C: memops only (one WG per batch, XCD-spread) =====
    {
      const int bA = b0;
      const int bB = b0 + 1;
      if (sj == 0 && jc == (bA & 7))
        memops(bA, t, xiT, Mg, ug, pg, wwg, Lg, wrg, rT);
      else if (sj == 1 && jc == (bB & 7))
        memops(bB, t, xiT, Mg, ug, pg, wwg, Lg, wrg, rT);
    }
    gbar_nf(bar, kbar); kbar++;
  }

  gbar_fence(bar, kbar); kbar++;   // make coherent state + private cT cache-readable

  // ---- epilogue: out(T-1), final h, c (state in buffer 0) ----
  if (gid < Bz*Hz){
    const int eb = gid >> 9, ej = gid & 511;
    const float* wj = woutT + (size_t)ej*XD;
    float acc = dot4c(hT + (size_t)eb*Hz,  wj,       512)
              + dot4c(rT + (size_t)eb*RWz, wj + 512, 1024)
              + b_out[ej];
    out[(size_t)eb*Tz*Hz + (size_t)(Tz-1)*Hz + ej] = acc;
    out[(size_t)Bz*Tz*Hz + (size_t)eb*Hz + ej]       = hT[(size_t)eb*Hz + ej];
    out[(size_t)Bz*Tz*Hz + HTB + (size_t)eb*Hz + ej] = cT[(size_t)eb*Hz + ej];
  }
}

extern "C" void kernel_launch(void* const* d_in, const int* in_sizes, int n_in,
                              void* d_out, int out_size, void* d_ws, size_t ws_size,
                              hipStream_t stream)
{
  const int*   src    = (const int*)  d_in[0];
  // d_in[1] = source_lengths (unused by reference)
  const float* emb    = (const float*)d_in[2];
  const float* w_ih   = (const float*)d_in[3];
  const float* w_hh   = (const float*)d_in[4];
  const float* b_lstm = (const float*)d_in[5];
  const float* w_xi   = (const float*)d_in[6];
  const float* b_xi   = (const float*)d_in[7];
  const float* w_out  = (const float*)d_in[8];
  const float* b_out  = (const float*)d_in[9];
  float* out = (float*)d_out;
  float* ws  = (float*)d_ws;

  hipMemsetAsync((char*)d_ws + (size_t)BAR_OFF*4, 0, 8192, stream);

  void* args[] = { &src, &emb, &w_ih, &w_hh, &b_lstm, &w_xi, &b_xi, &w_out, &b_out, &out, &ws };
  hipLaunchCooperativeKernel((const void*)dnc_kernel, dim3(NWG), dim3(NT), args, 0, stream);
}

// Round 19
// 11766.963 us; speedup vs baseline: 1.5460x; 1.2988x over previous
//
#include <hip/hip_runtime.h>

#define Bz 32
#define Tz 256
#define Hz 512
#define Nz 5
#define Rz 2
#define Wz 512
#define WP 520           // padded s_M row stride
#define RWz 1024
#define XD 1536          // H + R*W
#define GK 2048          // gates K (XD + Hz)
#define IFz 2573
#define EPSF 1e-6f
#define NWG 256
#define NT 1024
#define NTH (NWG*NT)     // 262144

#define HTB (Bz*Hz)      // 16384 floats per h buffer
#define RTB (Bz*RWz)     // 32768 floats per r buffer
#define BLS 2064         // per-batch LDS slab stride (2048 + 16 pad)

// workspace float offsets
#define WXIT_OFF (Tz*Bz*Hz)                            // 4194304 (now bf16 mirror of w_xi^T)
#define WOUT_OFF (WXIT_OFF + IFz*Hz)                   // 5511680 (now bf16 mirror of w_out^T)
#define HT_OFF   (WOUT_OFF + Hz*XD)                    // 6298112
#define CT_OFF   (HT_OFF + 2*HTB)                      // 6330880
#define RT_OFF   (CT_OFF + HTB)                        // 6347264
#define XIT_OFF  (RT_OFF + 2*RTB)                      // 6412800
#define MG_OFF   (XIT_OFF + IFz*Bz)                    // 6495136
#define UG_OFF   (MG_OFF + Bz*Nz*Wz)                   // 6577056
#define BAR_OFF  (UG_OFF + 1600 + 32)                  // 6578688 (64-aligned)
#define WBF_OFF  (BAR_OFF + 2048)                      // 6580736 (bf16 gates: 2048x2048 ushort)

// xi field offsets
#define O_KR 0
#define O_BR 1024
#define O_KW 1026
#define O_BW 1538
#define O_E  1539
#define O_V  2051
#define O_FG 2563
#define O_GA 2565
#define O_GW 2566
#define O_PI 2567

typedef unsigned long long u64;

__device__ __forceinline__ float sigf(float x){ return 1.0f/(1.0f+expf(-x)); }
__device__ __forceinline__ float splus(float x){ return fmaxf(x,0.0f) + log1pf(expf(-fabsf(x))); }
__device__ __forceinline__ unsigned short f2bf(float v){
  unsigned u = __float_as_uint(v);
  return (unsigned short)((u + 0x7FFFu + ((u >> 16) & 1u)) >> 16);
}

// coherent accessors (R12-proven)
__device__ __forceinline__ void stage64(float* dst_lds, const float* src){
  u64 v = __hip_atomic_load((const u64*)src, __ATOMIC_RELAXED, __HIP_MEMORY_SCOPE_AGENT);
  *(u64*)dst_lds = v;
}
__device__ __forceinline__ float ld32cv(const float* p){
  return __hip_atomic_load(p, __ATOMIC_RELAXED, __HIP_MEMORY_SCOPE_AGENT);
}
__device__ __forceinline__ void st32cv(float* p, float v){
  __hip_atomic_store(p, v, __ATOMIC_RELAXED, __HIP_MEMORY_SCOPE_AGENT);
}

// ---- grid barriers (verbatim from R12/R14 runs) ----
__device__ __forceinline__ void gbar_fence(unsigned* bar, unsigned k){
  __syncthreads();
  const int tid = threadIdx.x;
  const unsigned wg = blockIdx.x;
  if (tid == 0){
    __builtin_amdgcn_fence(__ATOMIC_RELEASE, "agent");
    __hip_atomic_fetch_add(&bar[(wg & 15u)*64], 1u, __ATOMIC_RELAXED, __HIP_MEMORY_SCOPE_AGENT);
  }
  if (wg == 0){
    if (tid < 16){
      const unsigned tgt = (NWG/16u)*(k+1u);
      while (__hip_atomic_load(&bar[tid*64], __ATOMIC_RELAXED, __HIP_MEMORY_SCOPE_AGENT) < tgt)
        __builtin_amdgcn_s_sleep(1);
    }
    __syncthreads();
    if (tid < 16){
      __builtin_amdgcn_fence(__ATOMIC_ACQ_REL, "agent");
      __hip_atomic_store(&bar[1024 + tid*64], k+1u, __ATOMIC_RELAXED, __HIP_MEMORY_SCOPE_AGENT);
    }
    __syncthreads();
  } else {
    if (tid == 0){
      while (__hip_atomic_load(&bar[1024 + (wg & 15u)*64], __ATOMIC_RELAXED, __HIP_MEMORY_SCOPE_AGENT) < k+1u)
        __builtin_amdgcn_s_sleep(1);
      __builtin_amdgcn_fence(__ATOMIC_ACQUIRE, "agent");
    }
    __syncthreads();
  }
}
__device__ __forceinline__ void gbar_nf(unsigned* bar, unsigned k){
  __syncthreads();
  const int tid = threadIdx.x;
  const unsigned wg = blockIdx.x;
  if (tid == 0){
    asm volatile("s_waitcnt vmcnt(0) lgkmcnt(0)" ::: "memory");
    __hip_atomic_fetch_add(&bar[(wg & 15u)*64], 1u, __ATOMIC_RELAXED, __HIP_MEMORY_SCOPE_AGENT);
  }
  if (wg == 0){
    if (tid < 16){
      const unsigned tgt = (NWG/16u)*(k+1u);
      while (__hip_atomic_load(&bar[tid*64], __ATOMIC_RELAXED, __HIP_MEMORY_SCOPE_AGENT) < tgt)
        __builtin_amdgcn_s_sleep(1);
    }
    __syncthreads();
    if (tid < 16)
      __hip_atomic_store(&bar[1024 + tid*64], k+1u, __ATOMIC_RELAXED, __HIP_MEMORY_SCOPE_AGENT);
    __syncthreads();
  } else {
    if (tid == 0){
      while (__hip_atomic_load(&bar[1024 + (wg & 15u)*64], __ATOMIC_RELAXED, __HIP_MEMORY_SCOPE_AGENT) < k+1u)
        __builtin_amdgcn_s_sleep(1);
    }
    __syncthreads();
  }
}

// strided fp32 dot
__device__ __forceinline__ float dotS(const float* x, const float* __restrict__ w,
                                      int iters, int strf){
  float a0=0.f,a1=0.f,a2=0.f,a3=0.f;
  #pragma unroll 16
  for (int i=0;i<iters;i++){
    float4 xv = *(const float4*)(x + (size_t)i*strf);
    float4 wv = *(const float4*)(w + (size_t)i*strf);
    a0=fmaf(xv.x,wv.x,a0); a1=fmaf(xv.y,wv.y,a1);
    a2=fmaf(xv.z,wv.z,a2); a3=fmaf(xv.w,wv.w,a3);
  }
  return (a0+a1)+(a2+a3);
}
// strided bf16-weight dot: x fp32, w bf16 (4 consecutive ushorts = one u64)
__device__ __forceinline__ float dotSbf(const float* x, const unsigned short* __restrict__ w,
                                        int iters, int strf){
  float a0=0.f,a1=0.f,a2=0.f,a3=0.f;
  #pragma unroll 16
  for (int i=0;i<iters;i++){
    float4 xv = *(const float4*)(x + (size_t)i*strf);
    u64 wb = *(const u64*)(w + (size_t)i*strf);
    float w0 = __uint_as_float((unsigned)( wb        & 0xFFFFu) << 16);
    float w1 = __uint_as_float((unsigned)((wb >> 16) & 0xFFFFu) << 16);
    float w2 = __uint_as_float((unsigned)((wb >> 32) & 0xFFFFu) << 16);
    float w3 = __uint_as_float((unsigned)((wb >> 48) & 0xFFFFu) << 16);
    a0=fmaf(xv.x,w0,a0); a1=fmaf(xv.y,w1,a1);
    a2=fmaf(xv.z,w2,a2); a3=fmaf(xv.w,w3,a3);
  }
  return (a0+a1)+(a2+a3);
}
// contiguous bf16-weight dot (epilogue)
__device__ __forceinline__ float dot4cbf(const float* __restrict__ x,
                                         const unsigned short* __restrict__ w, int n){
  float a0=0.f,a1=0.f,a2=0.f,a3=0.f;
  #pragma unroll 8
  for (int i=0;i<n/4;i++){
    float4 xv = *(const float4*)(x + i*4);
    u64 wb = *(const u64*)(w + i*4);
    float w0 = __uint_as_float((unsigned)( wb        & 0xFFFFu) << 16);
    float w1 = __uint_as_float((unsigned)((wb >> 16) & 0xFFFFu) << 16);
    float w2 = __uint_as_float((unsigned)((wb >> 32) & 0xFFFFu) << 16);
    float w3 = __uint_as_float((unsigned)((wb >> 48) & 0xFFFFu) << 16);
    a0=fmaf(xv.x,w0,a0); a1=fmaf(xv.y,w1,a1);
    a2=fmaf(xv.z,w2,a2); a3=fmaf(xv.w,w3,a3);
  }
  return (a0+a1)+(a2+a3);
}

__device__ void memops(int b, int t, const float* xiT,
                       float* Mg, float* ug, float* pg, float* wwg, float* Lg, float* wrg,
                       float* rT)
{
  __shared__ float s_xi[IFz];
  __shared__ float s_M[Nz*WP];
  __shared__ float s_u[Nz], s_p[Nz], s_ww[Nz], s_a[Nz], s_L[Nz*Nz], s_wr[Rz*Nz];
  __shared__ float s_sc[13];
  __shared__ float s_m2[Nz], s_dt[Nz], s_d0[Nz], s_d1[Nz];
  __shared__ float s_kw2, s_kr2[2];
  __shared__ float s_fwd[Rz*Nz], s_bwd[Rz*Nz];

  const int tid = threadIdx.x;
  const int wv = tid >> 6, ln = tid & 63;

  for (int f = tid; f < IFz; f += NT) s_xi[f] = ld32cv(&xiT[(size_t)b*IFz + f]);
  for (int i = tid; i < Nz*Wz; i += NT){
    int n = i >> 9, w = i & 511;
    s_M[n*WP+w] = Mg[(size_t)b*Nz*Wz + i];
  }
  if (tid < Nz){ s_u[tid]=ug[b*Nz+tid]; s_p[tid]=pg[b*Nz+tid]; s_ww[tid]=wwg[b*Nz+tid]; }
  if (tid < Nz*Nz) s_L[tid] = Lg[b*Nz*Nz+tid];
  if (tid < Rz*Nz) s_wr[tid] = wrg[b*Rz*Nz+tid];
  __syncthreads();

  if (tid == 0){
    s_sc[0] = 1.0f + splus(s_xi[O_BR+0]);
    s_sc[1] = 1.0f + splus(s_xi[O_BR+1]);
    s_sc[2] = 1.0f + splus(s_xi[O_BW]);
    s_sc[3] = sigf(s_xi[O_FG+0]);
    s_sc[4] = sigf(s_xi[O_FG+1]);
    s_sc[5] = sigf(s_xi[O_GA]);
    s_sc[6] = sigf(s_xi[O_GW]);
    for (int r=0;r<Rz;r++){
      float x0=s_xi[O_PI+r*3+0], x1=s_xi[O_PI+r*3+1], x2=s_xi[O_PI+r*3+2];
      float m = fmaxf(x0,fmaxf(x1,x2));
      float e0=expf(x0-m), e1=expf(x1-m), e2=expf(x2-m);
      float s = e0+e1+e2;
      s_sc[7+r*3+0]=e0/s; s_sc[7+r*3+1]=e1/s; s_sc[7+r*3+2]=e2/s;
    }
  }
  __syncthreads();

  if (tid < Nz){
    float psi = (1.0f - s_sc[3]*s_wr[0*Nz+tid]) * (1.0f - s_sc[4]*s_wr[1*Nz+tid]);
    float uu = s_u[tid], w = s_ww[tid];
    s_u[tid] = (uu + w - uu*w) * psi;
  }

  // cosine(M_old, kw)
  if (wv < 4){
    const int n = wv;
    float pd=0.f, pm=0.f;
    for (int w = ln; w < Wz; w += 64){
      float kv = s_xi[O_KW+w], mv = s_M[n*WP+w];
      pd = fmaf(kv,mv,pd); pm = fmaf(mv,mv,pm);
    }
    for (int off=32; off; off>>=1){ pd += __shfl_down(pd,off,64); pm += __shfl_down(pm,off,64); }
    if (ln==0){ s_dt[n]=pd; s_m2[n]=pm; }
  }
  if (wv == 3){
    float p2=0.f;
    for (int w=ln; w<Wz; w+=64){ float kv=s_xi[O_KW+w]; p2=fmaf(kv,kv,p2); }
    for (int off=32; off; off>>=1) p2 += __shfl_down(p2,off,64);
    if (ln==0) s_kw2 = p2;
  }
  __syncthreads();
  if (wv == 0){
    const int n = 4;
    float pd=0.f, pm=0.f;
    for (int w = ln; w < Wz; w += 64){
      float kv = s_xi[O_KW+w], mv = s_M[n*WP+w];
      pd = fmaf(kv,mv,pd); pm = fmaf(mv,mv,pm);
    }
    for (int off=32; off; off>>=1){ pd += __shfl_down(pd,off,64); pm += __shfl_down(pm,off,64); }
    if (ln==0){ s_dt[n]=pd; s_m2[n]=pm; }
  }
  __syncthreads();

  if (tid == 0){
    float su[Nz]; int idx[Nz];
    for (int i=0;i<Nz;i++){
      float v = EPSF + (1.0f-EPSF)*s_u[i];
      int j=i;
      while (j>0 && su[j-1] > v){ su[j]=su[j-1]; idx[j]=idx[j-1]; j--; }
      su[j]=v; idx[j]=i;
    }
    float cp = 1.0f;
    for (int k=0;k<Nz;k++){ s_a[idx[k]] = (1.0f - su[k])*cp; cp *= su[k]; }
    float rk = rsqrtf(s_kw2 + EPSF);
    float lg[Nz], mx=-1e30f;
    for (int n=0;n<Nz;n++){ lg[n] = s_sc[2]*s_dt[n]*rk*rsqrtf(s_m2[n]+EPSF); mx=fmaxf(mx,lg[n]); }
    float ssum=0.f;
    for (int n=0;n<Nz;n++){ lg[n]=expf(lg[n]-mx); ssum+=lg[n]; }
    float ga=s_sc[5], gw=s_sc[6];
    for (int n=0;n<Nz;n++){ float cwn = lg[n]/ssum; s_ww[n] = gw*(ga*s_a[n] + (1.0f-ga)*cwn); }
  }
  __syncthreads();

  for (int i = tid; i < Nz*Wz; i += NT){
    int n = i >> 9, w = i & 511;
    float e = sigf(s_xi[O_E+w]);
    float v = s_xi[O_V+w];
    s_M[n*WP+w] = s_M[n*WP+w]*(1.0f - s_ww[n]*e) + s_ww[n]*v;
  }
  __syncthreads();

  if (tid == 0){
    float wsum = 0.f;
    for (int n=0;n<Nz;n++) wsum += s_ww[n];
    float Lo[Nz*Nz];
    for (int i=0;i<Nz;i++)
      for (int j=0;j<Nz;j++)
        Lo[i*Nz+j] = (i==j) ? 0.0f : ((1.0f - s_ww[i] - s_ww[j])*s_L[i*Nz+j] + s_ww[i]*s_p[j]);
    for (int i=0;i<Nz*Nz;i++) s_L[i]=Lo[i];
    for (int j=0;j<Nz;j++) s_p[j] = (1.0f-wsum)*s_p[j] + s_ww[j];
    for (int r=0;r<Rz;r++)
      for (int n=0;n<Nz;n++){
        float f=0.f, bb=0.f;
        for (int m=0;m<Nz;m++){ f = fmaf(s_L[n*Nz+m], s_wr[r*Nz+m], f); bb = fmaf(s_L[m*Nz+n], s_wr[r*Nz+m], bb); }
        s_fwd[r*Nz+n]=f; s_bwd[r*Nz+n]=bb;
      }
  }
  __syncthreads();

  // cosine(M_new, kr)
  if (wv < 4){
    const int n = wv;
    float pm=0.f,p0=0.f,p1=0.f;
    for (int w=ln; w<Wz; w+=64){
      float mv=s_M[n*WP+w];
      pm=fmaf(mv,mv,pm);
      p0=fmaf(s_xi[O_KR+w],    mv,p0);
      p1=fmaf(s_xi[O_KR+Wz+w], mv,p1);
    }
    for (int off=32; off; off>>=1){
      pm += __shfl_down(pm,off,64); p0 += __shfl_down(p0,off,64); p1 += __shfl_down(p1,off,64);
    }
    if (ln==0){ s_m2[n]=pm; s_d0[n]=p0; s_d1[n]=p1; }
  }
  __syncthreads();
  if (wv == 0){
    const int n = 4;
    float pm=0.f,p0=0.f,p1=0.f;
    for (int w=ln; w<Wz; w+=64){
      float mv=s_M[n*WP+w];
      pm=fmaf(mv,mv,pm);
      p0=fmaf(s_xi[O_KR+w],    mv,p0);
      p1=fmaf(s_xi[O_KR+Wz+w], mv,p1);
    }
    for (int off=32; off; off>>=1){
      pm += __shfl_down(pm,off,64); p0 += __shfl_down(p0,off,64); p1 += __shfl_down(p1,off,64);
    }
    if (ln==0){ s_m2[n]=pm; s_d0[n]=p0; s_d1[n]=p1; }
  } else if (wv == 1 || wv == 2){
    const int r = wv - 1;
    float p2=0.f;
    for (int w=ln; w<Wz; w+=64){ float kv=s_xi[O_KR+r*Wz+w]; p2=fmaf(kv,kv,p2); }
    for (int off=32; off; off>>=1) p2 += __shfl_down(p2,off,64);
    if (ln==0) s_kr2[r]=p2;
  }
  __syncthreads();

  if (tid == 0){
    for (int r=0;r<Rz;r++){
      float rk = rsqrtf(s_kr2[r]+EPSF);
      const float* dd = (r==0) ? s_d0 : s_d1;
      float br = s_sc[r];
      float lg[Nz], mx=-1e30f;
      for (int n=0;n<Nz;n++){ lg[n] = br*dd[n]*rk*rsqrtf(s_m2[n]+EPSF); mx=fmaxf(mx,lg[n]); }
      float ssum=0.f;
      for (int n=0;n<Nz;n++){ lg[n]=expf(lg[n]-mx); ssum+=lg[n]; }
      for (int n=0;n<Nz;n++){
        float crn = lg[n]/ssum;
        s_wr[r*Nz+n] = s_sc[7+r*3+0]*s_bwd[r*Nz+n] + s_sc[7+r*3+1]*crn + s_sc[7+r*3+2]*s_fwd[r*Nz+n];
      }
    }
  }
  __syncthreads();

  // read vectors -> rT[nxt][b][r*512+w] (coherent) + private state (cached)
  float* rdst = rT + (size_t)((t+1)&1)*RTB + (size_t)b*RWz;
  for (int w = tid; w < Wz; w += NT){
    float m0=s_M[0*WP+w], m1=s_M[1*WP+w], m2=s_M[2*WP+w], m3=s_M[3*WP+w], m4=s_M[4*WP+w];
    #pragma unroll
    for (int r=0;r<Rz;r++){
      float rv = s_wr[r*Nz+0]*m0 + s_wr[r*Nz+1]*m1 + s_wr[r*Nz+2]*m2
               + s_wr[r*Nz+3]*m3 + s_wr[r*Nz+4]*m4;
      st32cv(&rdst[r*Wz + w], rv);
    }
  }
  for (int i = tid; i < Nz*Wz; i += NT){
    int n = i >> 9, w = i & 511;
    Mg[(size_t)b*Nz*Wz+i] = s_M[n*WP+w];
  }
  if (tid < Nz){ ug[b*Nz+tid]=s_u[tid]; pg[b*Nz+tid]=s_p[tid]; wwg[b*Nz+tid]=s_ww[tid]; }
  if (tid < Nz*Nz) Lg[b*Nz*Nz+tid]=s_L[tid];
  if (tid < Rz*Nz) wrg[b*Rz*Nz+tid]=s_wr[tid];
}

__global__ void __launch_bounds__(NT, 4)
dnc_kernel(const int* __restrict__ src, const float* __restrict__ emb,
           const float* __restrict__ w_ih, const float* __restrict__ w_hh,
           const float* __restrict__ b_lstm,
           const float* __restrict__ w_xi, const float* __restrict__ b_xi,
           const float* __restrict__ w_out, const float* __restrict__ b_out,
           float* __restrict__ out, float* __restrict__ ws)
{
  __shared__ __align__(16) float s_x[4112];   // 2 batches x 2048, stride BLS=2064

  const int tid = threadIdx.x;
  const int gid = blockIdx.x*NT + tid;

  float* embT  = ws;                       // [T][B][512]   cached RO
  float* hT    = ws + HT_OFF;              // [2][B][512]   coherent
  float* cT    = ws + CT_OFF;              // [B][512]      cached, WG-pinned
  float* rT    = ws + RT_OFF;              // [2][B][1024]  coherent
  float* xiT   = ws + XIT_OFF;             // [B][IFz]      coherent
  float* Mg    = ws + MG_OFF;              // [B][2560]     cached, WG-pinned
  float* ug    = ws + UG_OFF;
  float* pg    = ug + Bz*Nz;
  float* wwg   = pg + Bz*Nz;
  float* Lg    = wwg + Bz*Nz;
  float* wrg   = Lg + Bz*Nz*Nz;
  unsigned* bar = (unsigned*)(ws + BAR_OFF);
  unsigned short* wbf   = (unsigned short*)(ws + WBF_OFF);   // [2048][2048] bf16 [w_ih|w_hh]
  unsigned short* wxibf = (unsigned short*)(ws + WXIT_OFF);  // [IFz][512]   bf16 w_xi^T
  unsigned short* wobf  = (unsigned short*)(ws + WOUT_OFF);  // [512][1536]  bf16 w_out^T
  unsigned kbar = 0;

  // ---- init ----
  {
    float4* embT4 = (float4*)embT;
    const float4* emb4 = (const float4*)emb;
    for (int i = gid; i < Tz*Bz*128; i += NTH){
      int kg = i & 127, b = (i>>7) & 31, tt = i >> 12;
      embT4[i] = emb4[(size_t)src[b*Tz+tt]*128 + kg];
    }
  }
  for (int i = gid; i < IFz*Hz; i += NTH){           // wxibf[f][k] = bf16(w_xi[k][f])
    int f = i >> 9, k = i & 511;
    wxibf[i] = f2bf(w_xi[(size_t)k*IFz + f]);
  }
  for (int i = gid; i < Hz*XD; i += NTH){            // wobf[j][k] = bf16(w_out[k][j])
    int j = i / XD, k = i - j*XD;
    wobf[i] = f2bf(w_out[(size_t)k*Hz + j]);
  }
  for (int i = gid; i < GK*GK; i += NTH){            // wbf[row][k] = bf16([w_ih|w_hh])
    int row = i >> 11, k = i & 2047;
    float v = (k < XD) ? w_ih[(size_t)row*XD + k] : w_hh[(size_t)row*Hz + (k - XD)];
    wbf[i] = f2bf(v);
  }
  for (int i = gid; i < 2*HTB; i += NTH) hT[i]=0.f;
  for (int i = gid; i < HTB;   i += NTH) cT[i]=0.f;
  for (int i = gid; i < 2*RTB; i += NTH) rT[i]=0.f;
  for (int i = gid; i < Bz*Nz*Wz;i += NTH) Mg[i]=0.f;
  for (int i = gid; i < Bz*(3*Nz + Nz*Nz + Rz*Nz); i += NTH) ug[i]=0.f;
  gbar_fence(bar, kbar); kbar++;

  // WG decomposition: jc (XCD pin) x sj (j-half) x bp (batch pair)
  const int jc = blockIdx.x & 7;          // 0..7
  const int sj = (blockIdx.x >> 3) & 1;   // 0..1
  const int bp = blockIdx.x >> 4;         // 0..15
  const int b0 = 2*bp;                    // batches b0, b0+1
  const int jbase = jc*64 + sj*32;        // 32 j-rows per WG

  // ---- time loop (no agent fences inside) ----
  for (int t = 0; t < Tz; ++t){
    const int cur = t & 1, nxt = (t+1)&1;

    // ===== Phase A: gates GEMV (bf16 W) + fused out(t-1) (bf16 W), 2 batches =====
    {
      for (int u = tid; u < 1792; u += NT){
        const int bl = (u >= 896) ? 1 : 0;
        const int v  = u - bl*896;
        const int b  = b0 + bl;
        float* dst = s_x + bl*BLS;
        if (v < 256)
          stage64(dst + 1536 + v*2, hT + (size_t)cur*HTB + (size_t)b*Hz + v*2);
        else if (v < 768)
          stage64(dst + 512 + (v-256)*2, rT + (size_t)cur*RTB + (size_t)b*RWz + (v-256)*2);
        else
          *(float4*)(dst + (v-768)*4) =
            *(const float4*)(embT + ((size_t)t*Bz + b)*Hz + (v-768)*4);
      }
      __syncthreads();

      // gates: tid = jj(5b) | bl(1b) | gate(2b) | ks(2b)
      {
        const int ks   = tid & 3;
        const int gate = (tid >> 2) & 3;
        const int bl   = (tid >> 4) & 1;
        const int jj   = tid >> 5;         // 0..31
        const int j    = jbase + jj;
        const int row  = gate*Hz + j;
        const float* xb = s_x + bl*BLS;
        float acc = dotSbf(xb + ks*4, wbf + (size_t)row*GK + ks*4, 128, 16);
        acc += __shfl_xor(acc, 1, 64);
        acc += __shfl_xor(acc, 2, 64);
        acc += b_lstm[row];
        const int lane = tid & 63;
        const int base = lane & ~12;       // zero gate bits [2:3]
        float gi = __shfl(acc, base+0,  64);
        float gf = __shfl(acc, base+4,  64);
        float gg = __shfl(acc, base+8,  64);
        float go = __shfl(acc, base+12, 64);
        if ((lane & 15) == 0){             // ks==0 && gate==0
          const int b = b0 + bl;
          float cv = cT[(size_t)b*Hz + j];
          float cn = sigf(gf)*cv + sigf(gi)*tanhf(gg);
          float hn = sigf(go)*tanhf(cn);
          cT[(size_t)b*Hz + j] = cn;
          st32cv(&hT[(size_t)nxt*HTB + (size_t)b*Hz + j], hn);
        }
      }

      // fused out(t-1): tid = ojj(5b) | bl(1b) | oks(4b); [h|r]·wout bf16, strided-16
      if (t > 0){
        const int oks = tid & 15;
        const int bl  = (tid >> 4) & 1;
        const int ojj = tid >> 5;          // 0..31
        const int oj  = jbase + ojj;
        const float* xb = s_x + bl*BLS;
        const unsigned short* wo = wobf + (size_t)oj*XD + oks*4;
        const float* xh = xb + 1536 + oks*4;   // logical k<512 -> h
        const float* xr = xb + oks*4;          // logical k in [512,1536): s_x[k] = r
        float a0=0.f,a1=0.f,a2=0.f,a3=0.f;
        #pragma unroll 8
        for (int i=0;i<8;i++){
          float4 xv = *(const float4*)(xh + i*64);
          u64 wb = *(const u64*)(wo + i*64);
          float w0 = __uint_as_float((unsigned)( wb        & 0xFFFFu) << 16);
          float w1 = __uint_as_float((unsigned)((wb >> 16) & 0xFFFFu) << 16);
          float w2 = __uint_as_float((unsigned)((wb >> 32) & 0xFFFFu) << 16);
          float w3 = __uint_as_float((unsigned)((wb >> 48) & 0xFFFFu) << 16);
          a0=fmaf(xv.x,w0,a0); a1=fmaf(xv.y,w1,a1);
          a2=fmaf(xv.z,w2,a2); a3=fmaf(xv.w,w3,a3);
        }
        #pragma unroll 16
        for (int i=8;i<24;i++){
          float4 xv = *(const float4*)(xr + i*64);
          u64 wb = *(const u64*)(wo + i*64);
          float w0 = __uint_as_float((unsigned)( wb        & 0xFFFFu) << 16);
          float w1 = __uint_as_float((unsigned)((wb >> 16) & 0xFFFFu) << 16);
          float w2 = __uint_as_float((unsigned)((wb >> 32) & 0xFFFFu) << 16);
          float w3 = __uint_as_float((unsigned)((wb >> 48) & 0xFFFFu) << 16);
          a0=fmaf(xv.x,w0,a0); a1=fmaf(xv.y,w1,a1);
          a2=fmaf(xv.z,w2,a2); a3=fmaf(xv.w,w3,a3);
        }
        float oa = (a0+a1)+(a2+a3);
        oa += __shfl_xor(oa, 1, 64);
        oa += __shfl_xor(oa, 2, 64);
        oa += __shfl_xor(oa, 4, 64);
        oa += __shfl_xor(oa, 8, 64);
        if (oks == 0)
          out[(size_t)(b0+bl)*Tz*Hz + (size_t)(t-1)*Hz + oj] = oa + b_out[oj];
      }
    }
    gbar_nf(bar, kbar); kbar++;

    // ===== Phase B: xi = h_new @ w_xi (bf16 W, strided ks-4), 2 batches =====
    {
      if (tid < 512){
        const int bl = tid >> 8, v = tid & 255;
        stage64(s_x + bl*BLS + v*2, hT + (size_t)nxt*HTB + (size_t)(b0+bl)*Hz + v*2);
      }
      __syncthreads();
      const int ks  = tid & 3;
      const int bl  = (tid >> 2) & 1;
      const int fi0 = tid >> 3;            // 0..127
      #pragma unroll
      for (int round = 0; round < 2; ++round){
        int fi = round*128 + fi0;          // 0..255 (need 0..160)
        int f  = jc*322 + sj*161 + fi;
        bool ok = (fi < 161) && (f < IFz);
        int fr = ok ? f : 0;
        float acc = dotSbf(s_x + bl*BLS + ks*4, wxibf + (size_t)fr*Hz + ks*4, 32, 16);
        acc += __shfl_xor(acc, 1, 64);
        acc += __shfl_xor(acc, 2, 64);
        if (ok && ks == 0)
          st32cv(&xiT[(size_t)(b0+bl)*IFz + f], acc + b_xi[f]);
      }
    }
    gbar_nf(bar, kbar); kbar++;

    // ===== Phase C: memops only (one WG per batch, XCD-spread) =====
    {
      const int bA = b0;
      const int bB = b0 + 1;
      if (sj == 0 && jc == (bA & 7))
        memops(bA, t, xiT, Mg, ug, pg, wwg, Lg, wrg, rT);
      else if (sj == 1 && jc == (bB & 7))
        memops(bB, t, xiT, Mg, ug, pg, wwg, Lg, wrg, rT);
    }
    gbar_nf(bar, kbar); kbar++;
  }

  gbar_fence(bar, kbar); kbar++;   // make coherent state + private cT cache-readable

  // ---- epilogue: out(T-1), final h, c (state in buffer 0) ----
  if (gid < Bz*Hz){
    const int eb = gid >> 9, ej = gid & 511;
    const unsigned short* wj = wobf + (size_t)ej*XD;
    float acc = dot4cbf(hT + (size_t)eb*Hz,  wj,       512)
              + dot4cbf(rT + (size_t)eb*RWz, wj + 512, 1024)
              + b_out[ej];
    out[(size_t)eb*Tz*Hz + (size_t)(Tz-1)*Hz + ej] = acc;
    out[(size_t)Bz*Tz*Hz + (size_t)eb*Hz + ej]       = hT[(size_t)eb*Hz + ej];
    out[(size_t)Bz*Tz*Hz + HTB + (size_t)eb*Hz + ej] = cT[(size_t)eb*Hz + ej];
  }
}

extern "C" void kernel_launch(void* const* d_in, const int* in_sizes, int n_in,
                              void* d_out, int out_size, void* d_ws, size_t ws_size,
                              hipStream_t stream)
{
  const int*   src    = (const int*)  d_in[0];
  // d_in[1] = source_lengths (unused by reference)
  const float* emb    = (const float*)d_in[2];
  const float* w_ih   = (const float*)d_in[3];
  const float* w_hh   = (const float*)d_in[4];
  const float* b_lstm = (const float*)d_in[5];
  const float* w_xi   = (const float*)d_in[6];
  const float* b_xi   = (const float*)d_in[7];
  const float* w_out  = (const float*)d_in[8];
  const float* b_out  = (const float*)d_in[9];
  float* out = (float*)d_out;
  float* ws  = (float*)d_ws;

  hipMemsetAsync((char*)d_ws + (size_t)BAR_OFF*4, 0, 8192, stream);

  void* args[] = { &src, &emb, &w_ih, &w_hh, &b_lstm, &w_xi, &b_xi, &w_out, &b_out, &out, &ws };
  hipLaunchCooperativeKernel((const void*)dnc_kernel, dim3(NWG), dim3(NT), args, 0, stream);
}

// Round 20
// 11180.062 us; speedup vs baseline: 1.6271x; 1.0525x over previous
//
#include <hip/hip_runtime.h>

#define Bz 32
#define Tz 256
#define Hz 512
#define Nz 5
#define Rz 2
#define Wz 512
#define WP 520           // padded s_M row stride
#define RWz 1024
#define XD 1536          // H + R*W
#define GK 2048          // gates K (XD + Hz)
#define IFz 2573
#define EPSF 1e-6f
#define NWG 256
#define NT 1024
#define NTH (NWG*NT)     // 262144

#define HTB (Bz*Hz)      // 16384 floats per h buffer
#define RTB (Bz*RWz)     // 32768 floats per r buffer
#define BLS 2064         // per-batch LDS slab stride (2048 + 16 pad)

// workspace float offsets
#define WXIT_OFF (Tz*Bz*Hz)                            // 4194304 (bf16 mirror of w_xi^T)
#define WOUT_OFF (WXIT_OFF + IFz*Hz)                   // 5511680 (bf16 mirror of w_out^T)
#define HT_OFF   (WOUT_OFF + Hz*XD)                    // 6298112
#define CT_OFF   (HT_OFF + 2*HTB)                      // 6330880
#define RT_OFF   (CT_OFF + HTB)                        // 6347264
#define XIT_OFF  (RT_OFF + 2*RTB)                      // 6412800
#define MG_OFF   (XIT_OFF + IFz*Bz)                    // 6495136
#define UG_OFF   (MG_OFF + Bz*Nz*Wz)                   // 6577056
#define BAR_OFF  (UG_OFF + 1600 + 32)                  // 6578688 (64-aligned)
#define WBF_OFF  (BAR_OFF + 2048)                      // 6580736 (bf16 gates: 2048x2048 ushort)

// xi field offsets
#define O_KR 0
#define O_BR 1024
#define O_KW 1026
#define O_BW 1538
#define O_E  1539
#define O_V  2051
#define O_FG 2563
#define O_GA 2565
#define O_GW 2566
#define O_PI 2567

typedef unsigned long long u64;

__device__ __forceinline__ float sigf(float x){ return 1.0f/(1.0f+expf(-x)); }
__device__ __forceinline__ float splus(float x){ return fmaxf(x,0.0f) + log1pf(expf(-fabsf(x))); }
__device__ __forceinline__ unsigned short f2bf(float v){
  unsigned u = __float_as_uint(v);
  return (unsigned short)((u + 0x7FFFu + ((u >> 16) & 1u)) >> 16);
}
// cheap exact unpack: 4 bf16 weights from one u64, 1 op each
__device__ __forceinline__ void bf4(u64 wb, float& w0, float& w1, float& w2, float& w3){
  unsigned lo = (unsigned)wb, hi = (unsigned)(wb >> 32);
  w0 = __uint_as_float(lo << 16);
  w1 = __uint_as_float(lo & 0xFFFF0000u);
  w2 = __uint_as_float(hi << 16);
  w3 = __uint_as_float(hi & 0xFFFF0000u);
}

// coherent accessors (R12-proven)
__device__ __forceinline__ void stage64(float* dst_lds, const float* src){
  u64 v = __hip_atomic_load((const u64*)src, __ATOMIC_RELAXED, __HIP_MEMORY_SCOPE_AGENT);
  *(u64*)dst_lds = v;
}
__device__ __forceinline__ float ld32cv(const float* p){
  return __hip_atomic_load(p, __ATOMIC_RELAXED, __HIP_MEMORY_SCOPE_AGENT);
}
__device__ __forceinline__ void st32cv(float* p, float v){
  __hip_atomic_store(p, v, __ATOMIC_RELAXED, __HIP_MEMORY_SCOPE_AGENT);
}

// ---- grid barriers (verbatim from R12/R14/R18 runs) ----
__device__ __forceinline__ void gbar_fence(unsigned* bar, unsigned k){
  __syncthreads();
  const int tid = threadIdx.x;
  const unsigned wg = blockIdx.x;
  if (tid == 0){
    __builtin_amdgcn_fence(__ATOMIC_RELEASE, "agent");
    __hip_atomic_fetch_add(&bar[(wg & 15u)*64], 1u, __ATOMIC_RELAXED, __HIP_MEMORY_SCOPE_AGENT);
  }
  if (wg == 0){
    if (tid < 16){
      const unsigned tgt = (NWG/16u)*(k+1u);
      while (__hip_atomic_load(&bar[tid*64], __ATOMIC_RELAXED, __HIP_MEMORY_SCOPE_AGENT) < tgt)
        __builtin_amdgcn_s_sleep(1);
    }
    __syncthreads();
    if (tid < 16){
      __builtin_amdgcn_fence(__ATOMIC_ACQ_REL, "agent");
      __hip_atomic_store(&bar[1024 + tid*64], k+1u, __ATOMIC_RELAXED, __HIP_MEMORY_SCOPE_AGENT);
    }
    __syncthreads();
  } else {
    if (tid == 0){
      while (__hip_atomic_load(&bar[1024 + (wg & 15u)*64], __ATOMIC_RELAXED, __HIP_MEMORY_SCOPE_AGENT) < k+1u)
        __builtin_amdgcn_s_sleep(1);
      __builtin_amdgcn_fence(__ATOMIC_ACQUIRE, "agent");
    }
    __syncthreads();
  }
}
__device__ __forceinline__ void gbar_nf(unsigned* bar, unsigned k){
  __syncthreads();
  const int tid = threadIdx.x;
  const unsigned wg = blockIdx.x;
  if (tid == 0){
    asm volatile("s_waitcnt vmcnt(0) lgkmcnt(0)" ::: "memory");
    __hip_atomic_fetch_add(&bar[(wg & 15u)*64], 1u, __ATOMIC_RELAXED, __HIP_MEMORY_SCOPE_AGENT);
  }
  if (wg == 0){
    if (tid < 16){
      const unsigned tgt = (NWG/16u)*(k+1u);
      while (__hip_atomic_load(&bar[tid*64], __ATOMIC_RELAXED, __HIP_MEMORY_SCOPE_AGENT) < tgt)
        __builtin_amdgcn_s_sleep(1);
    }
    __syncthreads();
    if (tid < 16)
      __hip_atomic_store(&bar[1024 + tid*64], k+1u, __ATOMIC_RELAXED, __HIP_MEMORY_SCOPE_AGENT);
    __syncthreads();
  } else {
    if (tid == 0){
      while (__hip_atomic_load(&bar[1024 + (wg & 15u)*64], __ATOMIC_RELAXED, __HIP_MEMORY_SCOPE_AGENT) < k+1u)
        __builtin_amdgcn_s_sleep(1);
    }
    __syncthreads();
  }
}

// strided bf16-weight dot
__device__ __forceinline__ float dotSbf(const float* x, const unsigned short* __restrict__ w,
                                        int iters, int strf){
  float a0=0.f,a1=0.f,a2=0.f,a3=0.f;
  #pragma unroll 16
  for (int i=0;i<iters;i++){
    float4 xv = *(const float4*)(x + (size_t)i*strf);
    float w0,w1,w2,w3; bf4(*(const u64*)(w + (size_t)i*strf), w0,w1,w2,w3);
    a0=fmaf(xv.x,w0,a0); a1=fmaf(xv.y,w1,a1);
    a2=fmaf(xv.z,w2,a2); a3=fmaf(xv.w,w3,a3);
  }
  return (a0+a1)+(a2+a3);
}
// contiguous bf16-weight dot (epilogue)
__device__ __forceinline__ float dot4cbf(const float* __restrict__ x,
                                         const unsigned short* __restrict__ w, int n){
  float a0=0.f,a1=0.f,a2=0.f,a3=0.f;
  #pragma unroll 8
  for (int i=0;i<n/4;i++){
    float4 xv = *(const float4*)(x + i*4);
    float w0,w1,w2,w3; bf4(*(const u64*)(w + i*4), w0,w1,w2,w3);
    a0=fmaf(xv.x,w0,a0); a1=fmaf(xv.y,w1,a1);
    a2=fmaf(xv.z,w2,a2); a3=fmaf(xv.w,w3,a3);
  }
  return (a0+a1)+(a2+a3);
}

__device__ void memops(int b, int t, const float* xiT,
                       float* Mg, float* ug, float* pg, float* wwg, float* Lg, float* wrg,
                       float* rT)
{
  __shared__ float s_xi[IFz];
  __shared__ float s_M[Nz*WP];
  __shared__ float s_u[Nz], s_p[Nz], s_ww[Nz], s_a[Nz], s_L[Nz*Nz], s_wr[Rz*Nz];
  __shared__ float s_sc[13];
  __shared__ float s_m2[Nz], s_dt[Nz], s_d0[Nz], s_d1[Nz];
  __shared__ float s_kw2, s_kr2[2];
  __shared__ float s_fwd[Rz*Nz], s_bwd[Rz*Nz];

  const int tid = threadIdx.x;
  const int wv = tid >> 6, ln = tid & 63;

  for (int f = tid; f < IFz; f += NT) s_xi[f] = ld32cv(&xiT[(size_t)b*IFz + f]);
  for (int i = tid; i < Nz*Wz; i += NT){
    int n = i >> 9, w = i & 511;
    s_M[n*WP+w] = Mg[(size_t)b*Nz*Wz + i];
  }
  if (tid < Nz){ s_u[tid]=ug[b*Nz+tid]; s_p[tid]=pg[b*Nz+tid]; s_ww[tid]=wwg[b*Nz+tid]; }
  if (tid < Nz*Nz) s_L[tid] = Lg[b*Nz*Nz+tid];
  if (tid < Rz*Nz) s_wr[tid] = wrg[b*Rz*Nz+tid];
  __syncthreads();

  if (tid == 0){
    s_sc[0] = 1.0f + splus(s_xi[O_BR+0]);
    s_sc[1] = 1.0f + splus(s_xi[O_BR+1]);
    s_sc[2] = 1.0f + splus(s_xi[O_BW]);
    s_sc[3] = sigf(s_xi[O_FG+0]);
    s_sc[4] = sigf(s_xi[O_FG+1]);
    s_sc[5] = sigf(s_xi[O_GA]);
    s_sc[6] = sigf(s_xi[O_GW]);
    for (int r=0;r<Rz;r++){
      float x0=s_xi[O_PI+r*3+0], x1=s_xi[O_PI+r*3+1], x2=s_xi[O_PI+r*3+2];
      float m = fmaxf(x0,fmaxf(x1,x2));
      float e0=expf(x0-m), e1=expf(x1-m), e2=expf(x2-m);
      float s = e0+e1+e2;
      s_sc[7+r*3+0]=e0/s; s_sc[7+r*3+1]=e1/s; s_sc[7+r*3+2]=e2/s;
    }
  }
  __syncthreads();

  if (tid < Nz){
    float psi = (1.0f - s_sc[3]*s_wr[0*Nz+tid]) * (1.0f - s_sc[4]*s_wr[1*Nz+tid]);
    float uu = s_u[tid], w = s_ww[tid];
    s_u[tid] = (uu + w - uu*w) * psi;
  }

  // cosine(M_old, kw)
  if (wv < 4){
    const int n = wv;
    float pd=0.f, pm=0.f;
    for (int w = ln; w < Wz; w += 64){
      float kv = s_xi[O_KW+w], mv = s_M[n*WP+w];
      pd = fmaf(kv,mv,pd); pm = fmaf(mv,mv,pm);
    }
    for (int off=32; off; off>>=1){ pd += __shfl_down(pd,off,64); pm += __shfl_down(pm,off,64); }
    if (ln==0){ s_dt[n]=pd; s_m2[n]=pm; }
  }
  if (wv == 3){
    float p2=0.f;
    for (int w=ln; w<Wz; w+=64){ float kv=s_xi[O_KW+w]; p2=fmaf(kv,kv,p2); }
    for (int off=32; off; off>>=1) p2 += __shfl_down(p2,off,64);
    if (ln==0) s_kw2 = p2;
  }
  __syncthreads();
  if (wv == 0){
    const int n = 4;
    float pd=0.f, pm=0.f;
    for (int w = ln; w < Wz; w += 64){
      float kv = s_xi[O_KW+w], mv = s_M[n*WP+w];
      pd = fmaf(kv,mv,pd); pm = fmaf(mv,mv,pm);
    }
    for (int off=32; off; off>>=1){ pd += __shfl_down(pd,off,64); pm += __shfl_down(pm,off,64); }
    if (ln==0){ s_dt[n]=pd; s_m2[n]=pm; }
  }
  __syncthreads();

  if (tid == 0){
    float su[Nz]; int idx[Nz];
    for (int i=0;i<Nz;i++){
      float v = EPSF + (1.0f-EPSF)*s_u[i];
      int j=i;
      while (j>0 && su[j-1] > v){ su[j]=su[j-1]; idx[j]=idx[j-1]; j--; }
      su[j]=v; idx[j]=i;
    }
    float cp = 1.0f;
    for (int k=0;k<Nz;k++){ s_a[idx[k]] = (1.0f - su[k])*cp; cp *= su[k]; }
    float rk = rsqrtf(s_kw2 + EPSF);
    float lg[Nz], mx=-1e30f;
    for (int n=0;n<Nz;n++){ lg[n] = s_sc[2]*s_dt[n]*rk*rsqrtf(s_m2[n]+EPSF); mx=fmaxf(mx,lg[n]); }
    float ssum=0.f;
    for (int n=0;n<Nz;n++){ lg[n]=expf(lg[n]-mx); ssum+=lg[n]; }
    float ga=s_sc[5], gw=s_sc[6];
    for (int n=0;n<Nz;n++){ float cwn = lg[n]/ssum; s_ww[n] = gw*(ga*s_a[n] + (1.0f-ga)*cwn); }
  }
  __syncthreads();

  for (int i = tid; i < Nz*Wz; i += NT){
    int n = i >> 9, w = i & 511;
    float e = sigf(s_xi[O_E+w]);
    float v = s_xi[O_V+w];
    s_M[n*WP+w] = s_M[n*WP+w]*(1.0f - s_ww[n]*e) + s_ww[n]*v;
  }
  __syncthreads();

  if (tid == 0){
    float wsum = 0.f;
    for (int n=0;n<Nz;n++) wsum += s_ww[n];
    float Lo[Nz*Nz];
    for (int i=0;i<Nz;i++)
      for (int j=0;j<Nz;j++)
        Lo[i*Nz+j] = (i==j) ? 0.0f : ((1.0f - s_ww[i] - s_ww[j])*s_L[i*Nz+j] + s_ww[i]*s_p[j]);
    for (int i=0;i<Nz*Nz;i++) s_L[i]=Lo[i];
    for (int j=0;j<Nz;j++) s_p[j] = (1.0f-wsum)*s_p[j] + s_ww[j];
    for (int r=0;r<Rz;r++)
      for (int n=0;n<Nz;n++){
        float f=0.f, bb=0.f;
        for (int m=0;m<Nz;m++){ f = fmaf(s_L[n*Nz+m], s_wr[r*Nz+m], f); bb = fmaf(s_L[m*Nz+n], s_wr[r*Nz+m], bb); }
        s_fwd[r*Nz+n]=f; s_bwd[r*Nz+n]=bb;
      }
  }
  __syncthreads();

  // cosine(M_new, kr)
  if (wv < 4){
    const int n = wv;
    float pm=0.f,p0=0.f,p1=0.f;
    for (int w=ln; w<Wz; w+=64){
      float mv=s_M[n*WP+w];
      pm=fmaf(mv,mv,pm);
      p0=fmaf(s_xi[O_KR+w],    mv,p0);
      p1=fmaf(s_xi[O_KR+Wz+w], mv,p1);
    }
    for (int off=32; off; off>>=1){
      pm += __shfl_down(pm,off,64); p0 += __shfl_down(p0,off,64); p1 += __shfl_down(p1,off,64);
    }
    if (ln==0){ s_m2[n]=pm; s_d0[n]=p0; s_d1[n]=p1; }
  }
  __syncthreads();
  if (wv == 0){
    const int n = 4;
    float pm=0.f,p0=0.f,p1=0.f;
    for (int w=ln; w<Wz; w+=64){
      float mv=s_M[n*WP+w];
      pm=fmaf(mv,mv,pm);
      p0=fmaf(s_xi[O_KR+w],    mv,p0);
      p1=fmaf(s_xi[O_KR+Wz+w], mv,p1);
    }
    for (int off=32; off; off>>=1){
      pm += __shfl_down(pm,off,64); p0 += __shfl_down(p0,off,64); p1 += __shfl_down(p1,off,64);
    }
    if (ln==0){ s_m2[n]=pm; s_d0[n]=p0; s_d1[n]=p1; }
  } else if (wv == 1 || wv == 2){
    const int r = wv - 1;
    float p2=0.f;
    for (int w=ln; w<Wz; w+=64){ float kv=s_xi[O_KR+r*Wz+w]; p2=fmaf(kv,kv,p2); }
    for (int off=32; off; off>>=1) p2 += __shfl_down(p2,off,64);
    if (ln==0) s_kr2[r]=p2;
  }
  __syncthreads();

  if (tid == 0){
    for (int r=0;r<Rz;r++){
      float rk = rsqrtf(s_kr2[r]+EPSF);
      const float* dd = (r==0) ? s_d0 : s_d1;
      float br = s_sc[r];
      float lg[Nz], mx=-1e30f;
      for (int n=0;n<Nz;n++){ lg[n] = br*dd[n]*rk*rsqrtf(s_m2[n]+EPSF); mx=fmaxf(mx,lg[n]); }
      float ssum=0.f;
      for (int n=0;n<Nz;n++){ lg[n]=expf(lg[n]-mx); ssum+=lg[n]; }
      for (int n=0;n<Nz;n++){
        float crn = lg[n]/ssum;
        s_wr[r*Nz+n] = s_sc[7+r*3+0]*s_bwd[r*Nz+n] + s_sc[7+r*3+1]*crn + s_sc[7+r*3+2]*s_fwd[r*Nz+n];
      }
    }
  }
  __syncthreads();

  // read vectors -> rT[nxt][b][r*512+w] (coherent) + private state (cached)
  float* rdst = rT + (size_t)((t+1)&1)*RTB + (size_t)b*RWz;
  for (int w = tid; w < Wz; w += NT){
    float m0=s_M[0*WP+w], m1=s_M[1*WP+w], m2=s_M[2*WP+w], m3=s_M[3*WP+w], m4=s_M[4*WP+w];
    #pragma unroll
    for (int r=0;r<Rz;r++){
      float rv = s_wr[r*Nz+0]*m0 + s_wr[r*Nz+1]*m1 + s_wr[r*Nz+2]*m2
               + s_wr[r*Nz+3]*m3 + s_wr[r*Nz+4]*m4;
      st32cv(&rdst[r*Wz + w], rv);
    }
  }
  for (int i = tid; i < Nz*Wz; i += NT){
    int n = i >> 9, w = i & 511;
    Mg[(size_t)b*Nz*Wz+i] = s_M[n*WP+w];
  }
  if (tid < Nz){ ug[b*Nz+tid]=s_u[tid]; pg[b*Nz+tid]=s_p[tid]; wwg[b*Nz+tid]=s_ww[tid]; }
  if (tid < Nz*Nz) Lg[b*Nz*Nz+tid]=s_L[tid];
  if (tid < Rz*Nz) wrg[b*Rz*Nz+tid]=s_wr[tid];
}

__global__ void __launch_bounds__(NT, 4)
dnc_kernel(const int* __restrict__ src, const float* __restrict__ emb,
           const float* __restrict__ w_ih, const float* __restrict__ w_hh,
           const float* __restrict__ b_lstm,
           const float* __restrict__ w_xi, const float* __restrict__ b_xi,
           const float* __restrict__ w_out, const float* __restrict__ b_out,
           float* __restrict__ out, float* __restrict__ ws)
{
  __shared__ __align__(16) float s_x[4112];   // 2 batches x 2048, stride BLS=2064

  const int tid = threadIdx.x;
  const int gid = blockIdx.x*NT + tid;

  float* embT  = ws;                       // [T][B][512]   cached RO
  float* hT    = ws + HT_OFF;              // [2][B][512]   coherent
  float* cT    = ws + CT_OFF;              // [B][512]      cached, WG-pinned
  float* rT    = ws + RT_OFF;              // [2][B][1024]  coherent
  float* xiT   = ws + XIT_OFF;             // [B][IFz]      coherent
  float* Mg    = ws + MG_OFF;              // [B][2560]     cached, WG-pinned
  float* ug    = ws + UG_OFF;
  float* pg    = ug + Bz*Nz;
  float* wwg   = pg + Bz*Nz;
  float* Lg    = wwg + Bz*Nz;
  float* wrg   = Lg + Bz*Nz*Nz;
  unsigned* bar = (unsigned*)(ws + BAR_OFF);
  unsigned short* wbf   = (unsigned short*)(ws + WBF_OFF);   // [2048][2048] bf16 [w_ih|w_hh]
  unsigned short* wxibf = (unsigned short*)(ws + WXIT_OFF);  // [IFz][512]   bf16 w_xi^T
  unsigned short* wobf  = (unsigned short*)(ws + WOUT_OFF);  // [512][1536]  bf16 w_out^T
  unsigned kbar = 0;

  // ---- init ----
  {
    float4* embT4 = (float4*)embT;
    const float4* emb4 = (const float4*)emb;
    for (int i = gid; i < Tz*Bz*128; i += NTH){
      int kg = i & 127, b = (i>>7) & 31, tt = i >> 12;
      embT4[i] = emb4[(size_t)src[b*Tz+tt]*128 + kg];
    }
  }
  for (int i = gid; i < IFz*Hz; i += NTH){           // wxibf[f][k] = bf16(w_xi[k][f])
    int f = i >> 9, k = i & 511;
    wxibf[i] = f2bf(w_xi[(size_t)k*IFz + f]);
  }
  for (int i = gid; i < Hz*XD; i += NTH){            // wobf[j][k] = bf16(w_out[k][j])
    int j = i / XD, k = i - j*XD;
    wobf[i] = f2bf(w_out[(size_t)k*Hz + j]);
  }
  for (int i = gid; i < GK*GK; i += NTH){            // wbf[row][k] = bf16([w_ih|w_hh])
    int row = i >> 11, k = i & 2047;
    float v = (k < XD) ? w_ih[(size_t)row*XD + k] : w_hh[(size_t)row*Hz + (k - XD)];
    wbf[i] = f2bf(v);
  }
  for (int i = gid; i < 2*HTB; i += NTH) hT[i]=0.f;
  for (int i = gid; i < HTB;   i += NTH) cT[i]=0.f;
  for (int i = gid; i < 2*RTB; i += NTH) rT[i]=0.f;
  for (int i = gid; i < Bz*Nz*Wz;i += NTH) Mg[i]=0.f;
  for (int i = gid; i < Bz*(3*Nz + Nz*Nz + Rz*Nz); i += NTH) ug[i]=0.f;
  gbar_fence(bar, kbar); kbar++;

  // WG decomposition: jc (XCD pin) x sj (j-half) x bp (batch pair)
  const int jc = blockIdx.x & 7;          // 0..7
  const int sj = (blockIdx.x >> 3) & 1;   // 0..1
  const int bp = blockIdx.x >> 4;         // 0..15
  const int b0 = 2*bp;                    // batches b0, b0+1
  const int jbase = jc*64 + sj*32;        // 32 j-rows per WG (gates)
  // phase-C role assignment: slot = jc*2+sj; memops slots sA (even batch), sB (odd)
  const int slot = jc*2 + sj;
  const int sA = ((b0 & 7) << 1);
  const int sB = (((b0+1) & 7) << 1) | 1;
  const int rank = slot - (slot > sA ? 1 : 0) - (slot > sB ? 1 : 0);  // 0..13 for non-memops

  // ---- time loop (no agent fences inside) ----
  for (int t = 0; t < Tz; ++t){
    const int cur = t & 1, nxt = (t+1)&1;

    // ===== Phase A: gates GEMV (bf16 W) only, 2 batches =====
    {
      for (int u = tid; u < 1792; u += NT){
        const int bl = (u >= 896) ? 1 : 0;
        const int v  = u - bl*896;
        const int b  = b0 + bl;
        float* dst = s_x + bl*BLS;
        if (v < 256)
          stage64(dst + 1536 + v*2, hT + (size_t)cur*HTB + (size_t)b*Hz + v*2);
        else if (v < 768)
          stage64(dst + 512 + (v-256)*2, rT + (size_t)cur*RTB + (size_t)b*RWz + (v-256)*2);
        else
          *(float4*)(dst + (v-768)*4) =
            *(const float4*)(embT + ((size_t)t*Bz + b)*Hz + (v-768)*4);
      }
      __syncthreads();

      // gates: tid = jj(5b) | bl(1b) | gate(2b) | ks(2b)
      {
        const int ks   = tid & 3;
        const int gate = (tid >> 2) & 3;
        const int bl   = (tid >> 4) & 1;
        const int jj   = tid >> 5;         // 0..31
        const int j    = jbase + jj;
        const int row  = gate*Hz + j;
        const float* xb = s_x + bl*BLS;
        float acc = dotSbf(xb + ks*4, wbf + (size_t)row*GK + ks*4, 128, 16);
        acc += __shfl_xor(acc, 1, 64);
        acc += __shfl_xor(acc, 2, 64);
        acc += b_lstm[row];
        const int lane = tid & 63;
        const int base = lane & ~12;       // zero gate bits [2:3]
        float gi = __shfl(acc, base+0,  64);
        float gf = __shfl(acc, base+4,  64);
        float gg = __shfl(acc, base+8,  64);
        float go = __shfl(acc, base+12, 64);
        if ((lane & 15) == 0){             // ks==0 && gate==0
          const int b = b0 + bl;
          float cv = cT[(size_t)b*Hz + j];
          float cn = sigf(gf)*cv + sigf(gi)*tanhf(gg);
          float hn = sigf(go)*tanhf(cn);
          cT[(size_t)b*Hz + j] = cn;
          st32cv(&hT[(size_t)nxt*HTB + (size_t)b*Hz + j], hn);
        }
      }
    }
    gbar_nf(bar, kbar); kbar++;

    // ===== Phase B: xi = h_new @ w_xi (bf16 W, strided ks-4), 2 batches =====
    // overwrites only s_x[bl*BLS + 0..512) (emb slot); r|h retained for phase C out-dot
    {
      if (tid < 512){
        const int bl = tid >> 8, v = tid & 255;
        stage64(s_x + bl*BLS + v*2, hT + (size_t)nxt*HTB + (size_t)(b0+bl)*Hz + v*2);
      }
      __syncthreads();
      const int ks  = tid & 3;
      const int bl  = (tid >> 2) & 1;
      const int fi0 = tid >> 3;            // 0..127
      #pragma unroll
      for (int round = 0; round < 2; ++round){
        int fi = round*128 + fi0;          // 0..255 (need 0..160)
        int f  = jc*322 + sj*161 + fi;
        bool ok = (fi < 161) && (f < IFz);
        int fr = ok ? f : 0;
        float acc = dotSbf(s_x + bl*BLS + ks*4, wxibf + (size_t)fr*Hz + ks*4, 32, 16);
        acc += __shfl_xor(acc, 1, 64);
        acc += __shfl_xor(acc, 2, 64);
        if (ok && ks == 0)
          st32cv(&xiT[(size_t)(b0+bl)*IFz + f], acc + b_xi[f]);
      }
    }
    gbar_nf(bar, kbar); kbar++;

    // ===== Phase C: memops (2 WGs/pair) | out(t-1) (14 WGs/pair, 37 rows each) =====
    {
      if (slot == sA){
        memops(b0, t, xiT, Mg, ug, pg, wwg, Lg, wrg, rT);
      } else if (slot == sB){
        memops(b0+1, t, xiT, Mg, ug, pg, wwg, Lg, wrg, rT);
      } else if (t > 0){
        // out(t-1) from retained s_x (r at +512..1536, h(cur) at +1536..2048)
        const int oks = tid & 15;
        const int bl  = (tid >> 4) & 1;
        const int ojj = tid >> 5;          // 0..31
        const float* xb = s_x + bl*BLS;
        const float* xh = xb + 1536 + oks*4;
        const float* xr = xb + oks*4;
        #pragma unroll
        for (int pass = 0; pass < 2; ++pass){
          const int lr = pass*32 + ojj;
          const int oj = rank*37 + lr;
          if (lr < 37 && oj < 512){
            const unsigned short* wo = wobf + (size_t)oj*XD + oks*4;
            float a0=0.f,a1=0.f,a2=0.f,a3=0.f;
            #pragma unroll 8
            for (int i=0;i<8;i++){
              float4 xv = *(const float4*)(xh + i*64);
              float w0,w1,w2,w3; bf4(*(const u64*)(wo + i*64), w0,w1,w2,w3);
              a0=fmaf(xv.x,w0,a0); a1=fmaf(xv.y,w1,a1);
              a2=fmaf(xv.z,w2,a2); a3=fmaf(xv.w,w3,a3);
            }
            #pragma unroll 16
            for (int i=8;i<24;i++){
              float4 xv = *(const float4*)(xr + i*64);
              float w0,w1,w2,w3; bf4(*(const u64*)(wo + i*64), w0,w1,w2,w3);
              a0=fmaf(xv.x,w0,a0); a1=fmaf(xv.y,w1,a1);
              a2=fmaf(xv.z,w2,a2); a3=fmaf(xv.w,w3,a3);
            }
            float oa = (a0+a1)+(a2+a3);
            oa += __shfl_xor(oa, 1, 64);
            oa += __shfl_xor(oa, 2, 64);
            oa += __shfl_xor(oa, 4, 64);
            oa += __shfl_xor(oa, 8, 64);
            if (oks == 0)
              out[(size_t)(b0+bl)*Tz*Hz + (size_t)(t-1)*Hz + oj] = oa + b_out[oj];
          }
        }
      }
    }
    gbar_nf(bar, kbar); kbar++;
  }

  gbar_fence(bar, kbar); kbar++;   // make coherent state + private cT cache-readable

  // ---- epilogue: out(T-1), final h, c (state in buffer 0) ----
  if (gid < Bz*Hz){
    const int eb = gid >> 9, ej = gid & 511;
    const unsigned short* wj = wobf + (size_t)ej*XD;
    float acc = dot4cbf(hT + (size_t)eb*Hz,  wj,       512)
              + dot4cbf(rT + (size_t)eb*RWz, wj + 512, 1024)
              + b_out[ej];
    out[(size_t)eb*Tz*Hz + (size_t)(Tz-1)*Hz + ej] = acc;
    out[(size_t)Bz*Tz*Hz + (size_t)eb*Hz + ej]       = hT[(size_t)eb*Hz + ej];
    out[(size_t)Bz*Tz*Hz + HTB + (size_t)eb*Hz + ej] = cT[(size_t)eb*Hz + ej];
  }
}

extern "C" void kernel_launch(void* const* d_in, const int* in_sizes, int n_in,
                              void* d_out, int out_size, void* d_ws, size_t ws_size,
                              hipStream_t stream)
{
  const int*   src    = (const int*)  d_in[0];
  // d_in[1] = source_lengths (unused by reference)
  const float* emb    = (const float*)d_in[2];
  const float* w_ih   = (const float*)d_in[3];
  const float* w_hh   = (const float*)d_in[4];
  const float* b_lstm = (const float*)d_in[5];
  const float* w_xi   = (const float*)d_in[6];
  const float* b_xi   = (const float*)d_in[7];
  const float* w_out  = (const float*)d_in[8];
  const float* b_out  = (const float*)d_in[9];
  float* out = (float*)d_out;
  float* ws  = (float*)d_ws;

  hipMemsetAsync((char*)d_ws + (size_t)BAR_OFF*4, 0, 8192, stream);

  void* args[] = { &src, &emb, &w_ih, &w_hh, &b_lstm, &w_xi, &b_xi, &w_out, &b_out, &out, &ws };
  hipLaunchCooperativeKernel((const void*)dnc_kernel, dim3(NWG), dim3(NT), args, 0, stream);
}

// Round 22
// 10416.498 us; speedup vs baseline: 1.7464x; 1.0733x over previous
//
#include <hip/hip_runtime.h>

#define Bz 32
#define Tz 256
#define Hz 512
#define Nz 5
#define Rz 2
#define Wz 512
#define WP 520           // padded s_M row stride
#define RWz 1024
#define XD 1536          // H + R*W
#define GK 2048          // gates K (XD + Hz)
#define IFz 2573
#define EPSF 1e-6f
#define NWG 256
#define NT 1024
#define NTH (NWG*NT)     // 262144

#define HTB (Bz*Hz)      // 16384 floats per h buffer
#define RTB (Bz*RWz)     // 32768 floats per r buffer
#define BLS 2064         // per-batch LDS slab stride (2048 + 16 pad)

// workspace float offsets
#define WXIT_OFF (Tz*Bz*Hz)                            // 4194304 (bf16 mirror of w_xi^T)
#define WOUT_OFF (WXIT_OFF + IFz*Hz)                   // 5511680 (bf16 mirror of w_out^T)
#define HT_OFF   (WOUT_OFF + Hz*XD)                    // 6298112
#define CT_OFF   (HT_OFF + 2*HTB)                      // 6330880
#define RT_OFF   (CT_OFF + HTB)                        // 6347264
#define XIT_OFF  (RT_OFF + 2*RTB)                      // 6412800
#define MG_OFF   (XIT_OFF + IFz*Bz)                    // 6495136
#define UG_OFF   (MG_OFF + Bz*Nz*Wz)                   // 6577056
#define BAR_OFF  (UG_OFF + 1600 + 32)                  // 6578688 (barrier region, 2048 floats)
#define WBF_OFF  (BAR_OFF + 2048)                      // 6580736 (bf16 gates: 2048x2048 ushort)
// group counters live INSIDE the barrier region at bar[g*64+32] (unused padding slots,
// covered by the existing 8192-byte memset; no overlap with fence counters/flags)

// xi field offsets
#define O_KR 0
#define O_BR 1024
#define O_KW 1026
#define O_BW 1538
#define O_E  1539
#define O_V  2051
#define O_FG 2563
#define O_GA 2565
#define O_GW 2566
#define O_PI 2567

typedef unsigned long long u64;

__device__ __forceinline__ float sigf(float x){ return 1.0f/(1.0f+expf(-x)); }
__device__ __forceinline__ float splus(float x){ return fmaxf(x,0.0f) + log1pf(expf(-fabsf(x))); }
__device__ __forceinline__ unsigned short f2bf(float v){
  unsigned u = __float_as_uint(v);
  return (unsigned short)((u + 0x7FFFu + ((u >> 16) & 1u)) >> 16);
}
// cheap exact unpack: 4 bf16 weights from one u64, 1 op each
__device__ __forceinline__ void bf4(u64 wb, float& w0, float& w1, float& w2, float& w3){
  unsigned lo = (unsigned)wb, hi = (unsigned)(wb >> 32);
  w0 = __uint_as_float(lo << 16);
  w1 = __uint_as_float(lo & 0xFFFF0000u);
  w2 = __uint_as_float(hi << 16);
  w3 = __uint_as_float(hi & 0xFFFF0000u);
}

// coherent accessors (R12-proven)
__device__ __forceinline__ void stage64(float* dst_lds, const float* src){
  u64 v = __hip_atomic_load((const u64*)src, __ATOMIC_RELAXED, __HIP_MEMORY_SCOPE_AGENT);
  *(u64*)dst_lds = v;
}
__device__ __forceinline__ float ld32cv(const float* p){
  return __hip_atomic_load(p, __ATOMIC_RELAXED, __HIP_MEMORY_SCOPE_AGENT);
}
__device__ __forceinline__ void st32cv(float* p, float v){
  __hip_atomic_store(p, v, __ATOMIC_RELAXED, __HIP_MEMORY_SCOPE_AGENT);
}

// ---- grid-wide fence barrier (init/final only; verbatim from R12..R19) ----
__device__ __forceinline__ void gbar_fence(unsigned* bar, unsigned k){
  __syncthreads();
  const int tid = threadIdx.x;
  const unsigned wg = blockIdx.x;
  if (tid == 0){
    __builtin_amdgcn_fence(__ATOMIC_RELEASE, "agent");
    __hip_atomic_fetch_add(&bar[(wg & 15u)*64], 1u, __ATOMIC_RELAXED, __HIP_MEMORY_SCOPE_AGENT);
  }
  if (wg == 0){
    if (tid < 16){
      const unsigned tgt = (NWG/16u)*(k+1u);
      while (__hip_atomic_load(&bar[tid*64], __ATOMIC_RELAXED, __HIP_MEMORY_SCOPE_AGENT) < tgt)
        __builtin_amdgcn_s_sleep(1);
    }
    __syncthreads();
    if (tid < 16){
      __builtin_amdgcn_fence(__ATOMIC_ACQ_REL, "agent");
      __hip_atomic_store(&bar[1024 + tid*64], k+1u, __ATOMIC_RELAXED, __HIP_MEMORY_SCOPE_AGENT);
    }
    __syncthreads();
  } else {
    if (tid == 0){
      while (__hip_atomic_load(&bar[1024 + (wg & 15u)*64], __ATOMIC_RELAXED, __HIP_MEMORY_SCOPE_AGENT) < k+1u)
        __builtin_amdgcn_s_sleep(1);
      __builtin_amdgcn_fence(__ATOMIC_ACQUIRE, "agent");
    }
    __syncthreads();
  }
}
// ---- 16-WG group barrier: all cross-phase deps are within a bp group ----
// counter for group g at bar[g*64 + 32] (padding slot inside memset'd region)
__device__ __forceinline__ void gbar_grp(unsigned* bar, unsigned k, int grp){
  __syncthreads();
  if (threadIdx.x == 0){
    asm volatile("s_waitcnt vmcnt(0) lgkmcnt(0)" ::: "memory");
    unsigned* c = &bar[grp*64 + 32];
    __hip_atomic_fetch_add(c, 1u, __ATOMIC_RELAXED, __HIP_MEMORY_SCOPE_AGENT);
    const unsigned tgt = 16u*(k+1u);
    while (__hip_atomic_load(c, __ATOMIC_RELAXED, __HIP_MEMORY_SCOPE_AGENT) < tgt)
      __builtin_amdgcn_s_sleep(1);
  }
  __syncthreads();
}

// strided bf16-weight dot
__device__ __forceinline__ float dotSbf(const float* x, const unsigned short* __restrict__ w,
                                        int iters, int strf){
  float a0=0.f,a1=0.f,a2=0.f,a3=0.f;
  #pragma unroll 16
  for (int i=0;i<iters;i++){
    float4 xv = *(const float4*)(x + (size_t)i*strf);
    float w0,w1,w2,w3; bf4(*(const u64*)(w + (size_t)i*strf), w0,w1,w2,w3);
    a0=fmaf(xv.x,w0,a0); a1=fmaf(xv.y,w1,a1);
    a2=fmaf(xv.z,w2,a2); a3=fmaf(xv.w,w3,a3);
  }
  return (a0+a1)+(a2+a3);
}
// contiguous bf16-weight dot (epilogue)
__device__ __forceinline__ float dot4cbf(const float* __restrict__ x,
                                         const unsigned short* __restrict__ w, int n){
  float a0=0.f,a1=0.f,a2=0.f,a3=0.f;
  #pragma unroll 8
  for (int i=0;i<n/4;i++){
    float4 xv = *(const float4*)(x + i*4);
    float w0,w1,w2,w3; bf4(*(const u64*)(w + i*4), w0,w1,w2,w3);
    a0=fmaf(xv.x,w0,a0); a1=fmaf(xv.y,w1,a1);
    a2=fmaf(xv.z,w2,a2); a3=fmaf(xv.w,w3,a3);
  }
  return (a0+a1)+(a2+a3);
}

__device__ void memops(int b, int t, const float* xiT,
                       float* Mg, float* ug, float* pg, float* wwg, float* Lg, float* wrg,
                       float* rT)
{
  __shared__ float s_xi[IFz];
  __shared__ float s_M[Nz*WP];
  __shared__ float s_u[Nz], s_p[Nz], s_ww[Nz], s_a[Nz], s_L[Nz*Nz], s_wr[Rz*Nz];
  __shared__ float s_sc[13];
  __shared__ float s_m2[Nz], s_dt[Nz], s_d0[Nz], s_d1[Nz];
  __shared__ float s_kw2, s_kr2[2];
  __shared__ float s_fwd[Rz*Nz], s_bwd[Rz*Nz];

  const int tid = threadIdx.x;
  const int wv = tid >> 6, ln = tid & 63;

  for (int f = tid; f < IFz; f += NT) s_xi[f] = ld32cv(&xiT[(size_t)b*IFz + f]);
  for (int i = tid; i < Nz*Wz; i += NT){
    int n = i >> 9, w = i & 511;
    s_M[n*WP+w] = Mg[(size_t)b*Nz*Wz + i];
  }
  if (tid < Nz){ s_u[tid]=ug[b*Nz+tid]; s_p[tid]=pg[b*Nz+tid]; s_ww[tid]=wwg[b*Nz+tid]; }
  if (tid < Nz*Nz) s_L[tid] = Lg[b*Nz*Nz+tid];
  if (tid < Rz*Nz) s_wr[tid] = wrg[b*Rz*Nz+tid];
  __syncthreads();

  if (tid == 0){
    s_sc[0] = 1.0f + splus(s_xi[O_BR+0]);
    s_sc[1] = 1.0f + splus(s_xi[O_BR+1]);
    s_sc[2] = 1.0f + splus(s_xi[O_BW]);
    s_sc[3] = sigf(s_xi[O_FG+0]);
    s_sc[4] = sigf(s_xi[O_FG+1]);
    s_sc[5] = sigf(s_xi[O_GA]);
    s_sc[6] = sigf(s_xi[O_GW]);
    for (int r=0;r<Rz;r++){
      float x0=s_xi[O_PI+r*3+0], x1=s_xi[O_PI+r*3+1], x2=s_xi[O_PI+r*3+2];
      float m = fmaxf(x0,fmaxf(x1,x2));
      float e0=expf(x0-m), e1=expf(x1-m), e2=expf(x2-m);
      float s = e0+e1+e2;
      s_sc[7+r*3+0]=e0/s; s_sc[7+r*3+1]=e1/s; s_sc[7+r*3+2]=e2/s;
    }
  }
  __syncthreads();

  if (tid < Nz){
    float psi = (1.0f - s_sc[3]*s_wr[0*Nz+tid]) * (1.0f - s_sc[4]*s_wr[1*Nz+tid]);
    float uu = s_u[tid], w = s_ww[tid];
    s_u[tid] = (uu + w - uu*w) * psi;
  }

  // cosine(M_old, kw)
  if (wv < 4){
    const int n = wv;
    float pd=0.f, pm=0.f;
    for (int w = ln; w < Wz; w += 64){
      float kv = s_xi[O_KW+w], mv = s_M[n*WP+w];
      pd = fmaf(kv,mv,pd); pm = fmaf(mv,mv,pm);
    }
    for (int off=32; off; off>>=1){ pd += __shfl_down(pd,off,64); pm += __shfl_down(pm,off,64); }
    if (ln==0){ s_dt[n]=pd; s_m2[n]=pm; }
  }
  if (wv == 3){
    float p2=0.f;
    for (int w=ln; w<Wz; w+=64){ float kv=s_xi[O_KW+w]; p2=fmaf(kv,kv,p2); }
    for (int off=32; off; off>>=1) p2 += __shfl_down(p2,off,64);
    if (ln==0) s_kw2 = p2;
  }
  __syncthreads();
  if (wv == 0){
    const int n = 4;
    float pd=0.f, pm=0.f;
    for (int w = ln; w < Wz; w += 64){
      float kv = s_xi[O_KW+w], mv = s_M[n*WP+w];
      pd = fmaf(kv,mv,pd); pm = fmaf(mv,mv,pm);
    }
    for (int off=32; off; off>>=1){ pd += __shfl_down(pd,off,64); pm += __shfl_down(pm,off,64); }
    if (ln==0){ s_dt[n]=pd; s_m2[n]=pm; }
  }
  __syncthreads();

  if (tid == 0){
    float su[Nz]; int idx[Nz];
    for (int i=0;i<Nz;i++){
      float v = EPSF + (1.0f-EPSF)*s_u[i];
      int j=i;
      while (j>0 && su[j-1] > v){ su[j]=su[j-1]; idx[j]=idx[j-1]; j--; }
      su[j]=v; idx[j]=i;
    }
    float cp = 1.0f;
    for (int k=0;k<Nz;k++){ s_a[idx[k]] = (1.0f - su[k])*cp; cp *= su[k]; }
    float rk = rsqrtf(s_kw2 + EPSF);
    float lg[Nz], mx=-1e30f;
    for (int n=0;n<Nz;n++){ lg[n] = s_sc[2]*s_dt[n]*rk*rsqrtf(s_m2[n]+EPSF); mx=fmaxf(mx,lg[n]); }
    float ssum=0.f;
    for (int n=0;n<Nz;n++){ lg[n]=expf(lg[n]-mx); ssum+=lg[n]; }
    float ga=s_sc[5], gw=s_sc[6];
    for (int n=0;n<Nz;n++){ float cwn = lg[n]/ssum; s_ww[n] = gw*(ga*s_a[n] + (1.0f-ga)*cwn); }
  }
  __syncthreads();

  for (int i = tid; i < Nz*Wz; i += NT){
    int n = i >> 9, w = i & 511;
    float e = sigf(s_xi[O_E+w]);
    float v = s_xi[O_V+w];
    s_M[n*WP+w] = s_M[n*WP+w]*(1.0f - s_ww[n]*e) + s_ww[n]*v;
  }
  __syncthreads();

  if (tid == 0){
    float wsum = 0.f;
    for (int n=0;n<Nz;n++) wsum += s_ww[n];
    float Lo[Nz*Nz];
    for (int i=0;i<Nz;i++)
      for (int j=0;j<Nz;j++)
        Lo[i*Nz+j] = (i==j) ? 0.0f : ((1.0f - s_ww[i] - s_ww[j])*s_L[i*Nz+j] + s_ww[i]*s_p[j]);
    for (int i=0;i<Nz*Nz;i++) s_L[i]=Lo[i];
    for (int j=0;j<Nz;j++) s_p[j] = (1.0f-wsum)*s_p[j] + s_ww[j];
    for (int r=0;r<Rz;r++)
      for (int n=0;n<Nz;n++){
        float f=0.f, bb=0.f;
        for (int m=0;m<Nz;m++){ f = fmaf(s_L[n*Nz+m], s_wr[r*Nz+m], f); bb = fmaf(s_L[m*Nz+n], s_wr[r*Nz+m], bb); }
        s_fwd[r*Nz+n]=f; s_bwd[r*Nz+n]=bb;
      }
  }
  __syncthreads();

  // cosine(M_new, kr)
  if (wv < 4){
    const int n = wv;
    float pm=0.f,p0=0.f,p1=0.f;
    for (int w=ln; w<Wz; w+=64){
      float mv=s_M[n*WP+w];
      pm=fmaf(mv,mv,pm);
      p0=fmaf(s_xi[O_KR+w],    mv,p0);
      p1=fmaf(s_xi[O_KR+Wz+w], mv,p1);
    }
    for (int off=32; off; off>>=1){
      pm += __shfl_down(pm,off,64); p0 += __shfl_down(p0,off,64); p1 += __shfl_down(p1,off,64);
    }
    if (ln==0){ s_m2[n]=pm; s_d0[n]=p0; s_d1[n]=p1; }
  }
  __syncthreads();
  if (wv == 0){
    const int n = 4;
    float pm=0.f,p0=0.f,p1=0.f;
    for (int w=ln; w<Wz; w+=64){
      float mv=s_M[n*WP+w];
      pm=fmaf(mv,mv,pm);
      p0=fmaf(s_xi[O_KR+w],    mv,p0);
      p1=fmaf(s_xi[O_KR+Wz+w], mv,p1);
    }
    for (int off=32; off; off>>=1){
      pm += __shfl_down(pm,off,64); p0 += __shfl_down(p0,off,64); p1 += __shfl_down(p1,off,64);
    }
    if (ln==0){ s_m2[n]=pm; s_d0[n]=p0; s_d1[n]=p1; }
  } else if (wv == 1 || wv == 2){
    const int r = wv - 1;
    float p2=0.f;
    for (int w=ln; w<Wz; w+=64){ float kv=s_xi[O_KR+r*Wz+w]; p2=fmaf(kv,kv,p2); }
    for (int off=32; off; off>>=1) p2 += __shfl_down(p2,off,64);
    if (ln==0) s_kr2[r]=p2;
  }
  __syncthreads();

  if (tid == 0){
    for (int r=0;r<Rz;r++){
      float rk = rsqrtf(s_kr2[r]+EPSF);
      const float* dd = (r==0) ? s_d0 : s_d1;
      float br = s_sc[r];
      float lg[Nz], mx=-1e30f;
      for (int n=0;n<Nz;n++){ lg[n] = br*dd[n]*rk*rsqrtf(s_m2[n]+EPSF); mx=fmaxf(mx,lg[n]); }
      float ssum=0.f;
      for (int n=0;n<Nz;n++){ lg[n]=expf(lg[n]-mx); ssum+=lg[n]; }
      for (int n=0;n<Nz;n++){
        float crn = lg[n]/ssum;
        s_wr[r*Nz+n] = s_sc[7+r*3+0]*s_bwd[r*Nz+n] + s_sc[7+r*3+1]*crn + s_sc[7+r*3+2]*s_fwd[r*Nz+n];
      }
    }
  }
  __syncthreads();

  // read vectors -> rT[nxt][b][r*512+w] (coherent) + private state (cached)
  float* rdst = rT + (size_t)((t+1)&1)*RTB + (size_t)b*RWz;
  for (int w = tid; w < Wz; w += NT){
    float m0=s_M[0*WP+w], m1=s_M[1*WP+w], m2=s_M[2*WP+w], m3=s_M[3*WP+w], m4=s_M[4*WP+w];
    #pragma unroll
    for (int r=0;r<Rz;r++){
      float rv = s_wr[r*Nz+0]*m0 + s_wr[r*Nz+1]*m1 + s_wr[r*Nz+2]*m2
               + s_wr[r*Nz+3]*m3 + s_wr[r*Nz+4]*m4;
      st32cv(&rdst[r*Wz + w], rv);
    }
  }
  for (int i = tid; i < Nz*Wz; i += NT){
    int n = i >> 9, w = i & 511;
    Mg[(size_t)b*Nz*Wz+i] = s_M[n*WP+w];
  }
  if (tid < Nz){ ug[b*Nz+tid]=s_u[tid]; pg[b*Nz+tid]=s_p[tid]; wwg[b*Nz+tid]=s_ww[tid]; }
  if (tid < Nz*Nz) Lg[b*Nz*Nz+tid]=s_L[tid];
  if (tid < Rz*Nz) wrg[b*Rz*Nz+tid]=s_wr[tid];
}

__global__ void __launch_bounds__(NT, 4)
dnc_kernel(const int* __restrict__ src, const float* __restrict__ emb,
           const float* __restrict__ w_ih, const float* __restrict__ w_hh,
           const float* __restrict__ b_lstm,
           const float* __restrict__ w_xi, const float* __restrict__ b_xi,
           const float* __restrict__ w_out, const float* __restrict__ b_out,
           float* __restrict__ out, float* __restrict__ ws)
{
  __shared__ __align__(16) float s_x[4112];   // 2 batches x 2048, stride BLS=2064

  const int tid = threadIdx.x;
  const int gid = blockIdx.x*NT + tid;

  float* embT  = ws;                       // [T][B][512]   cached RO
  float* hT    = ws + HT_OFF;              // [2][B][512]   coherent
  float* cT    = ws + CT_OFF;              // [B][512]      cached, WG-pinned
  float* rT    = ws + RT_OFF;              // [2][B][1024]  coherent
  float* xiT   = ws + XIT_OFF;             // [B][IFz]      coherent
  float* Mg    = ws + MG_OFF;              // [B][2560]     cached, WG-pinned
  float* ug    = ws + UG_OFF;
  float* pg    = ug + Bz*Nz;
  float* wwg   = pg + Bz*Nz;
  float* Lg    = wwg + Bz*Nz;
  float* wrg   = Lg + Bz*Nz*Nz;
  unsigned* bar  = (unsigned*)(ws + BAR_OFF);
  unsigned short* wbf   = (unsigned short*)(ws + WBF_OFF);   // [2048][2048] bf16 [w_ih|w_hh]
  unsigned short* wxibf = (unsigned short*)(ws + WXIT_OFF);  // [IFz][512]   bf16 w_xi^T
  unsigned short* wobf  = (unsigned short*)(ws + WOUT_OFF);  // [512][1536]  bf16 w_out^T
  unsigned kbar = 0;

  // ---- init ----
  {
    float4* embT4 = (float4*)embT;
    const float4* emb4 = (const float4*)emb;
    for (int i = gid; i < Tz*Bz*128; i += NTH){
      int kg = i & 127, b = (i>>7) & 31, tt = i >> 12;
      embT4[i] = emb4[(size_t)src[b*Tz+tt]*128 + kg];
    }
  }
  for (int i = gid; i < IFz*Hz; i += NTH){           // wxibf[f][k] = bf16(w_xi[k][f])
    int f = i >> 9, k = i & 511;
    wxibf[i] = f2bf(w_xi[(size_t)k*IFz + f]);
  }
  for (int i = gid; i < Hz*XD; i += NTH){            // wobf[j][k] = bf16(w_out[k][j])
    int j = i / XD, k = i - j*XD;
    wobf[i] = f2bf(w_out[(size_t)k*Hz + j]);
  }
  for (int i = gid; i < GK*GK; i += NTH){            // wbf[row][k] = bf16([w_ih|w_hh])
    int row = i >> 11, k = i & 2047;
    float v = (k < XD) ? w_ih[(size_t)row*XD + k] : w_hh[(size_t)row*Hz + (k - XD)];
    wbf[i] = f2bf(v);
  }
  for (int i = gid; i < 2*HTB; i += NTH) hT[i]=0.f;
  for (int i = gid; i < HTB;   i += NTH) cT[i]=0.f;
  for (int i = gid; i < 2*RTB; i += NTH) rT[i]=0.f;
  for (int i = gid; i < Bz*Nz*Wz;i += NTH) Mg[i]=0.f;
  for (int i = gid; i < Bz*(3*Nz + Nz*Nz + Rz*Nz); i += NTH) ug[i]=0.f;
  gbar_fence(bar, 0);

  // WG decomposition: jc (XCD pin) x sj (j-half) x bp (batch pair == sync group)
  const int jc = blockIdx.x & 7;          // 0..7
  const int sj = (blockIdx.x >> 3) & 1;   // 0..1
  const int bp = blockIdx.x >> 4;         // 0..15 (group id)
  const int b0 = 2*bp;                    // batches b0, b0+1
  const int jbase = jc*64 + sj*32;        // 32 j-rows per WG (gates)
  // phase-C role: slot = jc*2+sj; memops slots sA (even batch), sB (odd)
  const int slot = jc*2 + sj;
  const int sA = ((b0 & 7) << 1);
  const int sB = (((b0+1) & 7) << 1) | 1;
  const int rank = slot - (slot > sA ? 1 : 0) - (slot > sB ? 1 : 0);  // 0..13 for non-memops

  // ---- time loop (group-local sync only; no agent fences inside) ----
  for (int t = 0; t < Tz; ++t){
    const int cur = t & 1, nxt = (t+1)&1;

    // ===== Phase A: gates GEMV (bf16 W), 2 batches =====
    {
      for (int u = tid; u < 1792; u += NT){
        const int bl = (u >= 896) ? 1 : 0;
        const int v  = u - bl*896;
        const int b  = b0 + bl;
        float* dst = s_x + bl*BLS;
        if (v < 256)
          stage64(dst + 1536 + v*2, hT + (size_t)cur*HTB + (size_t)b*Hz + v*2);
        else if (v < 768)
          stage64(dst + 512 + (v-256)*2, rT + (size_t)cur*RTB + (size_t)b*RWz + (v-256)*2);
        else
          *(float4*)(dst + (v-768)*4) =
            *(const float4*)(embT + ((size_t)t*Bz + b)*Hz + (v-768)*4);
      }
      __syncthreads();

      // gates: tid = jj(5b) | bl(1b) | gate(2b) | ks(2b)
      {
        const int ks   = tid & 3;
        const int gate = (tid >> 2) & 3;
        const int bl   = (tid >> 4) & 1;
        const int jj   = tid >> 5;         // 0..31
        const int j    = jbase + jj;
        const int row  = gate*Hz + j;
        const float* xb = s_x + bl*BLS;
        float acc = dotSbf(xb + ks*4, wbf + (size_t)row*GK + ks*4, 128, 16);
        acc += __shfl_xor(acc, 1, 64);
        acc += __shfl_xor(acc, 2, 64);
        acc += b_lstm[row];
        const int lane = tid & 63;
        const int base = lane & ~12;       // zero gate bits [2:3]
        float gi = __shfl(acc, base+0,  64);
        float gf = __shfl(acc, base+4,  64);
        float gg = __shfl(acc, base+8,  64);
        float go = __shfl(acc, base+12, 64);
        if ((lane & 15) == 0){             // ks==0 && gate==0
          const int b = b0 + bl;
          float cv = cT[(size_t)b*Hz + j];
          float cn = sigf(gf)*cv + sigf(gi)*tanhf(gg);
          float hn = sigf(go)*tanhf(cn);
          cT[(size_t)b*Hz + j] = cn;
          st32cv(&hT[(size_t)nxt*HTB + (size_t)b*Hz + j], hn);
        }
      }
    }
    gbar_grp(bar, kbar, bp); kbar++;

    // ===== Phase B: xi = h_new @ w_xi (bf16 W), 2 batches =====
    // overwrites only s_x[bl*BLS + 0..512) (emb slot); r|h retained for phase C out-dot
    {
      if (tid < 512){
        const int bl = tid >> 8, v = tid & 255;
        stage64(s_x + bl*BLS + v*2, hT + (size_t)nxt*HTB + (size_t)(b0+bl)*Hz + v*2);
      }
      __syncthreads();
      const int ks  = tid & 3;
      const int bl  = (tid >> 2) & 1;
      const int fi0 = tid >> 3;            // 0..127
      #pragma unroll
      for (int round = 0; round < 2; ++round){
        int fi = round*128 + fi0;          // 0..255 (need 0..160)
        int f  = jc*322 + sj*161 + fi;
        bool ok = (fi < 161) && (f < IFz);
        int fr = ok ? f : 0;
        float acc = dotSbf(s_x + bl*BLS + ks*4, wxibf + (size_t)fr*Hz + ks*4, 32, 16);
        acc += __shfl_xor(acc, 1, 64);
        acc += __shfl_xor(acc, 2, 64);
        if (ok && ks == 0)
          st32cv(&xiT[(size_t)(b0+bl)*IFz + f], acc + b_xi[f]);
      }
    }
    gbar_grp(bar, kbar, bp); kbar++;

    // ===== Phase C: memops (2 WGs/group) | out(t-1) (14 WGs/group, 37 rows each) =====
    {
      if (slot == sA){
        memops(b0, t, xiT, Mg, ug, pg, wwg, Lg, wrg, rT);
      } else if (slot == sB){
        memops(b0+1, t, xiT, Mg, ug, pg, wwg, Lg, wrg, rT);
      } else if (t > 0){
        const int oks = tid & 15;
        const int bl  = (tid >> 4) & 1;
        const int ojj = tid >> 5;          // 0..31
        const float* xb = s_x + bl*BLS;
        const float* xh = xb + 1536 + oks*4;
        const float* xr = xb + oks*4;
        #pragma unroll
        for (int pass = 0; pass < 2; ++pass){
          const int lr = pass*32 + ojj;
          const int oj = rank*37 + lr;
          if (lr < 37 && oj < 512){
            const unsigned short* wo = wobf + (size_t)oj*XD + oks*4;
            float a0=0.f,a1=0.f,a2=0.f,a3=0.f;
            #pragma unroll 8
            for (int i=0;i<8;i++){
              float4 xv = *(const float4*)(xh + i*64);
              float w0,w1,w2,w3; bf4(*(const u64*)(wo + i*64), w0,w1,w2,w3);
              a0=fmaf(xv.x,w0,a0); a1=fmaf(xv.y,w1,a1);
              a2=fmaf(xv.z,w2,a2); a3=fmaf(xv.w,w3,a3);
            }
            #pragma unroll 16
            for (int i=8;i<24;i++){
              float4 xv = *(const float4*)(xr + i*64);
              float w0,w1,w2,w3; bf4(*(const u64*)(wo + i*64), w0,w1,w2,w3);
              a0=fmaf(xv.x,w0,a0); a1=fmaf(xv.y,w1,a1);
              a2=fmaf(xv.z,w2,a2); a3=fmaf(xv.w,w3,a3);
            }
            float oa = (a0+a1)+(a2+a3);
            oa += __shfl_xor(oa, 1, 64);
            oa += __shfl_xor(oa, 2, 64);
            oa += __shfl_xor(oa, 4, 64);
            oa += __shfl_xor(oa, 8, 64);
            if (oks == 0)
              out[(size_t)(b0+bl)*Tz*Hz + (size_t)(t-1)*Hz + oj] = oa + b_out[oj];
          }
        }
      }
    }
    gbar_grp(bar, kbar, bp); kbar++;
  }

  gbar_fence(bar, 1);   // grid-wide: make coherent state + private cT cache-readable

  // ---- epilogue: out(T-1), final h, c (state in buffer 0) ----
  if (gid < Bz*Hz){
    const int eb = gid >> 9, ej = gid & 511;
    const unsigned short* wj = wobf + (size_t)ej*XD;
    float acc = dot4cbf(hT + (size_t)eb*Hz,  wj,       512)
              + dot4cbf(rT + (size_t)eb*RWz, wj + 512, 1024)
              + b_out[ej];
    out[(size_t)eb*Tz*Hz + (size_t)(Tz-1)*Hz + ej] = acc;
    out[(size_t)Bz*Tz*Hz + (size_t)eb*Hz + ej]       = hT[(size_t)eb*Hz + ej];
    out[(size_t)Bz*Tz*Hz + HTB + (size_t)eb*Hz + ej] = cT[(size_t)eb*Hz + ej];
  }
}

extern "C" void kernel_launch(void* const* d_in, const int* in_sizes, int n_in,
                              void* d_out, int out_size, void* d_ws, size_t ws_size,
                              hipStream_t stream)
{
  const int*   src    = (const int*)  d_in[0];
  // d_in[1] = source_lengths (unused by reference)
  const float* emb    = (const float*)d_in[2];
  const float* w_ih   = (const float*)d_in[3];
  const float* w_hh   = (const float*)d_in[4];
  const float* b_lstm = (const float*)d_in[5];
  const float* w_xi   = (const float*)d_in[6];
  const float* b_xi   = (const float*)d_in[7];
  const float* w_out  = (const float*)d_in[8];
  const float* b_out  = (const float*)d_in[9];
  float* out = (float*)d_out;
  float* ws  = (float*)d_ws;

  // zero the barrier region (fence counters/flags + group counters share it)
  hipMemsetAsync((char*)d_ws + (size_t)BAR_OFF*4, 0, 8192, stream);

  void* args[] = { &src, &emb, &w_ih, &w_hh, &b_lstm, &w_xi, &b_xi, &w_out, &b_out, &out, &ws };
  hipLaunchCooperativeKernel((const void*)dnc_kernel, dim3(NWG), dim3(NT), args, 0, stream);
}

// Round 23
// 8372.875 us; speedup vs baseline: 2.1726x; 1.2441x over previous
//
#include <hip/hip_runtime.h>

#define Bz 32
#define Tz 256
#define Hz 512
#define Nz 5
#define Rz 2
#define Wz 512
#define WP 520           // padded s_M row stride
#define RWz 1024
#define XD 1536          // H + R*W
#define GK 2048          // gates K (XD + Hz)
#define IFz 2573
#define EPSF 1e-6f
#define NWG 256
#define NT 1024
#define NTH (NWG*NT)     // 262144

#define HTB (Bz*Hz)      // 16384 floats per h buffer
#define RTB (Bz*RWz)     // 32768 floats per r buffer
#define BLS 2064         // per-batch LDS slab stride (2048 + 16 pad)

// workspace float offsets
#define WXIT_OFF (Tz*Bz*Hz)                            // 4194304 (bf16 mirror of w_xi^T)
#define WOUT_OFF (WXIT_OFF + IFz*Hz)                   // 5511680 (bf16 mirror of w_out^T)
#define HT_OFF   (WOUT_OFF + Hz*XD)                    // 6298112
#define CT_OFF   (HT_OFF + 2*HTB)                      // 6330880
#define RT_OFF   (CT_OFF + HTB)                        // 6347264
#define XIT_OFF  (RT_OFF + 2*RTB)                      // 6412800
#define MG_OFF   (XIT_OFF + IFz*Bz)                    // 6495136
#define UG_OFF   (MG_OFF + Bz*Nz*Wz)                   // 6577056
#define BAR_OFF  (UG_OFF + 1600 + 32)                  // 6578688 (barrier region, 2048 floats)
#define WBF_OFF  (BAR_OFF + 2048)                      // 6580736 (bf16 gates: 2048x2048 ushort)
// group counters live INSIDE the barrier region at bar[g*64+32] (unused padding slots)

// xi field offsets
#define O_KR 0
#define O_BR 1024
#define O_KW 1026
#define O_BW 1538
#define O_E  1539
#define O_V  2051
#define O_FG 2563
#define O_GA 2565
#define O_GW 2566
#define O_PI 2567

typedef unsigned long long u64;

__device__ __forceinline__ float sigf(float x){ return 1.0f/(1.0f+expf(-x)); }
__device__ __forceinline__ float splus(float x){ return fmaxf(x,0.0f) + log1pf(expf(-fabsf(x))); }
__device__ __forceinline__ unsigned short f2bf(float v){
  unsigned u = __float_as_uint(v);
  return (unsigned short)((u + 0x7FFFu + ((u >> 16) & 1u)) >> 16);
}
// cheap exact unpack: 4 bf16 weights from one u64, 1 op each
__device__ __forceinline__ void bf4(u64 wb, float& w0, float& w1, float& w2, float& w3){
  unsigned lo = (unsigned)wb, hi = (unsigned)(wb >> 32);
  w0 = __uint_as_float(lo << 16);
  w1 = __uint_as_float(lo & 0xFFFF0000u);
  w2 = __uint_as_float(hi << 16);
  w3 = __uint_as_float(hi & 0xFFFF0000u);
}

// coherent accessors (R12-proven)
__device__ __forceinline__ void stage64(float* dst_lds, const float* src){
  u64 v = __hip_atomic_load((const u64*)src, __ATOMIC_RELAXED, __HIP_MEMORY_SCOPE_AGENT);
  *(u64*)dst_lds = v;
}
__device__ __forceinline__ float ld32cv(const float* p){
  return __hip_atomic_load(p, __ATOMIC_RELAXED, __HIP_MEMORY_SCOPE_AGENT);
}
__device__ __forceinline__ void st32cv(float* p, float v){
  __hip_atomic_store(p, v, __ATOMIC_RELAXED, __HIP_MEMORY_SCOPE_AGENT);
}

// ---- grid-wide fence barrier (init/final only) ----
__device__ __forceinline__ void gbar_fence(unsigned* bar, unsigned k){
  __syncthreads();
  const int tid = threadIdx.x;
  const unsigned wg = blockIdx.x;
  if (tid == 0){
    __builtin_amdgcn_fence(__ATOMIC_RELEASE, "agent");
    __hip_atomic_fetch_add(&bar[(wg & 15u)*64], 1u, __ATOMIC_RELAXED, __HIP_MEMORY_SCOPE_AGENT);
  }
  if (wg == 0){
    if (tid < 16){
      const unsigned tgt = (NWG/16u)*(k+1u);
      while (__hip_atomic_load(&bar[tid*64], __ATOMIC_RELAXED, __HIP_MEMORY_SCOPE_AGENT) < tgt)
        __builtin_amdgcn_s_sleep(1);
    }
    __syncthreads();
    if (tid < 16){
      __builtin_amdgcn_fence(__ATOMIC_ACQ_REL, "agent");
      __hip_atomic_store(&bar[1024 + tid*64], k+1u, __ATOMIC_RELAXED, __HIP_MEMORY_SCOPE_AGENT);
    }
    __syncthreads();
  } else {
    if (tid == 0){
      while (__hip_atomic_load(&bar[1024 + (wg & 15u)*64], __ATOMIC_RELAXED, __HIP_MEMORY_SCOPE_AGENT) < k+1u)
        __builtin_amdgcn_s_sleep(1);
      __builtin_amdgcn_fence(__ATOMIC_ACQUIRE, "agent");
    }
    __syncthreads();
  }
}
// ---- 16-WG group barrier (counter at bar[g*64+32], R21-proven) ----
__device__ __forceinline__ void gbar_grp(unsigned* bar, unsigned k, int grp){
  __syncthreads();
  if (threadIdx.x == 0){
    asm volatile("s_waitcnt vmcnt(0) lgkmcnt(0)" ::: "memory");
    unsigned* c = &bar[grp*64 + 32];
    __hip_atomic_fetch_add(c, 1u, __ATOMIC_RELAXED, __HIP_MEMORY_SCOPE_AGENT);
    const unsigned tgt = 16u*(k+1u);
    while (__hip_atomic_load(c, __ATOMIC_RELAXED, __HIP_MEMORY_SCOPE_AGENT) < tgt)
      __builtin_amdgcn_s_sleep(1);
  }
  __syncthreads();
}

// contiguous bf16-weight dot (epilogue)
__device__ __forceinline__ float dot4cbf(const float* __restrict__ x,
                                         const unsigned short* __restrict__ w, int n){
  float a0=0.f,a1=0.f,a2=0.f,a3=0.f;
  #pragma unroll 8
  for (int i=0;i<n/4;i++){
    float4 xv = *(const float4*)(x + i*4);
    float w0,w1,w2,w3; bf4(*(const u64*)(w + i*4), w0,w1,w2,w3);
    a0=fmaf(xv.x,w0,a0); a1=fmaf(xv.y,w1,a1);
    a2=fmaf(xv.z,w2,a2); a3=fmaf(xv.w,w3,a3);
  }
  return (a0+a1)+(a2+a3);
}

__device__ void memops(int b, int t, const float* xiT,
                       float* Mg, float* ug, float* pg, float* wwg, float* Lg, float* wrg,
                       float* rT)
{
  __shared__ float s_xi[IFz];
  __shared__ float s_M[Nz*WP];
  __shared__ float s_u[Nz], s_p[Nz], s_ww[Nz], s_a[Nz], s_L[Nz*Nz], s_wr[Rz*Nz];
  __shared__ float s_sc[13];
  __shared__ float s_m2[Nz], s_dt[Nz], s_d0[Nz], s_d1[Nz];
  __shared__ float s_kw2, s_kr2[2];
  __shared__ float s_fwd[Rz*Nz], s_bwd[Rz*Nz];

  const int tid = threadIdx.x;
  const int wv = tid >> 6, ln = tid & 63;

  for (int f = tid; f < IFz; f += NT) s_xi[f] = ld32cv(&xiT[(size_t)b*IFz + f]);
  for (int i = tid; i < Nz*Wz; i += NT){
    int n = i >> 9, w = i & 511;
    s_M[n*WP+w] = Mg[(size_t)b*Nz*Wz + i];
  }
  if (tid < Nz){ s_u[tid]=ug[b*Nz+tid]; s_p[tid]=pg[b*Nz+tid]; s_ww[tid]=wwg[b*Nz+tid]; }
  if (tid < Nz*Nz) s_L[tid] = Lg[b*Nz*Nz+tid];
  if (tid < Rz*Nz) s_wr[tid] = wrg[b*Rz*Nz+tid];
  __syncthreads();

  if (tid == 0){
    s_sc[0] = 1.0f + splus(s_xi[O_BR+0]);
    s_sc[1] = 1.0f + splus(s_xi[O_BR+1]);
    s_sc[2] = 1.0f + splus(s_xi[O_BW]);
    s_sc[3] = sigf(s_xi[O_FG+0]);
    s_sc[4] = sigf(s_xi[O_FG+1]);
    s_sc[5] = sigf(s_xi[O_GA]);
    s_sc[6] = sigf(s_xi[O_GW]);
    for (int r=0;r<Rz;r++){
      float x0=s_xi[O_PI+r*3+0], x1=s_xi[O_PI+r*3+1], x2=s_xi[O_PI+r*3+2];
      float m = fmaxf(x0,fmaxf(x1,x2));
      float e0=expf(x0-m), e1=expf(x1-m), e2=expf(x2-m);
      float s = e0+e1+e2;
      s_sc[7+r*3+0]=e0/s; s_sc[7+r*3+1]=e1/s; s_sc[7+r*3+2]=e2/s;
    }
  }
  __syncthreads();

  if (tid < Nz){
    float psi = (1.0f - s_sc[3]*s_wr[0*Nz+tid]) * (1.0f - s_sc[4]*s_wr[1*Nz+tid]);
    float uu = s_u[tid], w = s_ww[tid];
    s_u[tid] = (uu + w - uu*w) * psi;
  }

  // cosine(M_old, kw)
  if (wv < 4){
    const int n = wv;
    float pd=0.f, pm=0.f;
    for (int w = ln; w < Wz; w += 64){
      float kv = s_xi[O_KW+w], mv = s_M[n*WP+w];
      pd = fmaf(kv,mv,pd); pm = fmaf(mv,mv,pm);
    }
    for (int off=32; off; off>>=1){ pd += __shfl_down(pd,off,64); pm += __shfl_down(pm,off,64); }
    if (ln==0){ s_dt[n]=pd; s_m2[n]=pm; }
  }
  if (wv == 3){
    float p2=0.f;
    for (int w=ln; w<Wz; w+=64){ float kv=s_xi[O_KW+w]; p2=fmaf(kv,kv,p2); }
    for (int off=32; off; off>>=1) p2 += __shfl_down(p2,off,64);
    if (ln==0) s_kw2 = p2;
  }
  __syncthreads();
  if (wv == 0){
    const int n = 4;
    float pd=0.f, pm=0.f;
    for (int w = ln; w < Wz; w += 64){
      float kv = s_xi[O_KW+w], mv = s_M[n*WP+w];
      pd = fmaf(kv,mv,pd); pm = fmaf(mv,mv,pm);
    }
    for (int off=32; off; off>>=1){ pd += __shfl_down(pd,off,64); pm += __shfl_down(pm,off,64); }
    if (ln==0){ s_dt[n]=pd; s_m2[n]=pm; }
  }
  __syncthreads();

  if (tid == 0){
    float su[Nz]; int idx[Nz];
    for (int i=0;i<Nz;i++){
      float v = EPSF + (1.0f-EPSF)*s_u[i];
      int j=i;
      while (j>0 && su[j-1] > v){ su[j]=su[j-1]; idx[j]=idx[j-1]; j--; }
      su[j]=v; idx[j]=i;
    }
    float cp = 1.0f;
    for (int k=0;k<Nz;k++){ s_a[idx[k]] = (1.0f - su[k])*cp; cp *= su[k]; }
    float rk = rsqrtf(s_kw2 + EPSF);
    float lg[Nz], mx=-1e30f;
    for (int n=0;n<Nz;n++){ lg[n] = s_sc[2]*s_dt[n]*rk*rsqrtf(s_m2[n]+EPSF); mx=fmaxf(mx,lg[n]); }
    float ssum=0.f;
    for (int n=0;n<Nz;n++){ lg[n]=expf(lg[n]-mx); ssum+=lg[n]; }
    float ga=s_sc[5], gw=s_sc[6];
    for (int n=0;n<Nz;n++){ float cwn = lg[n]/ssum; s_ww[n] = gw*(ga*s_a[n] + (1.0f-ga)*cwn); }
  }
  __syncthreads();

  for (int i = tid; i < Nz*Wz; i += NT){
    int n = i >> 9, w = i & 511;
    float e = sigf(s_xi[O_E+w]);
    float v = s_xi[O_V+w];
    s_M[n*WP+w] = s_M[n*WP+w]*(1.0f - s_ww[n]*e) + s_ww[n]*v;
  }
  __syncthreads();

  if (tid == 0){
    float wsum = 0.f;
    for (int n=0;n<Nz;n++) wsum += s_ww[n];
    float Lo[Nz*Nz];
    for (int i=0;i<Nz;i++)
      for (int j=0;j<Nz;j++)
        Lo[i*Nz+j] = (i==j) ? 0.0f : ((1.0f - s_ww[i] - s_ww[j])*s_L[i*Nz+j] + s_ww[i]*s_p[j]);
    for (int i=0;i<Nz*Nz;i++) s_L[i]=Lo[i];
    for (int j=0;j<Nz;j++) s_p[j] = (1.0f-wsum)*s_p[j] + s_ww[j];
    for (int r=0;r<Rz;r++)
      for (int n=0;n<Nz;n++){
        float f=0.f, bb=0.f;
        for (int m=0;m<Nz;m++){ f = fmaf(s_L[n*Nz+m], s_wr[r*Nz+m], f); bb = fmaf(s_L[m*Nz+n], s_wr[r*Nz+m], bb); }
        s_fwd[r*Nz+n]=f; s_bwd[r*Nz+n]=bb;
      }
  }
  __syncthreads();

  // cosine(M_new, kr)
  if (wv < 4){
    const int n = wv;
    float pm=0.f,p0=0.f,p1=0.f;
    for (int w=ln; w<Wz; w+=64){
      float mv=s_M[n*WP+w];
      pm=fmaf(mv,mv,pm);
      p0=fmaf(s_xi[O_KR+w],    mv,p0);
      p1=fmaf(s_xi[O_KR+Wz+w], mv,p1);
    }
    for (int off=32; off; off>>=1){
      pm += __shfl_down(pm,off,64); p0 += __shfl_down(p0,off,64); p1 += __shfl_down(p1,off,64);
    }
    if (ln==0){ s_m2[n]=pm; s_d0[n]=p0; s_d1[n]=p1; }
  }
  __syncthreads();
  if (wv == 0){
    const int n = 4;
    float pm=0.f,p0=0.f,p1=0.f;
    for (int w=ln; w<Wz; w+=64){
      float mv=s_M[n*WP+w];
      pm=fmaf(mv,mv,pm);
      p0=fmaf(s_xi[O_KR+w],    mv,p0);
      p1=fmaf(s_xi[O_KR+Wz+w], mv,p1);
    }
    for (int off=32; off; off>>=1){
      pm += __shfl_down(pm,off,64); p0 += __shfl_down(p0,off,64); p1 += __shfl_down(p1,off,64);
    }
    if (ln==0){ s_m2[n]=pm; s_d0[n]=p0; s_d1[n]=p1; }
  } else if (wv == 1 || wv == 2){
    const int r = wv - 1;
    float p2=0.f;
    for (int w=ln; w<Wz; w+=64){ float kv=s_xi[O_KR+r*Wz+w]; p2=fmaf(kv,kv,p2); }
    for (int off=32; off; off>>=1) p2 += __shfl_down(p2,off,64);
    if (ln==0) s_kr2[r]=p2;
  }
  __syncthreads();

  if (tid == 0){
    for (int r=0;r<Rz;r++){
      float rk = rsqrtf(s_kr2[r]+EPSF);
      const float* dd = (r==0) ? s_d0 : s_d1;
      float br = s_sc[r];
      float lg[Nz], mx=-1e30f;
      for (int n=0;n<Nz;n++){ lg[n] = br*dd[n]*rk*rsqrtf(s_m2[n]+EPSF); mx=fmaxf(mx,lg[n]); }
      float ssum=0.f;
      for (int n=0;n<Nz;n++){ lg[n]=expf(lg[n]-mx); ssum+=lg[n]; }
      for (int n=0;n<Nz;n++){
        float crn = lg[n]/ssum;
        s_wr[r*Nz+n] = s_sc[7+r*3+0]*s_bwd[r*Nz+n] + s_sc[7+r*3+1]*crn + s_sc[7+r*3+2]*s_fwd[r*Nz+n];
      }
    }
  }
  __syncthreads();

  // read vectors -> rT[nxt][b][r*512+w] (coherent) + private state (cached)
  float* rdst = rT + (size_t)((t+1)&1)*RTB + (size_t)b*RWz;
  for (int w = tid; w < Wz; w += NT){
    float m0=s_M[0*WP+w], m1=s_M[1*WP+w], m2=s_M[2*WP+w], m3=s_M[3*WP+w], m4=s_M[4*WP+w];
    #pragma unroll
    for (int r=0;r<Rz;r++){
      float rv = s_wr[r*Nz+0]*m0 + s_wr[r*Nz+1]*m1 + s_wr[r*Nz+2]*m2
               + s_wr[r*Nz+3]*m3 + s_wr[r*Nz+4]*m4;
      st32cv(&rdst[r*Wz + w], rv);
    }
  }
  for (int i = tid; i < Nz*Wz; i += NT){
    int n = i >> 9, w = i & 511;
    Mg[(size_t)b*Nz*Wz+i] = s_M[n*WP+w];
  }
  if (tid < Nz){ ug[b*Nz+tid]=s_u[tid]; pg[b*Nz+tid]=s_p[tid]; wwg[b*Nz+tid]=s_ww[tid]; }
  if (tid < Nz*Nz) Lg[b*Nz*Nz+tid]=s_L[tid];
  if (tid < Rz*Nz) wrg[b*Rz*Nz+tid]=s_wr[tid];
}

__global__ void __launch_bounds__(NT, 4)
dnc_kernel(const int* __restrict__ src, const float* __restrict__ emb,
           const float* __restrict__ w_ih, const float* __restrict__ w_hh,
           const float* __restrict__ b_lstm,
           const float* __restrict__ w_xi, const float* __restrict__ b_xi,
           const float* __restrict__ w_out, const float* __restrict__ b_out,
           float* __restrict__ out, float* __restrict__ ws)
{
  __shared__ __align__(16) float s_x[4112];   // 2 batches x 2048, stride BLS=2064

  const int tid = threadIdx.x;
  const int gid = blockIdx.x*NT + tid;

  float* embT  = ws;                       // [T][B][512]   cached RO
  float* hT    = ws + HT_OFF;              // [2][B][512]   coherent
  float* cT    = ws + CT_OFF;              // [B][512]      cached, WG-pinned
  float* rT    = ws + RT_OFF;              // [2][B][1024]  coherent
  float* xiT   = ws + XIT_OFF;             // [B][IFz]      coherent
  float* Mg    = ws + MG_OFF;              // [B][2560]     cached, WG-pinned
  float* ug    = ws + UG_OFF;
  float* pg    = ug + Bz*Nz;
  float* wwg   = pg + Bz*Nz;
  float* Lg    = wwg + Bz*Nz;
  float* wrg   = Lg + Bz*Nz*Nz;
  unsigned* bar  = (unsigned*)(ws + BAR_OFF);
  unsigned short* wbf   = (unsigned short*)(ws + WBF_OFF);   // [2048][2048] bf16 [w_ih|w_hh]
  unsigned short* wxibf = (unsigned short*)(ws + WXIT_OFF);  // [IFz][512]   bf16 w_xi^T
  unsigned short* wobf  = (unsigned short*)(ws + WOUT_OFF);  // [512][1536]  bf16 w_out^T
  unsigned kbar = 0;

  // ---- init ----
  {
    float4* embT4 = (float4*)embT;
    const float4* emb4 = (const float4*)emb;
    for (int i = gid; i < Tz*Bz*128; i += NTH){
      int kg = i & 127, b = (i>>7) & 31, tt = i >> 12;
      embT4[i] = emb4[(size_t)src[b*Tz+tt]*128 + kg];
    }
  }
  for (int i = gid; i < IFz*Hz; i += NTH){           // wxibf[f][k] = bf16(w_xi[k][f])
    int f = i >> 9, k = i & 511;
    wxibf[i] = f2bf(w_xi[(size_t)k*IFz + f]);
  }
  for (int i = gid; i < Hz*XD; i += NTH){            // wobf[j][k] = bf16(w_out[k][j])
    int j = i / XD, k = i - j*XD;
    wobf[i] = f2bf(w_out[(size_t)k*Hz + j]);
  }
  for (int i = gid; i < GK*GK; i += NTH){            // wbf[row][k] = bf16([w_ih|w_hh])
    int row = i >> 11, k = i & 2047;
    float v = (k < XD) ? w_ih[(size_t)row*XD + k] : w_hh[(size_t)row*Hz + (k - XD)];
    wbf[i] = f2bf(v);
  }
  for (int i = gid; i < 2*HTB; i += NTH) hT[i]=0.f;
  for (int i = gid; i < HTB;   i += NTH) cT[i]=0.f;
  for (int i = gid; i < 2*RTB; i += NTH) rT[i]=0.f;
  for (int i = gid; i < Bz*Nz*Wz;i += NTH) Mg[i]=0.f;
  for (int i = gid; i < Bz*(3*Nz + Nz*Nz + Rz*Nz); i += NTH) ug[i]=0.f;
  gbar_fence(bar, 0);

  // WG decomposition: jc (XCD pin) x sj (j-half) x bp (batch pair == sync group)
  const int jc = blockIdx.x & 7;          // 0..7
  const int sj = (blockIdx.x >> 3) & 1;   // 0..1
  const int bp = blockIdx.x >> 4;         // 0..15 (group id)
  const int b0 = 2*bp;                    // batches b0, b0+1
  const int jbase = jc*64 + sj*32;        // 32 j-rows per WG (gates)
  // phase-C role: slot = jc*2+sj; memops slots sA (even batch), sB (odd)
  const int slot = jc*2 + sj;
  const int sA = ((b0 & 7) << 1);
  const int sB = (((b0+1) & 7) << 1) | 1;
  const int rank = slot - (slot > sA ? 1 : 0) - (slot > sB ? 1 : 0);  // 0..13 for non-memops

  // ---- time loop (group-local sync only; no agent fences inside) ----
  for (int t = 0; t < Tz; ++t){
    const int cur = t & 1, nxt = (t+1)&1;

    // ===== Phase A: gates GEMV (bf16 W, batch-pair fused, ks-8) =====
    {
      for (int u = tid; u < 1792; u += NT){
        const int bl = (u >= 896) ? 1 : 0;
        const int v  = u - bl*896;
        const int b  = b0 + bl;
        float* dst = s_x + bl*BLS;
        if (v < 256)
          stage64(dst + 1536 + v*2, hT + (size_t)cur*HTB + (size_t)b*Hz + v*2);
        else if (v < 768)
          stage64(dst + 512 + (v-256)*2, rT + (size_t)cur*RTB + (size_t)b*RWz + (v-256)*2);
        else
          *(float4*)(dst + (v-768)*4) =
            *(const float4*)(embT + ((size_t)t*Bz + b)*Hz + (v-768)*4);
      }
      __syncthreads();

      // gates: tid = jj(5b) | gate(2b) | ks(3b); each thread covers BOTH batches
      {
        const int ks   = tid & 7;          // 0..7 (K-split-8: 64 f4-iters)
        const int gate = (tid >> 3) & 3;
        const int jj   = tid >> 5;         // 0..31
        const int j    = jbase + jj;
        const int row  = gate*Hz + j;
        const float* x0 = s_x + ks*4;
        const float* x1 = s_x + BLS + ks*4;
        const unsigned short* w = wbf + (size_t)row*GK + ks*4;
        float p00=0.f,p01=0.f,p02=0.f,p03=0.f;
        float p10=0.f,p11=0.f,p12=0.f,p13=0.f;
        #pragma unroll 16
        for (int i=0;i<64;i++){
          float w0,w1,w2,w3; bf4(*(const u64*)(w + i*32), w0,w1,w2,w3);
          float4 xv0 = *(const float4*)(x0 + i*32);
          float4 xv1 = *(const float4*)(x1 + i*32);
          p00=fmaf(xv0.x,w0,p00); p01=fmaf(xv0.y,w1,p01);
          p02=fmaf(xv0.z,w2,p02); p03=fmaf(xv0.w,w3,p03);
          p10=fmaf(xv1.x,w0,p10); p11=fmaf(xv1.y,w1,p11);
          p12=fmaf(xv1.z,w2,p12); p13=fmaf(xv1.w,w3,p13);
        }
        float acc0 = (p00+p01)+(p02+p03);
        float acc1 = (p10+p11)+(p12+p13);
        acc0 += __shfl_xor(acc0, 1, 64); acc1 += __shfl_xor(acc1, 1, 64);
        acc0 += __shfl_xor(acc0, 2, 64); acc1 += __shfl_xor(acc1, 2, 64);
        acc0 += __shfl_xor(acc0, 4, 64); acc1 += __shfl_xor(acc1, 4, 64);
        float bl_ = b_lstm[row];
        acc0 += bl_; acc1 += bl_;
        // lane bits: ks 0-2, gate 3-4, jj&1 bit 5. Gather gates at base+0/8/16/24.
        const int lane = tid & 63;
        const int base = lane & ~24;
        float gi0 = __shfl(acc0, base+0,  64), gi1 = __shfl(acc1, base+0,  64);
        float gf0 = __shfl(acc0, base+8,  64), gf1 = __shfl(acc1, base+8,  64);
        float gg0 = __shfl(acc0, base+16, 64), gg1 = __shfl(acc1, base+16, 64);
        float go0 = __shfl(acc0, base+24, 64), go1 = __shfl(acc1, base+24, 64);
        if ((lane & 31) == 0){             // ks==0 && gate==0
          float cv0 = cT[(size_t)b0*Hz + j];
          float cn0 = sigf(gf0)*cv0 + sigf(gi0)*tanhf(gg0);
          float hn0 = sigf(go0)*tanhf(cn0);
          cT[(size_t)b0*Hz + j] = cn0;
          st32cv(&hT[(size_t)nxt*HTB + (size_t)b0*Hz + j], hn0);
          float cv1 = cT[(size_t)(b0+1)*Hz + j];
          float cn1 = sigf(gf1)*cv1 + sigf(gi1)*tanhf(gg1);
          float hn1 = sigf(go1)*tanhf(cn1);
          cT[(size_t)(b0+1)*Hz + j] = cn1;
          st32cv(&hT[(size_t)nxt*HTB + (size_t)(b0+1)*Hz + j], hn1);
        }
      }
    }
    gbar_grp(bar, kbar, bp); kbar++;

    // ===== Phase B: xi = h_new @ w_xi (bf16 W, batch-pair fused, one round) =====
    // overwrites only s_x[bl*BLS + 0..512) (emb slot); r|h retained for phase C out-dot
    {
      if (tid < 512){
        const int bl = tid >> 8, v = tid & 255;
        stage64(s_x + bl*BLS + v*2, hT + (size_t)nxt*HTB + (size_t)(b0+bl)*Hz + v*2);
      }
      __syncthreads();
      const int ks  = tid & 3;             // 0..3 (128-elem slices, 32 f4-iters)
      const int fi  = tid >> 2;            // 0..255 (need 0..160)
      const int f   = jc*322 + sj*161 + fi;
      if (fi < 161 && f < IFz){
        const float* x0 = s_x + ks*4;
        const float* x1 = s_x + BLS + ks*4;
        const unsigned short* w = wxibf + (size_t)f*Hz + ks*4;
        float a0=0.f,a1=0.f;
        #pragma unroll 16
        for (int i=0;i<32;i++){
          float w0,w1,w2,w3; bf4(*(const u64*)(w + i*16), w0,w1,w2,w3);
          float4 xv0 = *(const float4*)(x0 + i*16);
          float4 xv1 = *(const float4*)(x1 + i*16);
          a0 = fmaf(xv0.x,w0,fmaf(xv0.y,w1,fmaf(xv0.z,w2,fmaf(xv0.w,w3,a0))));
          a1 = fmaf(xv1.x,w0,fmaf(xv1.y,w1,fmaf(xv1.z,w2,fmaf(xv1.w,w3,a1))));
        }
        a0 += __shfl_xor(a0, 1, 64); a1 += __shfl_xor(a1, 1, 64);
        a0 += __shfl_xor(a0, 2, 64); a1 += __shfl_xor(a1, 2, 64);
        if (ks == 0){
          float bx = b_xi[f];
          st32cv(&xiT[(size_t)b0*IFz + f],     a0 + bx);
          st32cv(&xiT[(size_t)(b0+1)*IFz + f], a1 + bx);
        }
      }
    }
    gbar_grp(bar, kbar, bp); kbar++;

    // ===== Phase C: memops (2 WGs/group) | out(t-1) (batch-pair fused, 1 pass) =====
    {
      if (slot == sA){
        memops(b0, t, xiT, Mg, ug, pg, wwg, Lg, wrg, rT);
      } else if (slot == sB){
        memops(b0+1, t, xiT, Mg, ug, pg, wwg, Lg, wrg, rT);
      } else if (t > 0){
        const int oks = tid & 15;          // 0..15 (96-elem slices, 24 f4-iters)
        const int ojj = tid >> 4;          // 0..63 (need 0..36)
        const int oj  = rank*37 + ojj;
        if (ojj < 37 && oj < 512){
          const unsigned short* wo = wobf + (size_t)oj*XD + oks*4;
          const float* xh0 = s_x + 1536 + oks*4;
          const float* xr0 = s_x + oks*4;
          const float* xh1 = s_x + BLS + 1536 + oks*4;
          const float* xr1 = s_x + BLS + oks*4;
          float a0=0.f,a1=0.f;
          #pragma unroll 8
          for (int i=0;i<8;i++){
            float w0,w1,w2,w3; bf4(*(const u64*)(wo + i*64), w0,w1,w2,w3);
            float4 x0 = *(const float4*)(xh0 + i*64);
            float4 x1 = *(const float4*)(xh1 + i*64);
            a0 = fmaf(x0.x,w0,fmaf(x0.y,w1,fmaf(x0.z,w2,fmaf(x0.w,w3,a0))));
            a1 = fmaf(x1.x,w0,fmaf(x1.y,w1,fmaf(x1.z,w2,fmaf(x1.w,w3,a1))));
          }
          #pragma unroll 16
          for (int i=8;i<24;i++){
            float w0,w1,w2,w3; bf4(*(const u64*)(wo + i*64), w0,w1,w2,w3);
            float4 x0 = *(const float4*)(xr0 + i*64);
            float4 x1 = *(const float4*)(xr1 + i*64);
            a0 = fmaf(x0.x,w0,fmaf(x0.y,w1,fmaf(x0.z,w2,fmaf(x0.w,w3,a0))));
            a1 = fmaf(x1.x,w0,fmaf(x1.y,w1,fmaf(x1.z,w2,fmaf(x1.w,w3,a1))));
          }
          a0 += __shfl_xor(a0, 1, 64); a1 += __shfl_xor(a1, 1, 64);
          a0 += __shfl_xor(a0, 2, 64); a1 += __shfl_xor(a1, 2, 64);
          a0 += __shfl_xor(a0, 4, 64); a1 += __shfl_xor(a1, 4, 64);
          a0 += __shfl_xor(a0, 8, 64); a1 += __shfl_xor(a1, 8, 64);
          if (oks == 0){
            float bo = b_out[oj];
            out[(size_t)b0*Tz*Hz + (size_t)(t-1)*Hz + oj]     = a0 + bo;
            out[(size_t)(b0+1)*Tz*Hz + (size_t)(t-1)*Hz + oj] = a1 + bo;
          }
        }
      }
    }
    gbar_grp(bar, kbar, bp); kbar++;
  }

  gbar_fence(bar, 1);   // grid-wide: make coherent state + private cT cache-readable

  // ---- epilogue: out(T-1), final h, c (state in buffer 0) ----
  if (gid < Bz*Hz){
    const int eb = gid >> 9, ej = gid & 511;
    const unsigned short* wj = wobf + (size_t)ej*XD;
    float acc = dot4cbf(hT + (size_t)eb*Hz,  wj,       512)
              + dot4cbf(rT + (size_t)eb*RWz, wj + 512, 1024)
              + b_out[ej];
    out[(size_t)eb*Tz*Hz + (size_t)(Tz-1)*Hz + ej] = acc;
    out[(size_t)Bz*Tz*Hz + (size_t)eb*Hz + ej]       = hT[(size_t)eb*Hz + ej];
    out[(size_t)Bz*Tz*Hz + HTB + (size_t)eb*Hz + ej] = cT[(size_t)eb*Hz + ej];
  }
}

extern "C" void kernel_launch(void* const* d_in, const int* in_sizes, int n_in,
                              void* d_out, int out_size, void* d_ws, size_t ws_size,
                              hipStream_t stream)
{
  const int*   src    = (const int*)  d_in[0];
  // d_in[1] = source_lengths (unused by reference)
  const float* emb    = (const float*)d_in[2];
  const float* w_ih   = (const float*)d_in[3];
  const float* w_hh   = (const float*)d_in[4];
  const float* b_lstm = (const float*)d_in[5];
  const float* w_xi   = (const float*)d_in[6];
  const float* b_xi   = (const float*)d_in[7];
  const float* w_out  = (const float*)d_in[8];
  const float* b_out  = (const float*)d_in[9];
  float* out = (float*)d_out;
  float* ws  = (float*)d_ws;

  // zero the barrier region (fence counters/flags + group counters share it)
  hipMemsetAsync((char*)d_ws + (size_t)BAR_OFF*4, 0, 8192, stream);

  void* args[] = { &src, &emb, &w_ih, &w_hh, &b_lstm, &w_xi, &b_xi, &w_out, &b_out, &out, &ws };
  hipLaunchCooperativeKernel((const void*)dnc_kernel, dim3(NWG), dim3(NT), args, 0, stream);
}

// Round 24
// 8035.883 us; speedup vs baseline: 2.2637x; 1.0419x over previous
//
#include <hip/hip_runtime.h>

#define Bz 32
#define Tz 256
#define Hz 512
#define Nz 5
#define Rz 2
#define Wz 512
#define WP 520           // padded s_M row stride
#define RWz 1024
#define XD 1536          // H + R*W
#define GK 2048          // gates K (XD + Hz)
#define IFz 2573
#define EPSF 1e-6f
#define NWG 256
#define NT 1024
#define NTH (NWG*NT)     // 262144

#define HTB (Bz*Hz)      // 16384 floats per h buffer
#define RTB (Bz*RWz)     // 32768 floats per r buffer
#define BLS 2064         // per-batch LDS slab stride (2048 + 16 pad)

// workspace float offsets
#define WXIT_OFF (Tz*Bz*Hz)                            // 4194304 (bf16 mirror of w_xi^T)
#define WOUT_OFF (WXIT_OFF + IFz*Hz)                   // 5511680 (bf16 mirror of w_out^T)
#define HT_OFF   (WOUT_OFF + Hz*XD)                    // 6298112
#define CT_OFF   (HT_OFF + 2*HTB)                      // 6330880
#define RT_OFF   (CT_OFF + HTB)                        // 6347264
#define XIT_OFF  (RT_OFF + 2*RTB)                      // 6412800
#define MG_OFF   (XIT_OFF + IFz*Bz)                    // 6495136
#define UG_OFF   (MG_OFF + Bz*Nz*Wz)                   // 6577056
#define BAR_OFF  (UG_OFF + 1600 + 32)                  // 6578688 (barrier region, 2048 floats)
#define WBF_OFF  (BAR_OFF + 2048)                      // 6580736 (bf16 gates: 2048x2048 ushort)
// fence counters at bar[g*64], fence flags at bar[1024+g*64].
// group flags at bar[g*64+32+slot] (slot 0..15) — inside memset'd padding, no overlap.

// xi field offsets
#define O_KR 0
#define O_BR 1024
#define O_KW 1026
#define O_BW 1538
#define O_E  1539
#define O_V  2051
#define O_FG 2563
#define O_GA 2565
#define O_GW 2566
#define O_PI 2567

typedef unsigned long long u64;

__device__ __forceinline__ float sigf(float x){ return 1.0f/(1.0f+expf(-x)); }
__device__ __forceinline__ float splus(float x){ return fmaxf(x,0.0f) + log1pf(expf(-fabsf(x))); }
__device__ __forceinline__ unsigned short f2bf(float v){
  unsigned u = __float_as_uint(v);
  return (unsigned short)((u + 0x7FFFu + ((u >> 16) & 1u)) >> 16);
}
// cheap exact unpack: 4 bf16 weights from one u64, 1 op each
__device__ __forceinline__ void bf4(u64 wb, float& w0, float& w1, float& w2, float& w3){
  unsigned lo = (unsigned)wb, hi = (unsigned)(wb >> 32);
  w0 = __uint_as_float(lo << 16);
  w1 = __uint_as_float(lo & 0xFFFF0000u);
  w2 = __uint_as_float(hi << 16);
  w3 = __uint_as_float(hi & 0xFFFF0000u);
}

// coherent accessors (R12-proven)
__device__ __forceinline__ void stage64(float* dst_lds, const float* src){
  u64 v = __hip_atomic_load((const u64*)src, __ATOMIC_RELAXED, __HIP_MEMORY_SCOPE_AGENT);
  *(u64*)dst_lds = v;
}
__device__ __forceinline__ float ld32cv(const float* p){
  return __hip_atomic_load(p, __ATOMIC_RELAXED, __HIP_MEMORY_SCOPE_AGENT);
}
__device__ __forceinline__ void st32cv(float* p, float v){
  __hip_atomic_store(p, v, __ATOMIC_RELAXED, __HIP_MEMORY_SCOPE_AGENT);
}

// ---- grid-wide fence barrier (init/final only) ----
__device__ __forceinline__ void gbar_fence(unsigned* bar, unsigned k){
  __syncthreads();
  const int tid = threadIdx.x;
  const unsigned wg = blockIdx.x;
  if (tid == 0){
    __builtin_amdgcn_fence(__ATOMIC_RELEASE, "agent");
    __hip_atomic_fetch_add(&bar[(wg & 15u)*64], 1u, __ATOMIC_RELAXED, __HIP_MEMORY_SCOPE_AGENT);
  }
  if (wg == 0){
    if (tid < 16){
      const unsigned tgt = (NWG/16u)*(k+1u);
      while (__hip_atomic_load(&bar[tid*64], __ATOMIC_RELAXED, __HIP_MEMORY_SCOPE_AGENT) < tgt)
        __builtin_amdgcn_s_sleep(1);
    }
    __syncthreads();
    if (tid < 16){
      __builtin_amdgcn_fence(__ATOMIC_ACQ_REL, "agent");
      __hip_atomic_store(&bar[1024 + tid*64], k+1u, __ATOMIC_RELAXED, __HIP_MEMORY_SCOPE_AGENT);
    }
    __syncthreads();
  } else {
    if (tid == 0){
      while (__hip_atomic_load(&bar[1024 + (wg & 15u)*64], __ATOMIC_RELAXED, __HIP_MEMORY_SCOPE_AGENT) < k+1u)
        __builtin_amdgcn_s_sleep(1);
      __builtin_amdgcn_fence(__ATOMIC_ACQUIRE, "agent");
    }
    __syncthreads();
  }
}
// ---- 16-WG group barrier, flag-based: one store per WG + parallel 16-flag poll ----
// WG `slot` of group `grp` owns flag bar[grp*64+32+slot]; monotonic epoch k+1.
__device__ __forceinline__ void gbar_grp(unsigned* bar, unsigned k, int grp, int slot){
  __syncthreads();   // each wave drains its own vmcnt before s_barrier (compiler-enforced)
  const int tid = threadIdx.x;
  if (tid == 0)
    __hip_atomic_store(&bar[grp*64 + 32 + slot], k+1u, __ATOMIC_RELAXED, __HIP_MEMORY_SCOPE_AGENT);
  if (tid < 16){
    const unsigned tgt = k+1u;
    while (__hip_atomic_load(&bar[grp*64 + 32 + tid], __ATOMIC_RELAXED, __HIP_MEMORY_SCOPE_AGENT) < tgt)
      __builtin_amdgcn_s_sleep(1);
  }
  __syncthreads();
}

// contiguous bf16-weight dot (epilogue)
__device__ __forceinline__ float dot4cbf(const float* __restrict__ x,
                                         const unsigned short* __restrict__ w, int n){
  float a0=0.f,a1=0.f,a2=0.f,a3=0.f;
  #pragma unroll 8
  for (int i=0;i<n/4;i++){
    float4 xv = *(const float4*)(x + i*4);
    float w0,w1,w2,w3; bf4(*(const u64*)(w + i*4), w0,w1,w2,w3);
    a0=fmaf(xv.x,w0,a0); a1=fmaf(xv.y,w1,a1);
    a2=fmaf(xv.z,w2,a2); a3=fmaf(xv.w,w3,a3);
  }
  return (a0+a1)+(a2+a3);
}

__device__ void memops(int b, int t, const float* xiT,
                       float* Mg, float* ug, float* pg, float* wwg, float* Lg, float* wrg,
                       float* rT)
{
  __shared__ float s_xi[IFz];
  __shared__ float s_M[Nz*WP];
  __shared__ float s_u[Nz], s_p[Nz], s_ww[Nz], s_a[Nz], s_L[Nz*Nz], s_wr[Rz*Nz];
  __shared__ float s_sc[13];
  __shared__ float s_m2[Nz], s_dt[Nz], s_d0[Nz], s_d1[Nz];
  __shared__ float s_kw2, s_kr2[2];
  __shared__ float s_fwd[Rz*Nz], s_bwd[Rz*Nz];

  const int tid = threadIdx.x;
  const int wv = tid >> 6, ln = tid & 63;

  for (int f = tid; f < IFz; f += NT) s_xi[f] = ld32cv(&xiT[(size_t)b*IFz + f]);
  for (int i = tid; i < Nz*Wz; i += NT){
    int n = i >> 9, w = i & 511;
    s_M[n*WP+w] = Mg[(size_t)b*Nz*Wz + i];
  }
  if (tid < Nz){ s_u[tid]=ug[b*Nz+tid]; s_p[tid]=pg[b*Nz+tid]; s_ww[tid]=wwg[b*Nz+tid]; }
  if (tid < Nz*Nz) s_L[tid] = Lg[b*Nz*Nz+tid];
  if (tid < Rz*Nz) s_wr[tid] = wrg[b*Rz*Nz+tid];
  __syncthreads();

  if (tid == 0){
    s_sc[0] = 1.0f + splus(s_xi[O_BR+0]);
    s_sc[1] = 1.0f + splus(s_xi[O_BR+1]);
    s_sc[2] = 1.0f + splus(s_xi[O_BW]);
    s_sc[3] = sigf(s_xi[O_FG+0]);
    s_sc[4] = sigf(s_xi[O_FG+1]);
    s_sc[5] = sigf(s_xi[O_GA]);
    s_sc[6] = sigf(s_xi[O_GW]);
    for (int r=0;r<Rz;r++){
      float x0=s_xi[O_PI+r*3+0], x1=s_xi[O_PI+r*3+1], x2=s_xi[O_PI+r*3+2];
      float m = fmaxf(x0,fmaxf(x1,x2));
      float e0=expf(x0-m), e1=expf(x1-m), e2=expf(x2-m);
      float s = e0+e1+e2;
      s_sc[7+r*3+0]=e0/s; s_sc[7+r*3+1]=e1/s; s_sc[7+r*3+2]=e2/s;
    }
  }
  __syncthreads();

  if (tid < Nz){
    float psi = (1.0f - s_sc[3]*s_wr[0*Nz+tid]) * (1.0f - s_sc[4]*s_wr[1*Nz+tid]);
    float uu = s_u[tid], w = s_ww[tid];
    s_u[tid] = (uu + w - uu*w) * psi;
  }

  // cosine(M_old, kw): waves 0..4 -> n, wave 5 -> ||kw||^2 (16 waves; R1-proven)
  if (wv < Nz){
    const int n = wv;
    float pd=0.f, pm=0.f;
    for (int w = ln; w < Wz; w += 64){
      float kv = s_xi[O_KW+w], mv = s_M[n*WP+w];
      pd = fmaf(kv,mv,pd); pm = fmaf(mv,mv,pm);
    }
    for (int off=32; off; off>>=1){ pd += __shfl_down(pd,off,64); pm += __shfl_down(pm,off,64); }
    if (ln==0){ s_dt[n]=pd; s_m2[n]=pm; }
  } else if (wv == 5){
    float p2=0.f;
    for (int w=ln; w<Wz; w+=64){ float kv=s_xi[O_KW+w]; p2=fmaf(kv,kv,p2); }
    for (int off=32; off; off>>=1) p2 += __shfl_down(p2,off,64);
    if (ln==0) s_kw2 = p2;
  }
  __syncthreads();

  if (tid == 0){
    float su[Nz]; int idx[Nz];
    for (int i=0;i<Nz;i++){
      float v = EPSF + (1.0f-EPSF)*s_u[i];
      int j=i;
      while (j>0 && su[j-1] > v){ su[j]=su[j-1]; idx[j]=idx[j-1]; j--; }
      su[j]=v; idx[j]=i;
    }
    float cp = 1.0f;
    for (int k=0;k<Nz;k++){ s_a[idx[k]] = (1.0f - su[k])*cp; cp *= su[k]; }
    float rk = rsqrtf(s_kw2 + EPSF);
    float lg[Nz], mx=-1e30f;
    for (int n=0;n<Nz;n++){ lg[n] = s_sc[2]*s_dt[n]*rk*rsqrtf(s_m2[n]+EPSF); mx=fmaxf(mx,lg[n]); }
    float ssum=0.f;
    for (int n=0;n<Nz;n++){ lg[n]=expf(lg[n]-mx); ssum+=lg[n]; }
    float ga=s_sc[5], gw=s_sc[6];
    for (int n=0;n<Nz;n++){ float cwn = lg[n]/ssum; s_ww[n] = gw*(ga*s_a[n] + (1.0f-ga)*cwn); }
  }
  __syncthreads();

  for (int i = tid; i < Nz*Wz; i += NT){
    int n = i >> 9, w = i & 511;
    float e = sigf(s_xi[O_E+w]);
    float v = s_xi[O_V+w];
    s_M[n*WP+w] = s_M[n*WP+w]*(1.0f - s_ww[n]*e) + s_ww[n]*v;
  }
  __syncthreads();

  if (tid == 0){
    float wsum = 0.f;
    for (int n=0;n<Nz;n++) wsum += s_ww[n];
    float Lo[Nz*Nz];
    for (int i=0;i<Nz;i++)
      for (int j=0;j<Nz;j++)
        Lo[i*Nz+j] = (i==j) ? 0.0f : ((1.0f - s_ww[i] - s_ww[j])*s_L[i*Nz+j] + s_ww[i]*s_p[j]);
    for (int i=0;i<Nz*Nz;i++) s_L[i]=Lo[i];
    for (int j=0;j<Nz;j++) s_p[j] = (1.0f-wsum)*s_p[j] + s_ww[j];
    for (int r=0;r<Rz;r++)
      for (int n=0;n<Nz;n++){
        float f=0.f, bb=0.f;
        for (int m=0;m<Nz;m++){ f = fmaf(s_L[n*Nz+m], s_wr[r*Nz+m], f); bb = fmaf(s_L[m*Nz+n], s_wr[r*Nz+m], bb); }
        s_fwd[r*Nz+n]=f; s_bwd[r*Nz+n]=bb;
      }
  }
  __syncthreads();

  // cosine(M_new, kr): waves 0..4 -> n, waves 5,6 -> ||kr||^2 (16 waves; R1-proven)
  if (wv < Nz){
    const int n = wv;
    float pm=0.f,p0=0.f,p1=0.f;
    for (int w=ln; w<Wz; w+=64){
      float mv=s_M[n*WP+w];
      pm=fmaf(mv,mv,pm);
      p0=fmaf(s_xi[O_KR+w],    mv,p0);
      p1=fmaf(s_xi[O_KR+Wz+w], mv,p1);
    }
    for (int off=32; off; off>>=1){
      pm += __shfl_down(pm,off,64); p0 += __shfl_down(p0,off,64); p1 += __shfl_down(p1,off,64);
    }
    if (ln==0){ s_m2[n]=pm; s_d0[n]=p0; s_d1[n]=p1; }
  } else if (wv == 5 || wv == 6){
    const int r = wv - 5;
    float p2=0.f;
    for (int w=ln; w<Wz; w+=64){ float kv=s_xi[O_KR+r*Wz+w]; p2=fmaf(kv,kv,p2); }
    for (int off=32; off; off>>=1) p2 += __shfl_down(p2,off,64);
    if (ln==0) s_kr2[r]=p2;
  }
  __syncthreads();

  if (tid == 0){
    for (int r=0;r<Rz;r++){
      float rk = rsqrtf(s_kr2[r]+EPSF);
      const float* dd = (r==0) ? s_d0 : s_d1;
      float br = s_sc[r];
      float lg[Nz], mx=-1e30f;
      for (int n=0;n<Nz;n++){ lg[n] = br*dd[n]*rk*rsqrtf(s_m2[n]+EPSF); mx=fmaxf(mx,lg[n]); }
      float ssum=0.f;
      for (int n=0;n<Nz;n++){ lg[n]=expf(lg[n]-mx); ssum+=lg[n]; }
      for (int n=0;n<Nz;n++){
        float crn = lg[n]/ssum;
        s_wr[r*Nz+n] = s_sc[7+r*3+0]*s_bwd[r*Nz+n] + s_sc[7+r*3+1]*crn + s_sc[7+r*3+2]*s_fwd[r*Nz+n];
      }
    }
  }
  __syncthreads();

  // read vectors -> rT[nxt][b][r*512+w] (coherent) + private state (cached)
  float* rdst = rT + (size_t)((t+1)&1)*RTB + (size_t)b*RWz;
  for (int w = tid; w < Wz; w += NT){
    float m0=s_M[0*WP+w], m1=s_M[1*WP+w], m2=s_M[2*WP+w], m3=s_M[3*WP+w], m4=s_M[4*WP+w];
    #pragma unroll
    for (int r=0;r<Rz;r++){
      float rv = s_wr[r*Nz+0]*m0 + s_wr[r*Nz+1]*m1 + s_wr[r*Nz+2]*m2
               + s_wr[r*Nz+3]*m3 + s_wr[r*Nz+4]*m4;
      st32cv(&rdst[r*Wz + w], rv);
    }
  }
  for (int i = tid; i < Nz*Wz; i += NT){
    int n = i >> 9, w = i & 511;
    Mg[(size_t)b*Nz*Wz+i] = s_M[n*WP+w];
  }
  if (tid < Nz){ ug[b*Nz+tid]=s_u[tid]; pg[b*Nz+tid]=s_p[tid]; wwg[b*Nz+tid]=s_ww[tid]; }
  if (tid < Nz*Nz) Lg[b*Nz*Nz+tid]=s_L[tid];
  if (tid < Rz*Nz) wrg[b*Rz*Nz+tid]=s_wr[tid];
}

__global__ void __launch_bounds__(NT, 4)
dnc_kernel(const int* __restrict__ src, const float* __restrict__ emb,
           const float* __restrict__ w_ih, const float* __restrict__ w_hh,
           const float* __restrict__ b_lstm,
           const float* __restrict__ w_xi, const float* __restrict__ b_xi,
           const float* __restrict__ w_out, const float* __restrict__ b_out,
           float* __restrict__ out, float* __restrict__ ws)
{
  __shared__ __align__(16) float s_x[4112];   // 2 batches x 2048, stride BLS=2064

  const int tid = threadIdx.x;
  const int gid = blockIdx.x*NT + tid;

  float* embT  = ws;                       // [T][B][512]   cached RO
  float* hT    = ws + HT_OFF;              // [2][B][512]   coherent
  float* cT    = ws + CT_OFF;              // [B][512]      cached, WG-pinned
  float* rT    = ws + RT_OFF;              // [2][B][1024]  coherent
  float* xiT   = ws + XIT_OFF;             // [B][IFz]      coherent
  float* Mg    = ws + MG_OFF;              // [B][2560]     cached, WG-pinned
  float* ug    = ws + UG_OFF;
  float* pg    = ug + Bz*Nz;
  float* wwg   = pg + Bz*Nz;
  float* Lg    = wwg + Bz*Nz;
  float* wrg   = Lg + Bz*Nz*Nz;
  unsigned* bar  = (unsigned*)(ws + BAR_OFF);
  unsigned short* wbf   = (unsigned short*)(ws + WBF_OFF);   // [2048][2048] bf16 [w_ih|w_hh]
  unsigned short* wxibf = (unsigned short*)(ws + WXIT_OFF);  // [IFz][512]   bf16 w_xi^T
  unsigned short* wobf  = (unsigned short*)(ws + WOUT_OFF);  // [512][1536]  bf16 w_out^T
  unsigned kbar = 0;

  // ---- init ----
  {
    float4* embT4 = (float4*)embT;
    const float4* emb4 = (const float4*)emb;
    for (int i = gid; i < Tz*Bz*128; i += NTH){
      int kg = i & 127, b = (i>>7) & 31, tt = i >> 12;
      embT4[i] = emb4[(size_t)src[b*Tz+tt]*128 + kg];
    }
  }
  for (int i = gid; i < IFz*Hz; i += NTH){           // wxibf[f][k] = bf16(w_xi[k][f])
    int f = i >> 9, k = i & 511;
    wxibf[i] = f2bf(w_xi[(size_t)k*IFz + f]);
  }
  for (int i = gid; i < Hz*XD; i += NTH){            // wobf[j][k] = bf16(w_out[k][j])
    int j = i / XD, k = i - j*XD;
    wobf[i] = f2bf(w_out[(size_t)k*Hz + j]);
  }
  for (int i = gid; i < GK*GK; i += NTH){            // wbf[row][k] = bf16([w_ih|w_hh])
    int row = i >> 11, k = i & 2047;
    float v = (k < XD) ? w_ih[(size_t)row*XD + k] : w_hh[(size_t)row*Hz + (k - XD)];
    wbf[i] = f2bf(v);
  }
  for (int i = gid; i < 2*HTB; i += NTH) hT[i]=0.f;
  for (int i = gid; i < HTB;   i += NTH) cT[i]=0.f;
  for (int i = gid; i < 2*RTB; i += NTH) rT[i]=0.f;
  for (int i = gid; i < Bz*Nz*Wz;i += NTH) Mg[i]=0.f;
  for (int i = gid; i < Bz*(3*Nz + Nz*Nz + Rz*Nz); i += NTH) ug[i]=0.f;
  gbar_fence(bar, 0);

  // WG decomposition: jc (XCD pin) x sj (j-half) x bp (batch pair == sync group)
  const int jc = blockIdx.x & 7;          // 0..7
  const int sj = (blockIdx.x >> 3) & 1;   // 0..1
  const int bp = blockIdx.x >> 4;         // 0..15 (group id)
  const int b0 = 2*bp;                    // batches b0, b0+1
  const int jbase = jc*64 + sj*32;        // 32 j-rows per WG (gates)
  // phase-C role: slot = jc*2+sj; memops slots sA (even batch), sB (odd)
  const int slot = jc*2 + sj;
  const int sA = ((b0 & 7) << 1);
  const int sB = (((b0+1) & 7) << 1) | 1;
  const int rank = slot - (slot > sA ? 1 : 0) - (slot > sB ? 1 : 0);  // 0..13 for non-memops

  // ---- time loop (group-local sync only; no agent fences inside) ----
  for (int t = 0; t < Tz; ++t){
    const int cur = t & 1, nxt = (t+1)&1;

    // ===== Phase A: gates GEMV (bf16 W, batch-pair fused, ks-8) =====
    {
      for (int u = tid; u < 1792; u += NT){
        const int bl = (u >= 896) ? 1 : 0;
        const int v  = u - bl*896;
        const int b  = b0 + bl;
        float* dst = s_x + bl*BLS;
        if (v < 256)
          stage64(dst + 1536 + v*2, hT + (size_t)cur*HTB + (size_t)b*Hz + v*2);
        else if (v < 768)
          stage64(dst + 512 + (v-256)*2, rT + (size_t)cur*RTB + (size_t)b*RWz + (v-256)*2);
        else
          *(float4*)(dst + (v-768)*4) =
            *(const float4*)(embT + ((size_t)t*Bz + b)*Hz + (v-768)*4);
      }
      __syncthreads();

      // gates: tid = jj(5b) | gate(2b) | ks(3b); each thread covers BOTH batches
      {
        const int ks   = tid & 7;          // 0..7 (K-split-8: 64 f4-iters)
        const int gate = (tid >> 3) & 3;
        const int jj   = tid >> 5;         // 0..31
        const int j    = jbase + jj;
        const int row  = gate*Hz + j;
        const float* x0 = s_x + ks*4;
        const float* x1 = s_x + BLS + ks*4;
        const unsigned short* w = wbf + (size_t)row*GK + ks*4;
        float p00=0.f,p01=0.f,p02=0.f,p03=0.f;
        float p10=0.f,p11=0.f,p12=0.f,p13=0.f;
        #pragma unroll 16
        for (int i=0;i<64;i++){
          float w0,w1,w2,w3; bf4(*(const u64*)(w + i*32), w0,w1,w2,w3);
          float4 xv0 = *(const float4*)(x0 + i*32);
          float4 xv1 = *(const float4*)(x1 + i*32);
          p00=fmaf(xv0.x,w0,p00); p01=fmaf(xv0.y,w1,p01);
          p02=fmaf(xv0.z,w2,p02); p03=fmaf(xv0.w,w3,p03);
          p10=fmaf(xv1.x,w0,p10); p11=fmaf(xv1.y,w1,p11);
          p12=fmaf(xv1.z,w2,p12); p13=fmaf(xv1.w,w3,p13);
        }
        float acc0 = (p00+p01)+(p02+p03);
        float acc1 = (p10+p11)+(p12+p13);
        acc0 += __shfl_xor(acc0, 1, 64); acc1 += __shfl_xor(acc1, 1, 64);
        acc0 += __shfl_xor(acc0, 2, 64); acc1 += __shfl_xor(acc1, 2, 64);
        acc0 += __shfl_xor(acc0, 4, 64); acc1 += __shfl_xor(acc1, 4, 64);
        float bl_ = b_lstm[row];
        acc0 += bl_; acc1 += bl_;
        // lane bits: ks 0-2, gate 3-4, jj&1 bit 5. Gather gates at base+0/8/16/24.
        const int lane = tid & 63;
        const int base = lane & ~24;
        float gi0 = __shfl(acc0, base+0,  64), gi1 = __shfl(acc1, base+0,  64);
        float gf0 = __shfl(acc0, base+8,  64), gf1 = __shfl(acc1, base+8,  64);
        float gg0 = __shfl(acc0, base+16, 64), gg1 = __shfl(acc1, base+16, 64);
        float go0 = __shfl(acc0, base+24, 64), go1 = __shfl(acc1, base+24, 64);
        if ((lane & 31) == 0){             // ks==0 && gate==0
          float cv0 = cT[(size_t)b0*Hz + j];
          float cn0 = sigf(gf0)*cv0 + sigf(gi0)*tanhf(gg0);
          float hn0 = sigf(go0)*tanhf(cn0);
          cT[(size_t)b0*Hz + j] = cn0;
          st32cv(&hT[(size_t)nxt*HTB + (size_t)b0*Hz + j], hn0);
          float cv1 = cT[(size_t)(b0+1)*Hz + j];
          float cn1 = sigf(gf1)*cv1 + sigf(gi1)*tanhf(gg1);
          float hn1 = sigf(go1)*tanhf(cn1);
          cT[(size_t)(b0+1)*Hz + j] = cn1;
          st32cv(&hT[(size_t)nxt*HTB + (size_t)(b0+1)*Hz + j], hn1);
        }
      }
    }
    gbar_grp(bar, kbar, bp, slot); kbar++;

    // ===== Phase B: xi = h_new @ w_xi (bf16 W, batch-pair fused, one round) =====
    // overwrites only s_x[bl*BLS + 0..512) (emb slot); r|h retained for phase C out-dot
    {
      if (tid < 512){
        const int bl = tid >> 8, v = tid & 255;
        stage64(s_x + bl*BLS + v*2, hT + (size_t)nxt*HTB + (size_t)(b0+bl)*Hz + v*2);
      }
      __syncthreads();
      const int ks  = tid & 3;             // 0..3 (128-elem slices, 32 f4-iters)
      const int fi  = tid >> 2;            // 0..255 (need 0..160)
      const int f   = jc*322 + sj*161 + fi;
      if (fi < 161 && f < IFz){
        const float* x0 = s_x + ks*4;
        const float* x1 = s_x + BLS + ks*4;
        const unsigned short* w = wxibf + (size_t)f*Hz + ks*4;
        float a0=0.f,a1=0.f;
        #pragma unroll 16
        for (int i=0;i<32;i++){
          float w0,w1,w2,w3; bf4(*(const u64*)(w + i*16), w0,w1,w2,w3);
          float4 xv0 = *(const float4*)(x0 + i*16);
          float4 xv1 = *(const float4*)(x1 + i*16);
          a0 = fmaf(xv0.x,w0,fmaf(xv0.y,w1,fmaf(xv0.z,w2,fmaf(xv0.w,w3,a0))));
          a1 = fmaf(xv1.x,w0,fmaf(xv1.y,w1,fmaf(xv1.z,w2,fmaf(xv1.w,w3,a1))));
        }
        a0 += __shfl_xor(a0, 1, 64); a1 += __shfl_xor(a1, 1, 64);
        a0 += __shfl_xor(a0, 2, 64); a1 += __shfl_xor(a1, 2, 64);
        if (ks == 0){
          float bx = b_xi[f];
          st32cv(&xiT[(size_t)b0*IFz + f],     a0 + bx);
          st32cv(&xiT[(size_t)(b0+1)*IFz + f], a1 + bx);
        }
      }
    }
    gbar_grp(bar, kbar, bp, slot); kbar++;

    // ===== Phase C: memops (2 WGs/group) | out(t-1) (batch-pair fused, 1 pass) =====
    {
      if (slot == sA){
        memops(b0, t, xiT, Mg, ug, pg, wwg, Lg, wrg, rT);
      } else if (slot == sB){
        memops(b0+1, t, xiT, Mg, ug, pg, wwg, Lg, wrg, rT);
      } else if (t > 0){
        const int oks = tid & 15;          // 0..15 (96-elem slices, 24 f4-iters)
        const int ojj = tid >> 4;          // 0..63 (need 0..36)
        const int oj  = rank*37 + ojj;
        if (ojj < 37 && oj < 512){
          const unsigned short* wo = wobf + (size_t)oj*XD + oks*4;
          const float* xh0 = s_x + 1536 + oks*4;
          const float* xr0 = s_x + oks*4;
          const float* xh1 = s_x + BLS + 1536 + oks*4;
          const float* xr1 = s_x + BLS + oks*4;
          float a0=0.f,a1=0.f;
          #pragma unroll 8
          for (int i=0;i<8;i++){
            float w0,w1,w2,w3; bf4(*(const u64*)(wo + i*64), w0,w1,w2,w3);
            float4 x0 = *(const float4*)(xh0 + i*64);
            float4 x1 = *(const float4*)(xh1 + i*64);
            a0 = fmaf(x0.x,w0,fmaf(x0.y,w1,fmaf(x0.z,w2,fmaf(x0.w,w3,a0))));
            a1 = fmaf(x1.x,w0,fmaf(x1.y,w1,fmaf(x1.z,w2,fmaf(x1.w,w3,a1))));
          }
          #pragma unroll 16
          for (int i=8;i<24;i++){
            float w0,w1,w2,w3; bf4(*(const u64*)(wo + i*64), w0,w1,w2,w3);
            float4 x0 = *(const float4*)(xr0 + i*64);
            float4 x1 = *(const float4*)(xr1 + i*64);
            a0 = fmaf(x0.x,w0,fmaf(x0.y,w1,fmaf(x0.z,w2,fmaf(x0.w,w3,a0))));
            a1 = fmaf(x1.x,w0,fmaf(x1.y,w1,fmaf(x1.z,w2,fmaf(x1.w,w3,a1))));
          }
          a0 += __shfl_xor(a0, 1, 64); a1 += __shfl_xor(a1, 1, 64);
          a0 += __shfl_xor(a0, 2, 64); a1 += __shfl_xor(a1, 2, 64);
          a0 += __shfl_xor(a0, 4, 64); a1 += __shfl_xor(a1, 4, 64);
          a0 += __shfl_xor(a0, 8, 64); a1 += __shfl_xor(a1, 8, 64);
          if (oks == 0){
            float bo = b_out[oj];
            out[(size_t)b0*Tz*Hz + (size_t)(t-1)*Hz + oj]     = a0 + bo;
            out[(size_t)(b0+1)*Tz*Hz + (size_t)(t-1)*Hz + oj] = a1 + bo;
          }
        }
      }
    }
    gbar_grp(bar, kbar, bp, slot); kbar++;
  }

  gbar_fence(bar, 1);   // grid-wide: make coherent state + private cT cache-readable

  // ---- epilogue: out(T-1), final h, c (state in buffer 0) ----
  if (gid < Bz*Hz){
    const int eb = gid >> 9, ej = gid & 511;
    const unsigned short* wj = wobf + (size_t)ej*XD;
    float acc = dot4cbf(hT + (size_t)eb*Hz,  wj,       512)
              + dot4cbf(rT + (size_t)eb*RWz, wj + 512, 1024)
              + b_out[ej];
    out[(size_t)eb*Tz*Hz + (size_t)(Tz-1)*Hz + ej] = acc;
    out[(size_t)Bz*Tz*Hz + (size_t)eb*Hz + ej]       = hT[(size_t)eb*Hz + ej];
    out[(size_t)Bz*Tz*Hz + HTB + (size_t)eb*Hz + ej] = cT[(size_t)eb*Hz + ej];
  }
}

extern "C" void kernel_launch(void* const* d_in, const int* in_sizes, int n_in,
                              void* d_out, int out_size, void* d_ws, size_t ws_size,
                              hipStream_t stream)
{
  const int*   src    = (const int*)  d_in[0];
  // d_in[1] = source_lengths (unused by reference)
  const float* emb    = (const float*)d_in[2];
  const float* w_ih   = (const float*)d_in[3];
  const float* w_hh   = (const float*)d_in[4];
  const float* b_lstm = (const float*)d_in[5];
  const float* w_xi   = (const float*)d_in[6];
  const float* b_xi   = (const float*)d_in[7];
  const float* w_out  = (const float*)d_in[8];
  const float* b_out  = (const float*)d_in[9];
  float* out = (float*)d_out;
  float* ws  = (float*)d_ws;

  // zero the barrier region (fence counters/flags + group flags share it)
  hipMemsetAsync((char*)d_ws + (size_t)BAR_OFF*4, 0, 8192, stream);

  void* args[] = { &src, &emb, &w_ih, &w_hh, &b_lstm, &w_xi, &b_xi, &w_out, &b_out, &out, &ws };
  hipLaunchCooperativeKernel((const void*)dnc_kernel, dim3(NWG), dim3(NT), args, 0, stream);
}